// Round 16
// baseline (1237.864 us; speedup 1.0000x reference)
//
#include <hip/hip_runtime.h>
#include <hip/hip_bf16.h>
#include <math.h>

// Problem constants
#define NB    2
#define SEQ   2048
#define DMODEL 1024
#define NH    16
#define HDIM  64
#define NE    8
#define DFF   4096
#define TTOK  4096   // NB*SEQ

#define MT_MAX   40     // 256-row m-tiles: sum ceil(cnt_e/256) <= 32+8
#define SLOT_MAX 10240  // 8192 + 8*255 padded, rounded

// ctrl block layout (ints)
#define C_CNT  0
#define C_FILL 8
#define C_BASE 16
#define C_NMT  24
#define C_MTE  32
#define C_MTS  80

typedef __attribute__((ext_vector_type(8))) short short8;
typedef __attribute__((ext_vector_type(4))) float f32x4;
typedef __attribute__((ext_vector_type(4))) unsigned int uint4v;

static __device__ __forceinline__ float bf2f(unsigned short u) {
  union { unsigned int i; float f; } c; c.i = ((unsigned int)u) << 16; return c.f;
}
static __device__ __forceinline__ unsigned short f2bf(float f) {
  unsigned int x = __float_as_uint(f);
  unsigned int r = (x + 0x7FFFu + ((x >> 16) & 1u)) >> 16;
  return (unsigned short)r;
}

// Async global->LDS, 16B per lane. LDS dest is WAVE-UNIFORM base + lane*16.
static __device__ __forceinline__ void gl_lds16(const void* g, void* l) {
  __builtin_amdgcn_global_load_lds(
      (const __attribute__((address_space(1))) unsigned int*)(uintptr_t)g,
      (__attribute__((address_space(3))) unsigned int*)(uintptr_t)l,
      16, 0, 0);
}

// ---------------------------------------------------------------------------
// LayerNorm. MODE 0: fp32 out. MODE 1: bf16 out. MODE 2: split hi/lo bf16.
// ---------------------------------------------------------------------------
template<int MODE>
__global__ __launch_bounds__(256) void ln_kernel(
    const float* __restrict__ x,
    const float* __restrict__ gam,
    const float* __restrict__ bet,
    float* __restrict__ outf,
    unsigned short* __restrict__ outb,
    unsigned short* __restrict__ outlo)
{
  int t = blockIdx.x, tid = threadIdx.x;
  f32x4 v = ((const f32x4*)(x + (size_t)t * DMODEL))[tid];
  float s  = v[0] + v[1] + v[2] + v[3];
  float sq = v[0]*v[0] + v[1]*v[1] + v[2]*v[2] + v[3]*v[3];
  #pragma unroll
  for (int off = 1; off < 64; off <<= 1) {
    s  += __shfl_xor(s, off);
    sq += __shfl_xor(sq, off);
  }
  __shared__ float red[8];
  int w = tid >> 6, l = tid & 63;
  if (l == 0) { red[w] = s; red[4 + w] = sq; }
  __syncthreads();
  s  = red[0] + red[1] + red[2] + red[3];
  sq = red[4] + red[5] + red[6] + red[7];
  float mu  = s * (1.0f / DMODEL);
  float var = sq * (1.0f / DMODEL) - mu * mu;
  float rs  = rsqrtf(var + 1e-5f);
  f32x4 g = ((const f32x4*)gam)[tid];
  f32x4 b = ((const f32x4*)bet)[tid];
  float r[4];
  r[0] = (v[0] - mu) * rs * g[0] + b[0];
  r[1] = (v[1] - mu) * rs * g[1] + b[1];
  r[2] = (v[2] - mu) * rs * g[2] + b[2];
  r[3] = (v[3] - mu) * rs * g[3] + b[3];
  if constexpr (MODE == 0) {
    f32x4 o = {r[0], r[1], r[2], r[3]};
    ((f32x4*)(outf + (size_t)t * DMODEL))[tid] = o;
  } else if constexpr (MODE == 1) {
    ushort4 o; o.x = f2bf(r[0]); o.y = f2bf(r[1]); o.z = f2bf(r[2]); o.w = f2bf(r[3]);
    ((ushort4*)(outb + (size_t)t * DMODEL))[tid] = o;
  } else {
    ushort4 hi, lo;
    unsigned short h0 = f2bf(r[0]); hi.x = h0; lo.x = f2bf(r[0] - bf2f(h0));
    unsigned short h1 = f2bf(r[1]); hi.y = h1; lo.y = f2bf(r[1] - bf2f(h1));
    unsigned short h2 = f2bf(r[2]); hi.z = h2; lo.z = f2bf(r[2] - bf2f(h2));
    unsigned short h3 = f2bf(r[3]); hi.w = h3; lo.w = f2bf(r[3] - bf2f(h3));
    ((ushort4*)(outb  + (size_t)t * DMODEL))[tid] = hi;
    ((ushort4*)(outlo + (size_t)t * DMODEL))[tid] = lo;
  }
}

// ---------------------------------------------------------------------------
// Split-bf16 MFMA GEMM (fp32-grade): C = (Ah+Al)(Bh+Bl) + bias [+resid].
// ---------------------------------------------------------------------------
template<int EPI>
__global__ __launch_bounds__(256) void mgemm_split(
    const unsigned short* __restrict__ Ah,
    const unsigned short* __restrict__ Alo,
    const unsigned short* __restrict__ Bth,
    const unsigned short* __restrict__ Btl,
    const float* __restrict__ bias,
    const float* __restrict__ resid,
    float* __restrict__ C, int M, int N, int K)
{
  __shared__ unsigned short AH[128][32];
  __shared__ unsigned short AL[128][32];
  __shared__ unsigned short BH[128][32];
  __shared__ unsigned short BL[128][32];
  int tid = threadIdx.x;
  int l = tid & 63, wv = tid >> 6;
  int wr = wv >> 1, wc = wv & 1;
  int m0 = blockIdx.y * 128, n0 = blockIdx.x * 128;
  int rsub = l >> 2, csub = (l & 3) * 8;
  int row0 = wv * 32 + rsub, row1 = row0 + 16;

  const unsigned short* gah0 = Ah  + (size_t)(m0 + row0) * K + csub;
  const unsigned short* gah1 = Ah  + (size_t)(m0 + row1) * K + csub;
  const unsigned short* gal0 = Alo + (size_t)(m0 + row0) * K + csub;
  const unsigned short* gal1 = Alo + (size_t)(m0 + row1) * K + csub;
  const unsigned short* gbh0 = Bth + (size_t)(n0 + row0) * K + csub;
  const unsigned short* gbh1 = Bth + (size_t)(n0 + row1) * K + csub;
  const unsigned short* gbl0 = Btl + (size_t)(n0 + row0) * K + csub;
  const unsigned short* gbl1 = Btl + (size_t)(n0 + row1) * K + csub;

  const f32x4 z = {0.f, 0.f, 0.f, 0.f};
  f32x4 acc[4][4];
  #pragma unroll
  for (int i = 0; i < 4; ++i)
    #pragma unroll
    for (int j = 0; j < 4; ++j) acc[i][j] = z;

  for (int k0 = 0; k0 < K; k0 += 32) {
    __syncthreads();
    gl_lds16(gah0 + k0, &AH[wv * 32][0]);
    gl_lds16(gah1 + k0, &AH[wv * 32 + 16][0]);
    gl_lds16(gal0 + k0, &AL[wv * 32][0]);
    gl_lds16(gal1 + k0, &AL[wv * 32 + 16][0]);
    gl_lds16(gbh0 + k0, &BH[wv * 32][0]);
    gl_lds16(gbh1 + k0, &BH[wv * 32 + 16][0]);
    gl_lds16(gbl0 + k0, &BL[wv * 32][0]);
    gl_lds16(gbl1 + k0, &BL[wv * 32 + 16][0]);
    __syncthreads();

    short8 afh[4], afl[4], bfh[4], bfl[4];
    #pragma unroll
    for (int m = 0; m < 4; ++m) {
      afh[m] = *(const short8*)(&AH[wr * 64 + m * 16 + (l & 15)][(l >> 4) << 3]);
      afl[m] = *(const short8*)(&AL[wr * 64 + m * 16 + (l & 15)][(l >> 4) << 3]);
    }
    #pragma unroll
    for (int n = 0; n < 4; ++n) {
      bfh[n] = *(const short8*)(&BH[wc * 64 + n * 16 + (l & 15)][(l >> 4) << 3]);
      bfl[n] = *(const short8*)(&BL[wc * 64 + n * 16 + (l & 15)][(l >> 4) << 3]);
    }
    #pragma unroll
    for (int m = 0; m < 4; ++m)
      #pragma unroll
      for (int n = 0; n < 4; ++n) {
        acc[m][n] = __builtin_amdgcn_mfma_f32_16x16x32_bf16(afh[m], bfh[n], acc[m][n], 0, 0, 0);
        acc[m][n] = __builtin_amdgcn_mfma_f32_16x16x32_bf16(afl[m], bfh[n], acc[m][n], 0, 0, 0);
        acc[m][n] = __builtin_amdgcn_mfma_f32_16x16x32_bf16(afh[m], bfl[n], acc[m][n], 0, 0, 0);
      }
  }

  int rbase = m0 + wr * 64 + ((l >> 4) << 2);
  int cbase = n0 + wc * 64 + (l & 15);
  #pragma unroll
  for (int n = 0; n < 4; ++n) {
    int col = cbase + n * 16;
    float bv = bias[col];
    #pragma unroll
    for (int m = 0; m < 4; ++m) {
      #pragma unroll
      for (int r = 0; r < 4; ++r) {
        int row = rbase + m * 16 + r;
        float v = acc[m][n][r] + bv;
        if constexpr (EPI == 1) v += resid[(size_t)row * N + col];
        C[(size_t)row * N + col] = v;
      }
    }
  }
}

// ---------------------------------------------------------------------------
// qkv_split: fp32 qkv [T][3][H][64] -> per-head split bf16 arrays.
// ---------------------------------------------------------------------------
__global__ __launch_bounds__(256) void qkv_split(
    const float* __restrict__ qkv,
    unsigned short* __restrict__ Qh, unsigned short* __restrict__ Ql,
    unsigned short* __restrict__ Kh, unsigned short* __restrict__ Kl,
    unsigned short* __restrict__ Vth, unsigned short* __restrict__ Vtl)
{
  __shared__ float Vt[64][68];
  int st = blockIdx.x, bh = blockIdx.y;
  int b = bh >> 4, h = bh & 15;
  int tid = threadIdx.x;
  int row = tid >> 2, cs = (tid & 3) * 16;
  size_t hb = (size_t)bh * SEQ * 64;
  int srow = st * 64 + row;
  size_t src = (size_t)(b * SEQ + srow) * 3072 + (size_t)h * HDIM + cs;

  #pragma unroll
  for (int qk = 0; qk < 2; ++qk) {
    const float* p = qkv + src + qk * 1024;
    unsigned short hi8[16], lo8[16];
    #pragma unroll
    for (int i = 0; i < 16; ++i) {
      float v = p[i];
      unsigned short hh_ = f2bf(v);
      hi8[i] = hh_; lo8[i] = f2bf(v - bf2f(hh_));
    }
    unsigned short* dh = (qk ? Kh : Qh) + hb + (size_t)srow * 64 + cs;
    unsigned short* dl = (qk ? Kl : Ql) + hb + (size_t)srow * 64 + cs;
    *(uint4v*)dh       = *(const uint4v*)&hi8[0];
    *(uint4v*)(dh + 8) = *(const uint4v*)&hi8[8];
    *(uint4v*)dl       = *(const uint4v*)&lo8[0];
    *(uint4v*)(dl + 8) = *(const uint4v*)&lo8[8];
  }
  {
    const float* p = qkv + src + 2048;
    #pragma unroll
    for (int i = 0; i < 4; ++i)
      *(f32x4*)&Vt[row][cs + i * 4] = *(const f32x4*)(p + i * 4);
  }
  __syncthreads();
  {
    int d = tid >> 2, ks = (tid & 3) * 16;
    unsigned short hi8[16], lo8[16];
    #pragma unroll
    for (int j = 0; j < 16; ++j) {
      float v = Vt[ks + j][d];
      unsigned short hh_ = f2bf(v);
      hi8[j] = hh_; lo8[j] = f2bf(v - bf2f(hh_));
    }
    size_t dst = hb + (size_t)d * SEQ + st * 64 + ks;
    *(uint4v*)(Vth + dst)     = *(const uint4v*)&hi8[0];
    *(uint4v*)(Vth + dst + 8) = *(const uint4v*)&hi8[8];
    *(uint4v*)(Vtl + dst)     = *(const uint4v*)&lo8[0];
    *(uint4v*)(Vtl + dst + 8) = *(const uint4v*)&lo8[8];
  }
}

// ---------------------------------------------------------------------------
// attn_mf3: split-bf16 MFMA flash attention, KV-parity + causal-fold.
// ---------------------------------------------------------------------------
__global__ __launch_bounds__(256) void attn_mf3(
    const unsigned short* __restrict__ Qh, const unsigned short* __restrict__ Ql,
    const unsigned short* __restrict__ Kh, const unsigned short* __restrict__ Kl,
    const unsigned short* __restrict__ Vth, const unsigned short* __restrict__ Vtl,
    float* __restrict__ paro,     // [2][TTOK][DMODEL] unnormalized o
    float* __restrict__ parml)    // [2][TTOK][NH][2]  (m, l)
{
  __shared__ unsigned short KVh[64][72], KVl[64][72];
  __shared__ unsigned short Phs[64][72], Pls[64][72];
  int bh = blockIdx.y;
  int b = bh >> 4, h = bh & 15;
  int bx = blockIdx.x;                 // 0..31
  int p  = bx >> 1, par = bx & 1;
  int tid = threadIdx.x, wv = tid >> 6, l = tid & 63;
  int lm = l & 15, lh = l >> 4;
  const size_t hb = (size_t)bh * SEQ * 64;
  int srow = tid >> 2, scs = (tid & 3) * 16;
  int qin = wv * 16 + lh * 4;          // + r = q row within tile
  const f32x4 z = {0.f, 0.f, 0.f, 0.f};

  #pragma unroll 1
  for (int job = 0; job < 2; ++job) {
    int qt = job ? (31 - p) : p;
    int q0 = qt * 64 + wv * 16;

    short8 aQh[2], aQl[2];
    {
      size_t qa = hb + (size_t)(q0 + lm) * 64 + (lh << 3);
      aQh[0] = *(const short8*)(Qh + qa);
      aQh[1] = *(const short8*)(Qh + qa + 32);
      aQl[0] = *(const short8*)(Ql + qa);
      aQl[1] = *(const short8*)(Ql + qa + 32);
    }
    f32x4 ctx[4] = {z, z, z, z};
    float mrun[4] = {-1e4f, -1e4f, -1e4f, -1e4f};
    float lrun[4] = {0.f, 0.f, 0.f, 0.f};

    for (int kt = par; kt <= qt; kt += 2) {
      uint4v vh0, vh1, vl0, vl1;
      {
        size_t vg = hb + (size_t)srow * SEQ + kt * 64 + scs;
        vh0 = *(const uint4v*)(Vth + vg);
        vh1 = *(const uint4v*)(Vth + vg + 8);
        vl0 = *(const uint4v*)(Vtl + vg);
        vl1 = *(const uint4v*)(Vtl + vg + 8);
      }
      __syncthreads();                       // prev PV reads done
      {
        size_t kg = hb + (size_t)(kt * 64 + srow) * 64 + scs;
        *(uint4v*)&KVh[srow][scs]     = *(const uint4v*)(Kh + kg);
        *(uint4v*)&KVh[srow][scs + 8] = *(const uint4v*)(Kh + kg + 8);
        *(uint4v*)&KVl[srow][scs]     = *(const uint4v*)(Kl + kg);
        *(uint4v*)&KVl[srow][scs + 8] = *(const uint4v*)(Kl + kg + 8);
      }
      __syncthreads();                       // K staged

      f32x4 S4[4] = {z, z, z, z};
      #pragma unroll
      for (int n = 0; n < 4; ++n) {
        #pragma unroll
        for (int c = 0; c < 2; ++c) {
          short8 kbh = *(const short8*)&KVh[n * 16 + lm][c * 32 + (lh << 3)];
          short8 kbl = *(const short8*)&KVl[n * 16 + lm][c * 32 + (lh << 3)];
          S4[n] = __builtin_amdgcn_mfma_f32_16x16x32_bf16(aQh[c], kbh, S4[n], 0, 0, 0);
          S4[n] = __builtin_amdgcn_mfma_f32_16x16x32_bf16(aQl[c], kbh, S4[n], 0, 0, 0);
          S4[n] = __builtin_amdgcn_mfma_f32_16x16x32_bf16(aQh[c], kbl, S4[n], 0, 0, 0);
        }
      }
      bool diag = (kt == qt);
      #pragma unroll
      for (int r = 0; r < 4; ++r) {
        float s0 = S4[0][r] * 0.125f, s1 = S4[1][r] * 0.125f;
        float s2 = S4[2][r] * 0.125f, s3 = S4[3][r] * 0.125f;
        if (diag) {
          int qq = qin + r;
          if (lm      > qq) s0 = -1e30f;
          if (16 + lm > qq) s1 = -1e30f;
          if (32 + lm > qq) s2 = -1e30f;
          if (48 + lm > qq) s3 = -1e30f;
        }
        float cm = fmaxf(fmaxf(s0, s1), fmaxf(s2, s3));
        cm = fmaxf(cm, __shfl_xor(cm, 1));
        cm = fmaxf(cm, __shfl_xor(cm, 2));
        cm = fmaxf(cm, __shfl_xor(cm, 4));
        cm = fmaxf(cm, __shfl_xor(cm, 8));
        if (cm > mrun[r] + 8.0f) {           // defer-max (THR=8)
          float sc = __expf(mrun[r] - cm);
          lrun[r] *= sc;
          ctx[0][r] *= sc; ctx[1][r] *= sc; ctx[2][r] *= sc; ctx[3][r] *= sc;
          mrun[r] = cm;
        }
        float p0 = __expf(s0 - mrun[r]), p1 = __expf(s1 - mrun[r]);
        float p2 = __expf(s2 - mrun[r]), p3 = __expf(s3 - mrun[r]);
        float rs = (p0 + p1) + (p2 + p3);
        rs += __shfl_xor(rs, 1); rs += __shfl_xor(rs, 2);
        rs += __shfl_xor(rs, 4); rs += __shfl_xor(rs, 8);
        lrun[r] += rs;
        int prow = qin + r;
        unsigned short e0 = f2bf(p0); Phs[prow][lm]      = e0; Pls[prow][lm]      = f2bf(p0 - bf2f(e0));
        unsigned short e1 = f2bf(p1); Phs[prow][16 + lm] = e1; Pls[prow][16 + lm] = f2bf(p1 - bf2f(e1));
        unsigned short e2 = f2bf(p2); Phs[prow][32 + lm] = e2; Pls[prow][32 + lm] = f2bf(p2 - bf2f(e2));
        unsigned short e3 = f2bf(p3); Phs[prow][48 + lm] = e3; Pls[prow][48 + lm] = f2bf(p3 - bf2f(e3));
      }
      __syncthreads();                       // QK^T reads of KV done
      {
        *(uint4v*)&KVh[srow][scs]     = vh0;
        *(uint4v*)&KVh[srow][scs + 8] = vh1;
        *(uint4v*)&KVl[srow][scs]     = vl0;
        *(uint4v*)&KVl[srow][scs + 8] = vl1;
      }
      __syncthreads();                       // V staged

      #pragma unroll
      for (int c = 0; c < 2; ++c) {
        short8 pah = *(const short8*)&Phs[wv * 16 + lm][c * 32 + (lh << 3)];
        short8 pal = *(const short8*)&Pls[wv * 16 + lm][c * 32 + (lh << 3)];
        #pragma unroll
        for (int n = 0; n < 4; ++n) {
          short8 vbh = *(const short8*)&KVh[n * 16 + lm][c * 32 + (lh << 3)];
          short8 vbl = *(const short8*)&KVl[n * 16 + lm][c * 32 + (lh << 3)];
          ctx[n] = __builtin_amdgcn_mfma_f32_16x16x32_bf16(pah, vbh, ctx[n], 0, 0, 0);
          ctx[n] = __builtin_amdgcn_mfma_f32_16x16x32_bf16(pal, vbh, ctx[n], 0, 0, 0);
          ctx[n] = __builtin_amdgcn_mfma_f32_16x16x32_bf16(pah, vbl, ctx[n], 0, 0, 0);
        }
      }
    }

    // write flash partials for this q-tile
    #pragma unroll
    for (int r = 0; r < 4; ++r) {
      int qg = b * SEQ + qt * 64 + wv * 16 + lh * 4 + r;
      size_t ob = ((size_t)par * TTOK + qg) * DMODEL + (size_t)h * HDIM + lm;
      #pragma unroll
      for (int n = 0; n < 4; ++n) paro[ob + n * 16] = ctx[n][r];
      if (lm == 0) {
        size_t mb = (((size_t)par * TTOK + qg) * NH + h) * 2;
        parml[mb] = mrun[r]; parml[mb + 1] = lrun[r];
      }
    }
  }
}

// ---------------------------------------------------------------------------
// attn_merge<NS>: exact flash merge of NS partials -> ctx hi/lo split.
// ---------------------------------------------------------------------------
template<int NS>
__global__ __launch_bounds__(256) void attn_merge(
    const float* __restrict__ paro,
    const float* __restrict__ parml,
    unsigned short* __restrict__ ctxh,
    unsigned short* __restrict__ ctxl)
{
  int gid = blockIdx.x * 256 + threadIdx.x;
  int ds = gid & 3;
  int h  = (gid >> 2) & 15;
  int t  = gid >> 6;
  float m[NS], lv[NS];
  float mx = -1e30f;
  #pragma unroll
  for (int i = 0; i < NS; ++i) {
    size_t mb = (((size_t)i * TTOK + t) * NH + h) * 2;
    m[i] = parml[mb]; lv[i] = parml[mb + 1];
    mx = fmaxf(mx, m[i]);
  }
  float w[NS], lsum = 0.f;
  #pragma unroll
  for (int i = 0; i < NS; ++i) { w[i] = __expf(m[i] - mx); lsum += lv[i] * w[i]; }
  float inv = 1.0f / lsum;
  size_t ob = (size_t)t * DMODEL + (size_t)h * HDIM + ds * 16;
  #pragma unroll
  for (int i4 = 0; i4 < 4; ++i4) {
    f32x4 v = {0.f, 0.f, 0.f, 0.f};
    #pragma unroll
    for (int i = 0; i < NS; ++i) {
      const f32x4* oi = (const f32x4*)(paro + (size_t)i * TTOK * DMODEL + ob);
      v += oi[i4] * w[i];
    }
    v = v * inv;
    ushort4 hi, lo;
    unsigned short e0 = f2bf(v[0]); hi.x = e0; lo.x = f2bf(v[0] - bf2f(e0));
    unsigned short e1 = f2bf(v[1]); hi.y = e1; lo.y = f2bf(v[1] - bf2f(e1));
    unsigned short e2 = f2bf(v[2]); hi.z = e2; lo.z = f2bf(v[2] - bf2f(e2));
    unsigned short e3 = f2bf(v[3]); hi.w = e3; lo.w = f2bf(v[3] - bf2f(e3));
    *(ushort4*)(ctxh + ob + i4 * 4) = hi;
    *(ushort4*)(ctxl + ob + i4 * 4) = lo;
  }
}

// ---------------------------------------------------------------------------
// Router (fp32)
// ---------------------------------------------------------------------------
__global__ __launch_bounds__(256) void router_kernel(
    const float* __restrict__ x1,
    const float* __restrict__ gam,
    const float* __restrict__ bet,
    const float* __restrict__ wrt,
    int* __restrict__ ctrl,
    int2* __restrict__ t_e,
    float2* __restrict__ t_g)
{
  int w = threadIdx.x >> 6, l = threadIdx.x & 63;
  int t = blockIdx.x * 4 + w;
  const f32x4* row = (const f32x4*)(x1 + (size_t)t * DMODEL);
  f32x4 v[4];
  float s = 0.f, sq = 0.f;
  #pragma unroll
  for (int i = 0; i < 4; ++i) {
    v[i] = row[l + i * 64];
    #pragma unroll
    for (int j = 0; j < 4; ++j) { s += v[i][j]; sq += v[i][j] * v[i][j]; }
  }
  #pragma unroll
  for (int off = 1; off < 64; off <<= 1) {
    s  += __shfl_xor(s, off);
    sq += __shfl_xor(sq, off);
  }
  float mu  = s * (1.0f / DMODEL);
  float var = sq * (1.0f / DMODEL) - mu * mu;
  float rs  = rsqrtf(var + 1e-5f);

  float acc[NE] = {0.f, 0.f, 0.f, 0.f, 0.f, 0.f, 0.f, 0.f};
  #pragma unroll
  for (int i = 0; i < 4; ++i) {
    int base = (l + i * 64) * 4;
    #pragma unroll
    for (int j = 0; j < 4; ++j) {
      int idx = base + j;
      float xn = (v[i][j] - mu) * rs * gam[idx] + bet[idx];
      const f32x4* wr0 = (const f32x4*)(wrt + idx * NE);
      f32x4 w0 = wr0[0], w1v = wr0[1];
      acc[0] += xn * w0[0]; acc[1] += xn * w0[1];
      acc[2] += xn * w0[2]; acc[3] += xn * w0[3];
      acc[4] += xn * w1v[0]; acc[5] += xn * w1v[1];
      acc[6] += xn * w1v[2]; acc[7] += xn * w1v[3];
    }
  }
  #pragma unroll
  for (int e = 0; e < NE; ++e) {
    #pragma unroll
    for (int off = 1; off < 64; off <<= 1) acc[e] += __shfl_xor(acc[e], off);
  }
  if (l == 0) {
    int e0 = 0; float m0v = acc[0];
    #pragma unroll
    for (int e = 1; e < NE; ++e) if (acc[e] > m0v) { m0v = acc[e]; e0 = e; }
    int e1 = -1; float m1v = -1e30f;
    #pragma unroll
    for (int e = 0; e < NE; ++e) if (e != e0 && acc[e] > m1v) { m1v = acc[e]; e1 = e; }
    float r = __expf(m1v - m0v);
    float g0 = 1.0f / (1.0f + r);
    float g1 = r * g0;
    t_e[t] = make_int2(e0, e1);
    t_g[t] = make_float2(g0, g1);
    atomicAdd(&ctrl[C_CNT + e0], 1);
    atomicAdd(&ctrl[C_CNT + e1], 1);
  }
}

// ---------------------------------------------------------------------------
// Scan: 256-padded per-expert slot bases + 256-row m-tile table.
// ---------------------------------------------------------------------------
__global__ void scan_kernel(int* __restrict__ ctrl)
{
  if (threadIdx.x == 0 && blockIdx.x == 0) {
    int b = 0, m = 0;
    for (int e = 0; e < NE; ++e) {
      ctrl[C_BASE + e] = b;
      int pc = (ctrl[C_CNT + e] + 255) & ~255;
      int nt = pc >> 8;
      for (int i = 0; i < nt; ++i) {
        ctrl[C_MTE + m] = e;
        ctrl[C_MTS + m] = b + (i << 8);
        ++m;
      }
      b += pc;
    }
    ctrl[C_NMT] = m;
  }
}

// ---------------------------------------------------------------------------
__global__ __launch_bounds__(256) void gather_kernel(
    int* __restrict__ ctrl,
    const int2* __restrict__ t_e,
    const float2* __restrict__ t_g,
    int* __restrict__ slot_token,
    float* __restrict__ slot_gate)
{
  int t = blockIdx.x * 256 + threadIdx.x;
  int2 e = t_e[t];
  float2 g = t_g[t];
  int p0 = atomicAdd(&ctrl[C_FILL + e.x], 1);
  int s0 = ctrl[C_BASE + e.x] + p0;
  slot_token[s0] = t; slot_gate[s0] = g.x;
  int p1 = atomicAdd(&ctrl[C_FILL + e.y], 1);
  int s1 = ctrl[C_BASE + e.y] + p1;
  slot_token[s1] = t; slot_gate[s1] = g.y;
}

// ---------------------------------------------------------------------------
// Transpose + fp32->bf16: in [E][K][N] fp32 -> out [E][N][K] bf16.
// ---------------------------------------------------------------------------
__global__ __launch_bounds__(256) void transpose_conv(
    const float* __restrict__ in, unsigned short* __restrict__ outb,
    unsigned short* __restrict__ outlo, int K, int N)
{
  __shared__ float T[64][68];
  int e = blockIdx.z;
  int n0 = blockIdx.x * 64, k0 = blockIdx.y * 64;
  const float* src = in + (size_t)e * K * N;
  unsigned short* dst = outb + (size_t)e * K * N;
  unsigned short* dstl = outlo ? outlo + (size_t)e * K * N : nullptr;
  int tid = threadIdx.x;
  int r = tid >> 4, c4 = (tid & 15) * 4;
  #pragma unroll
  for (int i = 0; i < 4; ++i) {
    f32x4 v = *(const f32x4*)(src + (size_t)(k0 + r + i * 16) * N + n0 + c4);
    *(f32x4*)(&T[r + i * 16][c4]) = v;
  }
  __syncthreads();
  #pragma unroll
  for (int i = 0; i < 4; ++i) {
    int rr = r + i * 16;
    float v0 = T[c4 + 0][rr], v1 = T[c4 + 1][rr];
    float v2 = T[c4 + 2][rr], v3 = T[c4 + 3][rr];
    ushort4 o;
    o.x = f2bf(v0); o.y = f2bf(v1); o.z = f2bf(v2); o.w = f2bf(v3);
    *(ushort4*)(dst + (size_t)(n0 + rr) * K + k0 + c4) = o;
    if (dstl) {
      ushort4 lo;
      lo.x = f2bf(v0 - bf2f(o.x));
      lo.y = f2bf(v1 - bf2f(o.y));
      lo.z = f2bf(v2 - bf2f(o.z));
      lo.w = f2bf(v3 - bf2f(o.w));
      *(ushort4*)(dstl + (size_t)(n0 + rr) * K + k0 + c4) = lo;
    }
  }
}

// ---------------------------------------------------------------------------
// Sparse MoE w1, BM=256: Hs[slot] = gelu(h2[token(slot)] @ w1t[e]^T + b1[e]).
// Grid (MT_MAX, DFF/128): x = m-tile (XCD-grouped: gridDim.x % 8 == 0).
// ---------------------------------------------------------------------------
__global__ __launch_bounds__(256) void moe_w1g(
    const unsigned short* __restrict__ h2,
    const unsigned short* __restrict__ w1t,
    const float* __restrict__ b1,
    const int* __restrict__ ctrl,
    const int* __restrict__ slot_token,
    unsigned short* __restrict__ Hs)
{
  int mt = blockIdx.x;
  if (mt >= ctrl[C_NMT]) return;
  int e = ctrl[C_MTE + mt];
  int slot0 = ctrl[C_MTS + mt];
  const int N = DFF, K = DMODEL;
  const unsigned short* Bt = w1t + (size_t)e * K * N;
  const float* bias = b1 + (size_t)e * DFF;

  __shared__ unsigned short Al[256][32];
  __shared__ unsigned short Bl[128][32];
  __shared__ int tokrow[256];
  int tid = threadIdx.x;
  {
    int tk = slot_token[slot0 + tid];
    tokrow[tid] = tk < 0 ? 0 : tk;
  }
  __syncthreads();
  int l = tid & 63, wv = tid >> 6;
  int wr = wv >> 1, wc = wv & 1;
  int n0 = blockIdx.y * 128;
  int rsub = l >> 2, csub = (l & 3) * 8;
  const unsigned short* ga[4];
  #pragma unroll
  for (int j = 0; j < 4; ++j)
    ga[j] = h2 + (size_t)tokrow[wv * 64 + rsub + 16 * j] * DMODEL + csub;
  const unsigned short* gb0 = Bt + (size_t)(n0 + wv * 32 + rsub) * K + csub;
  const unsigned short* gb1 = Bt + (size_t)(n0 + wv * 32 + 16 + rsub) * K + csub;

  const f32x4 z = {0.f, 0.f, 0.f, 0.f};
  f32x4 acc[2][4][4];
  #pragma unroll
  for (int hh = 0; hh < 2; ++hh)
    #pragma unroll
    for (int i = 0; i < 4; ++i)
      #pragma unroll
      for (int j = 0; j < 4; ++j) acc[hh][i][j] = z;

  for (int k0 = 0; k0 < K; k0 += 32) {
    __syncthreads();
    #pragma unroll
    for (int j = 0; j < 4; ++j)
      gl_lds16(ga[j] + k0, &Al[wv * 64 + 16 * j][0]);
    gl_lds16(gb0 + k0, &Bl[wv * 32][0]);
    gl_lds16(gb1 + k0, &Bl[wv * 32 + 16][0]);
    __syncthreads();

    short8 af0[4], af1[4], bfr[4];
    #pragma unroll
    for (int m = 0; m < 4; ++m) {
      af0[m] = *(const short8*)(&Al[wr * 64 + m * 16 + (l & 15)][(l >> 4) << 3]);
      af1[m] = *(const short8*)(&Al[128 + wr * 64 + m * 16 + (l & 15)][(l >> 4) << 3]);
    }
    #pragma unroll
    for (int n = 0; n < 4; ++n)
      bfr[n] = *(const short8*)(&Bl[wc * 64 + n * 16 + (l & 15)][(l >> 4) << 3]);
    #pragma unroll
    for (int m = 0; m < 4; ++m)
      #pragma unroll
      for (int n = 0; n < 4; ++n) {
        acc[0][m][n] = __builtin_amdgcn_mfma_f32_16x16x32_bf16(af0[m], bfr[n], acc[0][m][n], 0, 0, 0);
        acc[1][m][n] = __builtin_amdgcn_mfma_f32_16x16x32_bf16(af1[m], bfr[n], acc[1][m][n], 0, 0, 0);
      }
  }

  int cbase = n0 + wc * 64 + (l & 15);
  #pragma unroll
  for (int hh = 0; hh < 2; ++hh) {
    int rbase = hh * 128 + wr * 64 + ((l >> 4) << 2);
    #pragma unroll
    for (int n = 0; n < 4; ++n) {
      int col = cbase + n * 16;
      float bv = bias[col];
      #pragma unroll
      for (int m = 0; m < 4; ++m) {
        #pragma unroll
        for (int r = 0; r < 4; ++r) {
          int srow = slot0 + rbase + m * 16 + r;
          float v = acc[hh][m][n][r] + bv;
          v = 0.5f * v * (1.0f + erff(v * 0.70710678118654752f));
          Hs[(size_t)srow * DFF + col] = f2bf(v);
        }
      }
    }
  }
}

// ---------------------------------------------------------------------------
// Sparse MoE w2, BM=256: ffn[token] += gate * (Hs[slot] @ w2t[e]^T + b2[e]).
// Grid (MT_MAX, DMODEL/128): x = m-tile (XCD-grouped).
// ---------------------------------------------------------------------------
__global__ __launch_bounds__(256) void moe_w2g(
    const unsigned short* __restrict__ Hs,
    const unsigned short* __restrict__ w2t,
    const float* __restrict__ b2,
    const int* __restrict__ ctrl,
    const int* __restrict__ slot_token,
    const float* __restrict__ slot_gate,
    float* __restrict__ ffn)
{
  int mt = blockIdx.x;
  if (mt >= ctrl[C_NMT]) return;
  int e = ctrl[C_MTE + mt];
  int slot0 = ctrl[C_MTS + mt];
  const int N = DMODEL, K = DFF;
  const unsigned short* Bt = w2t + (size_t)e * (size_t)K * N;
  const float* bias = b2 + (size_t)e * DMODEL;

  __shared__ unsigned short Al[256][32];
  __shared__ unsigned short Bl[128][32];
  int tid = threadIdx.x;
  int l = tid & 63, wv = tid >> 6;
  int wr = wv >> 1, wc = wv & 1;
  int n0 = blockIdx.y * 128;
  int rsub = l >> 2, csub = (l & 3) * 8;
  const unsigned short* ga[4];
  #pragma unroll
  for (int j = 0; j < 4; ++j)
    ga[j] = Hs + (size_t)(slot0 + wv * 64 + rsub + 16 * j) * DFF + csub;
  const unsigned short* gb0 = Bt + (size_t)(n0 + wv * 32 + rsub) * K + csub;
  const unsigned short* gb1 = Bt + (size_t)(n0 + wv * 32 + 16 + rsub) * K + csub;

  const f32x4 z = {0.f, 0.f, 0.f, 0.f};
  f32x4 acc[2][4][4];
  #pragma unroll
  for (int hh = 0; hh < 2; ++hh)
    #pragma unroll
    for (int i = 0; i < 4; ++i)
      #pragma unroll
      for (int j = 0; j < 4; ++j) acc[hh][i][j] = z;

  for (int k0 = 0; k0 < K; k0 += 32) {
    __syncthreads();
    #pragma unroll
    for (int j = 0; j < 4; ++j)
      gl_lds16(ga[j] + k0, &Al[wv * 64 + 16 * j][0]);
    gl_lds16(gb0 + k0, &Bl[wv * 32][0]);
    gl_lds16(gb1 + k0, &Bl[wv * 32 + 16][0]);
    __syncthreads();

    short8 af0[4], af1[4], bfr[4];
    #pragma unroll
    for (int m = 0; m < 4; ++m) {
      af0[m] = *(const short8*)(&Al[wr * 64 + m * 16 + (l & 15)][(l >> 4) << 3]);
      af1[m] = *(const short8*)(&Al[128 + wr * 64 + m * 16 + (l & 15)][(l >> 4) << 3]);
    }
    #pragma unroll
    for (int n = 0; n < 4; ++n)
      bfr[n] = *(const short8*)(&Bl[wc * 64 + n * 16 + (l & 15)][(l >> 4) << 3]);
    #pragma unroll
    for (int m = 0; m < 4; ++m)
      #pragma unroll
      for (int n = 0; n < 4; ++n) {
        acc[0][m][n] = __builtin_amdgcn_mfma_f32_16x16x32_bf16(af0[m], bfr[n], acc[0][m][n], 0, 0, 0);
        acc[1][m][n] = __builtin_amdgcn_mfma_f32_16x16x32_bf16(af1[m], bfr[n], acc[1][m][n], 0, 0, 0);
      }
  }

  int cbase = n0 + wc * 64 + (l & 15);
  #pragma unroll
  for (int hh = 0; hh < 2; ++hh) {
    int rbase = hh * 128 + wr * 64 + ((l >> 4) << 2);
    #pragma unroll
    for (int n = 0; n < 4; ++n) {
      int col = cbase + n * 16;
      float bv = bias[col];
      #pragma unroll
      for (int m = 0; m < 4; ++m) {
        #pragma unroll
        for (int r = 0; r < 4; ++r) {
          int srow = slot0 + rbase + m * 16 + r;
          int tok = slot_token[srow];
          if (tok >= 0) {
            float v = acc[hh][m][n][r] + bv;
            atomicAdd(&ffn[(size_t)tok * DMODEL + col], slot_gate[srow] * v);
          }
        }
      }
    }
  }
}

// ---------------------------------------------------------------------------
__global__ __launch_bounds__(256) void final_add(
    const float* __restrict__ x1,
    const float* __restrict__ ffn,
    float* __restrict__ out)
{
  int i = blockIdx.x * 256 + threadIdx.x;
  f32x4 xr = ((const f32x4*)x1)[i];
  f32x4 fr = ((const f32x4*)ffn)[i];
  f32x4 o;
  o[0] = xr[0] + fr[0];
  o[1] = xr[1] + fr[1];
  o[2] = xr[2] + fr[2];
  o[3] = xr[3] + fr[3];
  ((f32x4*)out)[i] = o;
}

// ---------------------------------------------------------------------------
extern "C" void kernel_launch(void* const* d_in, const int* in_sizes, int n_in,
                              void* d_out, int out_size, void* d_ws, size_t ws_size,
                              hipStream_t stream) {
  (void)in_sizes; (void)n_in; (void)out_size;
  const float* x     = (const float*)d_in[0];
  const float* ln1_g = (const float*)d_in[1];
  const float* ln1_b = (const float*)d_in[2];
  const float* ln2_g = (const float*)d_in[3];
  const float* ln2_b = (const float*)d_in[4];
  const float* wqkv  = (const float*)d_in[5];
  const float* bqkv  = (const float*)d_in[6];
  const float* wo    = (const float*)d_in[7];
  const float* bo    = (const float*)d_in[8];
  const float* wrt   = (const float*)d_in[9];
  const float* w1    = (const float*)d_in[10];
  const float* b1    = (const float*)d_in[11];
  const float* w2    = (const float*)d_in[12];
  const float* b2    = (const float*)d_in[13];
  float* out = (float*)d_out;

  char* ws = (char*)d_ws;
  size_t off = 0;
  auto alloc = [&](size_t bytes) -> void* {
    void* p = ws + off;
    off += (bytes + 255) & ~(size_t)255;
    return p;
  };
  float*          x1    = (float*)alloc((size_t)TTOK * DMODEL * 4);
  unsigned short* h2    = (unsigned short*)alloc((size_t)TTOK * DMODEL * 2);
  int*            ctrl  = (int*)alloc(1024);
  int2*           t_e   = (int2*)alloc((size_t)TTOK * 8);
  float2*         t_g   = (float2*)alloc((size_t)TTOK * 8);
  int*            slot_token = (int*)alloc((size_t)SLOT_MAX * 4);
  float*          slot_gate  = (float*)alloc((size_t)SLOT_MAX * 4);
  float*          P1    = (float*)alloc((size_t)TTOK * DMODEL * 4);
  char*           P2    = (char*)alloc((size_t)SLOT_MAX * DFF * 2);
  unsigned short* w1t   = (unsigned short*)alloc((size_t)NE * DMODEL * DFF * 2);
  unsigned short* w2t   = (unsigned short*)alloc((size_t)NE * DFF * DMODEL * 2);
  unsigned short* wqkvTh = (unsigned short*)alloc((size_t)DMODEL * 3 * DMODEL * 2);
  unsigned short* wqkvTl = (unsigned short*)alloc((size_t)DMODEL * 3 * DMODEL * 2);
  unsigned short* woTh  = (unsigned short*)alloc((size_t)DMODEL * DMODEL * 2);
  unsigned short* woTl  = (unsigned short*)alloc((size_t)DMODEL * DMODEL * 2);
  unsigned short* hh    = (unsigned short*)alloc((size_t)TTOK * DMODEL * 2);
  unsigned short* hl    = (unsigned short*)alloc((size_t)TTOK * DMODEL * 2);
  unsigned short* ctxh  = (unsigned short*)alloc((size_t)TTOK * DMODEL * 2);
  unsigned short* ctxl  = (unsigned short*)alloc((size_t)TTOK * DMODEL * 2);
  // MFMA attention split-qkv arrays + flash partials
  size_t headsz = (size_t)NB * NH * SEQ * HDIM;   // elems per array
  unsigned short* Qh  = (unsigned short*)alloc(headsz * 2);
  unsigned short* Ql  = (unsigned short*)alloc(headsz * 2);
  unsigned short* Khp = (unsigned short*)alloc(headsz * 2);
  unsigned short* Klp = (unsigned short*)alloc(headsz * 2);
  unsigned short* Vth = (unsigned short*)alloc(headsz * 2);
  unsigned short* Vtl = (unsigned short*)alloc(headsz * 2);
  float*          paro2  = (float*)alloc((size_t)2 * TTOK * DMODEL * 4);
  float*          parml2 = (float*)alloc((size_t)2 * TTOK * NH * 2 * 4);

  float*          qkv  = (float*)P2;        // dead before Hs is written
  float*          ffn  = P1;
  unsigned short* Hs   = (unsigned short*)P2;

  // 0) zero control counters, mark all slots invalid
  hipMemsetAsync(ctrl, 0, 16 * 4, stream);
  hipMemsetAsync(slot_token, 0xFF, (size_t)SLOT_MAX * 4, stream);

  // 0b) weight prep
  transpose_conv<<<dim3(DFF / 64, DMODEL / 64, NE), 256, 0, stream>>>(
      w1, w1t, nullptr, DMODEL, DFF);
  transpose_conv<<<dim3(DMODEL / 64, DFF / 64, NE), 256, 0, stream>>>(
      w2, w2t, nullptr, DFF, DMODEL);
  transpose_conv<<<dim3(3 * DMODEL / 64, DMODEL / 64, 1), 256, 0, stream>>>(
      wqkv, wqkvTh, wqkvTl, DMODEL, 3 * DMODEL);
  transpose_conv<<<dim3(DMODEL / 64, DMODEL / 64, 1), 256, 0, stream>>>(
      wo, woTh, woTl, DMODEL, DMODEL);

  // 1) h = LN1(x) -> split hi/lo
  ln_kernel<2><<<TTOK, 256, 0, stream>>>(x, ln1_g, ln1_b, nullptr, hh, hl);
  // 2) qkv = h @ wqkv + bqkv   (split-bf16 MFMA, fp32-grade)
  mgemm_split<0><<<dim3(3 * DMODEL / 128, TTOK / 128), 256, 0, stream>>>(
      hh, hl, wqkvTh, wqkvTl, bqkv, nullptr, qkv, TTOK, 3 * DMODEL, DMODEL);
  // 3) ctx = causal attention (split-bf16 MFMA flash, parity+fold) -> merge
  qkv_split<<<dim3(SEQ / 64, NB * NH), 256, 0, stream>>>(
      qkv, Qh, Ql, Khp, Klp, Vth, Vtl);
  attn_mf3<<<dim3(32, NB * NH), 256, 0, stream>>>(
      Qh, Ql, Khp, Klp, Vth, Vtl, paro2, parml2);
  attn_merge<2><<<(TTOK * NH * 4) / 256, 256, 0, stream>>>(
      paro2, parml2, ctxh, ctxl);
  // 4) x1 = x + ctx @ wo + bo  (split-bf16 MFMA)
  mgemm_split<1><<<dim3(DMODEL / 128, TTOK / 128), 256, 0, stream>>>(
      ctxh, ctxl, woTh, woTl, bo, x, x1, TTOK, DMODEL, DMODEL);

  // 5) h2 = LN2(x1)
  ln_kernel<1><<<TTOK, 256, 0, stream>>>(x1, ln2_g, ln2_b, nullptr, h2, nullptr);
  // 6) router -> scan -> gather
  router_kernel<<<TTOK / 4, 256, 0, stream>>>(x1, ln2_g, ln2_b, wrt, ctrl, t_e, t_g);
  scan_kernel<<<1, 64, 0, stream>>>(ctrl);
  gather_kernel<<<TTOK / 256, 256, 0, stream>>>(ctrl, t_e, t_g, slot_token, slot_gate);
  // 7) sparse MoE (BM=256 tiles; grid.x = m-tile, gridDim.x % 8 == 0 so all
  //    n-blocks of one m-tile share an XCD -> A-tile L2 reuse)
  hipMemsetAsync(ffn, 0, (size_t)TTOK * DMODEL * 4, stream);
  moe_w1g<<<dim3(MT_MAX, DFF / 128), 256, 0, stream>>>(
      h2, w1t, b1, ctrl, slot_token, Hs);
  moe_w2g<<<dim3(MT_MAX, DMODEL / 128), 256, 0, stream>>>(
      Hs, w2t, b2, ctrl, slot_token, slot_gate, ffn);
  // 8) out = x1 + ffn
  final_add<<<(TTOK * DMODEL / 4) / 256, 256, 0, stream>>>(x1, ffn, out);
}

// Round 17
// 1226.182 us; speedup vs baseline: 1.0095x; 1.0095x over previous
//
#include <hip/hip_runtime.h>
#include <hip/hip_bf16.h>
#include <math.h>

// Problem constants
#define NB    2
#define SEQ   2048
#define DMODEL 1024
#define NH    16
#define HDIM  64
#define NE    8
#define DFF   4096
#define TTOK  4096   // NB*SEQ

#define MT_MAX   40     // 256-row m-tiles: sum ceil(cnt_e/256) <= 32+8
#define SLOT_MAX 10240  // 8192 + 8*255 padded, rounded

// ctrl block layout (ints)
#define C_CNT  0
#define C_FILL 8
#define C_BASE 16
#define C_NMT  24
#define C_MTE  32
#define C_MTS  80

typedef __attribute__((ext_vector_type(8))) short short8;
typedef __attribute__((ext_vector_type(4))) float f32x4;
typedef __attribute__((ext_vector_type(4))) unsigned int uint4v;

static __device__ __forceinline__ float bf2f(unsigned short u) {
  union { unsigned int i; float f; } c; c.i = ((unsigned int)u) << 16; return c.f;
}
static __device__ __forceinline__ unsigned short f2bf(float f) {
  unsigned int x = __float_as_uint(f);
  unsigned int r = (x + 0x7FFFu + ((x >> 16) & 1u)) >> 16;
  return (unsigned short)r;
}

// Async global->LDS, 16B per lane. LDS dest is WAVE-UNIFORM base + lane*16.
static __device__ __forceinline__ void gl_lds16(const void* g, void* l) {
  __builtin_amdgcn_global_load_lds(
      (const __attribute__((address_space(1))) unsigned int*)(uintptr_t)g,
      (__attribute__((address_space(3))) unsigned int*)(uintptr_t)l,
      16, 0, 0);
}

// ---------------------------------------------------------------------------
// LayerNorm. MODE 0: fp32 out. MODE 1: bf16 out. MODE 2: split hi/lo bf16.
// ---------------------------------------------------------------------------
template<int MODE>
__global__ __launch_bounds__(256) void ln_kernel(
    const float* __restrict__ x,
    const float* __restrict__ gam,
    const float* __restrict__ bet,
    float* __restrict__ outf,
    unsigned short* __restrict__ outb,
    unsigned short* __restrict__ outlo)
{
  int t = blockIdx.x, tid = threadIdx.x;
  f32x4 v = ((const f32x4*)(x + (size_t)t * DMODEL))[tid];
  float s  = v[0] + v[1] + v[2] + v[3];
  float sq = v[0]*v[0] + v[1]*v[1] + v[2]*v[2] + v[3]*v[3];
  #pragma unroll
  for (int off = 1; off < 64; off <<= 1) {
    s  += __shfl_xor(s, off);
    sq += __shfl_xor(sq, off);
  }
  __shared__ float red[8];
  int w = tid >> 6, l = tid & 63;
  if (l == 0) { red[w] = s; red[4 + w] = sq; }
  __syncthreads();
  s  = red[0] + red[1] + red[2] + red[3];
  sq = red[4] + red[5] + red[6] + red[7];
  float mu  = s * (1.0f / DMODEL);
  float var = sq * (1.0f / DMODEL) - mu * mu;
  float rs  = rsqrtf(var + 1e-5f);
  f32x4 g = ((const f32x4*)gam)[tid];
  f32x4 b = ((const f32x4*)bet)[tid];
  float r[4];
  r[0] = (v[0] - mu) * rs * g[0] + b[0];
  r[1] = (v[1] - mu) * rs * g[1] + b[1];
  r[2] = (v[2] - mu) * rs * g[2] + b[2];
  r[3] = (v[3] - mu) * rs * g[3] + b[3];
  if constexpr (MODE == 0) {
    f32x4 o = {r[0], r[1], r[2], r[3]};
    ((f32x4*)(outf + (size_t)t * DMODEL))[tid] = o;
  } else if constexpr (MODE == 1) {
    ushort4 o; o.x = f2bf(r[0]); o.y = f2bf(r[1]); o.z = f2bf(r[2]); o.w = f2bf(r[3]);
    ((ushort4*)(outb + (size_t)t * DMODEL))[tid] = o;
  } else {
    ushort4 hi, lo;
    unsigned short h0 = f2bf(r[0]); hi.x = h0; lo.x = f2bf(r[0] - bf2f(h0));
    unsigned short h1 = f2bf(r[1]); hi.y = h1; lo.y = f2bf(r[1] - bf2f(h1));
    unsigned short h2 = f2bf(r[2]); hi.z = h2; lo.z = f2bf(r[2] - bf2f(h2));
    unsigned short h3 = f2bf(r[3]); hi.w = h3; lo.w = f2bf(r[3] - bf2f(h3));
    ((ushort4*)(outb  + (size_t)t * DMODEL))[tid] = hi;
    ((ushort4*)(outlo + (size_t)t * DMODEL))[tid] = lo;
  }
}

// ---------------------------------------------------------------------------
// Split-bf16 MFMA GEMM (fp32-grade): C = (Ah+Al)(Bh+Bl) + bias [+resid].
// ---------------------------------------------------------------------------
template<int EPI>
__global__ __launch_bounds__(256) void mgemm_split(
    const unsigned short* __restrict__ Ah,
    const unsigned short* __restrict__ Alo,
    const unsigned short* __restrict__ Bth,
    const unsigned short* __restrict__ Btl,
    const float* __restrict__ bias,
    const float* __restrict__ resid,
    float* __restrict__ C, int M, int N, int K)
{
  __shared__ unsigned short AH[128][32];
  __shared__ unsigned short AL[128][32];
  __shared__ unsigned short BH[128][32];
  __shared__ unsigned short BL[128][32];
  int tid = threadIdx.x;
  int l = tid & 63, wv = tid >> 6;
  int wr = wv >> 1, wc = wv & 1;
  int m0 = blockIdx.y * 128, n0 = blockIdx.x * 128;
  int rsub = l >> 2, csub = (l & 3) * 8;
  int row0 = wv * 32 + rsub, row1 = row0 + 16;

  const unsigned short* gah0 = Ah  + (size_t)(m0 + row0) * K + csub;
  const unsigned short* gah1 = Ah  + (size_t)(m0 + row1) * K + csub;
  const unsigned short* gal0 = Alo + (size_t)(m0 + row0) * K + csub;
  const unsigned short* gal1 = Alo + (size_t)(m0 + row1) * K + csub;
  const unsigned short* gbh0 = Bth + (size_t)(n0 + row0) * K + csub;
  const unsigned short* gbh1 = Bth + (size_t)(n0 + row1) * K + csub;
  const unsigned short* gbl0 = Btl + (size_t)(n0 + row0) * K + csub;
  const unsigned short* gbl1 = Btl + (size_t)(n0 + row1) * K + csub;

  const f32x4 z = {0.f, 0.f, 0.f, 0.f};
  f32x4 acc[4][4];
  #pragma unroll
  for (int i = 0; i < 4; ++i)
    #pragma unroll
    for (int j = 0; j < 4; ++j) acc[i][j] = z;

  for (int k0 = 0; k0 < K; k0 += 32) {
    __syncthreads();
    gl_lds16(gah0 + k0, &AH[wv * 32][0]);
    gl_lds16(gah1 + k0, &AH[wv * 32 + 16][0]);
    gl_lds16(gal0 + k0, &AL[wv * 32][0]);
    gl_lds16(gal1 + k0, &AL[wv * 32 + 16][0]);
    gl_lds16(gbh0 + k0, &BH[wv * 32][0]);
    gl_lds16(gbh1 + k0, &BH[wv * 32 + 16][0]);
    gl_lds16(gbl0 + k0, &BL[wv * 32][0]);
    gl_lds16(gbl1 + k0, &BL[wv * 32 + 16][0]);
    __syncthreads();

    short8 afh[4], afl[4], bfh[4], bfl[4];
    #pragma unroll
    for (int m = 0; m < 4; ++m) {
      afh[m] = *(const short8*)(&AH[wr * 64 + m * 16 + (l & 15)][(l >> 4) << 3]);
      afl[m] = *(const short8*)(&AL[wr * 64 + m * 16 + (l & 15)][(l >> 4) << 3]);
    }
    #pragma unroll
    for (int n = 0; n < 4; ++n) {
      bfh[n] = *(const short8*)(&BH[wc * 64 + n * 16 + (l & 15)][(l >> 4) << 3]);
      bfl[n] = *(const short8*)(&BL[wc * 64 + n * 16 + (l & 15)][(l >> 4) << 3]);
    }
    #pragma unroll
    for (int m = 0; m < 4; ++m)
      #pragma unroll
      for (int n = 0; n < 4; ++n) {
        acc[m][n] = __builtin_amdgcn_mfma_f32_16x16x32_bf16(afh[m], bfh[n], acc[m][n], 0, 0, 0);
        acc[m][n] = __builtin_amdgcn_mfma_f32_16x16x32_bf16(afl[m], bfh[n], acc[m][n], 0, 0, 0);
        acc[m][n] = __builtin_amdgcn_mfma_f32_16x16x32_bf16(afh[m], bfl[n], acc[m][n], 0, 0, 0);
      }
  }

  int rbase = m0 + wr * 64 + ((l >> 4) << 2);
  int cbase = n0 + wc * 64 + (l & 15);
  #pragma unroll
  for (int n = 0; n < 4; ++n) {
    int col = cbase + n * 16;
    float bv = bias[col];
    #pragma unroll
    for (int m = 0; m < 4; ++m) {
      #pragma unroll
      for (int r = 0; r < 4; ++r) {
        int row = rbase + m * 16 + r;
        float v = acc[m][n][r] + bv;
        if constexpr (EPI == 1) v += resid[(size_t)row * N + col];
        C[(size_t)row * N + col] = v;
      }
    }
  }
}

// ---------------------------------------------------------------------------
// qkv_split: fp32 qkv [T][3][H][64] -> per-head split bf16 arrays.
// ---------------------------------------------------------------------------
__global__ __launch_bounds__(256) void qkv_split(
    const float* __restrict__ qkv,
    unsigned short* __restrict__ Qh, unsigned short* __restrict__ Ql,
    unsigned short* __restrict__ Kh, unsigned short* __restrict__ Kl,
    unsigned short* __restrict__ Vth, unsigned short* __restrict__ Vtl)
{
  __shared__ float Vt[64][68];
  int st = blockIdx.x, bh = blockIdx.y;
  int b = bh >> 4, h = bh & 15;
  int tid = threadIdx.x;
  int row = tid >> 2, cs = (tid & 3) * 16;
  size_t hb = (size_t)bh * SEQ * 64;
  int srow = st * 64 + row;
  size_t src = (size_t)(b * SEQ + srow) * 3072 + (size_t)h * HDIM + cs;

  #pragma unroll
  for (int qk = 0; qk < 2; ++qk) {
    const float* p = qkv + src + qk * 1024;
    unsigned short hi8[16], lo8[16];
    #pragma unroll
    for (int i = 0; i < 16; ++i) {
      float v = p[i];
      unsigned short hh_ = f2bf(v);
      hi8[i] = hh_; lo8[i] = f2bf(v - bf2f(hh_));
    }
    unsigned short* dh = (qk ? Kh : Qh) + hb + (size_t)srow * 64 + cs;
    unsigned short* dl = (qk ? Kl : Ql) + hb + (size_t)srow * 64 + cs;
    *(uint4v*)dh       = *(const uint4v*)&hi8[0];
    *(uint4v*)(dh + 8) = *(const uint4v*)&hi8[8];
    *(uint4v*)dl       = *(const uint4v*)&lo8[0];
    *(uint4v*)(dl + 8) = *(const uint4v*)&lo8[8];
  }
  {
    const float* p = qkv + src + 2048;
    #pragma unroll
    for (int i = 0; i < 4; ++i)
      *(f32x4*)&Vt[row][cs + i * 4] = *(const f32x4*)(p + i * 4);
  }
  __syncthreads();
  {
    int d = tid >> 2, ks = (tid & 3) * 16;
    unsigned short hi8[16], lo8[16];
    #pragma unroll
    for (int j = 0; j < 16; ++j) {
      float v = Vt[ks + j][d];
      unsigned short hh_ = f2bf(v);
      hi8[j] = hh_; lo8[j] = f2bf(v - bf2f(hh_));
    }
    size_t dst = hb + (size_t)d * SEQ + st * 64 + ks;
    *(uint4v*)(Vth + dst)     = *(const uint4v*)&hi8[0];
    *(uint4v*)(Vth + dst + 8) = *(const uint4v*)&hi8[8];
    *(uint4v*)(Vtl + dst)     = *(const uint4v*)&lo8[0];
    *(uint4v*)(Vtl + dst + 8) = *(const uint4v*)&lo8[8];
  }
}

// ---------------------------------------------------------------------------
// attn_mf3: split-bf16 MFMA flash attention, KV-parity + causal-fold.
// ---------------------------------------------------------------------------
__global__ __launch_bounds__(256) void attn_mf3(
    const unsigned short* __restrict__ Qh, const unsigned short* __restrict__ Ql,
    const unsigned short* __restrict__ Kh, const unsigned short* __restrict__ Kl,
    const unsigned short* __restrict__ Vth, const unsigned short* __restrict__ Vtl,
    float* __restrict__ paro,     // [2][TTOK][DMODEL] unnormalized o
    float* __restrict__ parml)    // [2][TTOK][NH][2]  (m, l)
{
  __shared__ unsigned short KVh[64][72], KVl[64][72];
  __shared__ unsigned short Phs[64][72], Pls[64][72];
  int bh = blockIdx.y;
  int b = bh >> 4, h = bh & 15;
  int bx = blockIdx.x;                 // 0..31
  int p  = bx >> 1, par = bx & 1;
  int tid = threadIdx.x, wv = tid >> 6, l = tid & 63;
  int lm = l & 15, lh = l >> 4;
  const size_t hb = (size_t)bh * SEQ * 64;
  int srow = tid >> 2, scs = (tid & 3) * 16;
  int qin = wv * 16 + lh * 4;          // + r = q row within tile
  const f32x4 z = {0.f, 0.f, 0.f, 0.f};

  #pragma unroll 1
  for (int job = 0; job < 2; ++job) {
    int qt = job ? (31 - p) : p;
    int q0 = qt * 64 + wv * 16;

    short8 aQh[2], aQl[2];
    {
      size_t qa = hb + (size_t)(q0 + lm) * 64 + (lh << 3);
      aQh[0] = *(const short8*)(Qh + qa);
      aQh[1] = *(const short8*)(Qh + qa + 32);
      aQl[0] = *(const short8*)(Ql + qa);
      aQl[1] = *(const short8*)(Ql + qa + 32);
    }
    f32x4 ctx[4] = {z, z, z, z};
    float mrun[4] = {-1e4f, -1e4f, -1e4f, -1e4f};
    float lrun[4] = {0.f, 0.f, 0.f, 0.f};

    for (int kt = par; kt <= qt; kt += 2) {
      uint4v vh0, vh1, vl0, vl1;
      {
        size_t vg = hb + (size_t)srow * SEQ + kt * 64 + scs;
        vh0 = *(const uint4v*)(Vth + vg);
        vh1 = *(const uint4v*)(Vth + vg + 8);
        vl0 = *(const uint4v*)(Vtl + vg);
        vl1 = *(const uint4v*)(Vtl + vg + 8);
      }
      __syncthreads();                       // prev PV reads done
      {
        size_t kg = hb + (size_t)(kt * 64 + srow) * 64 + scs;
        *(uint4v*)&KVh[srow][scs]     = *(const uint4v*)(Kh + kg);
        *(uint4v*)&KVh[srow][scs + 8] = *(const uint4v*)(Kh + kg + 8);
        *(uint4v*)&KVl[srow][scs]     = *(const uint4v*)(Kl + kg);
        *(uint4v*)&KVl[srow][scs + 8] = *(const uint4v*)(Kl + kg + 8);
      }
      __syncthreads();                       // K staged

      f32x4 S4[4] = {z, z, z, z};
      #pragma unroll
      for (int n = 0; n < 4; ++n) {
        #pragma unroll
        for (int c = 0; c < 2; ++c) {
          short8 kbh = *(const short8*)&KVh[n * 16 + lm][c * 32 + (lh << 3)];
          short8 kbl = *(const short8*)&KVl[n * 16 + lm][c * 32 + (lh << 3)];
          S4[n] = __builtin_amdgcn_mfma_f32_16x16x32_bf16(aQh[c], kbh, S4[n], 0, 0, 0);
          S4[n] = __builtin_amdgcn_mfma_f32_16x16x32_bf16(aQl[c], kbh, S4[n], 0, 0, 0);
          S4[n] = __builtin_amdgcn_mfma_f32_16x16x32_bf16(aQh[c], kbl, S4[n], 0, 0, 0);
        }
      }
      bool diag = (kt == qt);
      #pragma unroll
      for (int r = 0; r < 4; ++r) {
        float s0 = S4[0][r] * 0.125f, s1 = S4[1][r] * 0.125f;
        float s2 = S4[2][r] * 0.125f, s3 = S4[3][r] * 0.125f;
        if (diag) {
          int qq = qin + r;
          if (lm      > qq) s0 = -1e30f;
          if (16 + lm > qq) s1 = -1e30f;
          if (32 + lm > qq) s2 = -1e30f;
          if (48 + lm > qq) s3 = -1e30f;
        }
        float cm = fmaxf(fmaxf(s0, s1), fmaxf(s2, s3));
        cm = fmaxf(cm, __shfl_xor(cm, 1));
        cm = fmaxf(cm, __shfl_xor(cm, 2));
        cm = fmaxf(cm, __shfl_xor(cm, 4));
        cm = fmaxf(cm, __shfl_xor(cm, 8));
        if (cm > mrun[r] + 8.0f) {           // defer-max (THR=8)
          float sc = __expf(mrun[r] - cm);
          lrun[r] *= sc;
          ctx[0][r] *= sc; ctx[1][r] *= sc; ctx[2][r] *= sc; ctx[3][r] *= sc;
          mrun[r] = cm;
        }
        float p0 = __expf(s0 - mrun[r]), p1 = __expf(s1 - mrun[r]);
        float p2 = __expf(s2 - mrun[r]), p3 = __expf(s3 - mrun[r]);
        float rs = (p0 + p1) + (p2 + p3);
        rs += __shfl_xor(rs, 1); rs += __shfl_xor(rs, 2);
        rs += __shfl_xor(rs, 4); rs += __shfl_xor(rs, 8);
        lrun[r] += rs;
        int prow = qin + r;
        unsigned short e0 = f2bf(p0); Phs[prow][lm]      = e0; Pls[prow][lm]      = f2bf(p0 - bf2f(e0));
        unsigned short e1 = f2bf(p1); Phs[prow][16 + lm] = e1; Pls[prow][16 + lm] = f2bf(p1 - bf2f(e1));
        unsigned short e2 = f2bf(p2); Phs[prow][32 + lm] = e2; Pls[prow][32 + lm] = f2bf(p2 - bf2f(e2));
        unsigned short e3 = f2bf(p3); Phs[prow][48 + lm] = e3; Pls[prow][48 + lm] = f2bf(p3 - bf2f(e3));
      }
      __syncthreads();                       // QK^T reads of KV done
      {
        *(uint4v*)&KVh[srow][scs]     = vh0;
        *(uint4v*)&KVh[srow][scs + 8] = vh1;
        *(uint4v*)&KVl[srow][scs]     = vl0;
        *(uint4v*)&KVl[srow][scs + 8] = vl1;
      }
      __syncthreads();                       // V staged

      #pragma unroll
      for (int c = 0; c < 2; ++c) {
        short8 pah = *(const short8*)&Phs[wv * 16 + lm][c * 32 + (lh << 3)];
        short8 pal = *(const short8*)&Pls[wv * 16 + lm][c * 32 + (lh << 3)];
        #pragma unroll
        for (int n = 0; n < 4; ++n) {
          short8 vbh = *(const short8*)&KVh[n * 16 + lm][c * 32 + (lh << 3)];
          short8 vbl = *(const short8*)&KVl[n * 16 + lm][c * 32 + (lh << 3)];
          ctx[n] = __builtin_amdgcn_mfma_f32_16x16x32_bf16(pah, vbh, ctx[n], 0, 0, 0);
          ctx[n] = __builtin_amdgcn_mfma_f32_16x16x32_bf16(pal, vbh, ctx[n], 0, 0, 0);
          ctx[n] = __builtin_amdgcn_mfma_f32_16x16x32_bf16(pah, vbl, ctx[n], 0, 0, 0);
        }
      }
    }

    // write flash partials for this q-tile
    #pragma unroll
    for (int r = 0; r < 4; ++r) {
      int qg = b * SEQ + qt * 64 + wv * 16 + lh * 4 + r;
      size_t ob = ((size_t)par * TTOK + qg) * DMODEL + (size_t)h * HDIM + lm;
      #pragma unroll
      for (int n = 0; n < 4; ++n) paro[ob + n * 16] = ctx[n][r];
      if (lm == 0) {
        size_t mb = (((size_t)par * TTOK + qg) * NH + h) * 2;
        parml[mb] = mrun[r]; parml[mb + 1] = lrun[r];
      }
    }
  }
}

// ---------------------------------------------------------------------------
// attn_merge<NS>: exact flash merge of NS partials -> ctx hi/lo split.
// ---------------------------------------------------------------------------
template<int NS>
__global__ __launch_bounds__(256) void attn_merge(
    const float* __restrict__ paro,
    const float* __restrict__ parml,
    unsigned short* __restrict__ ctxh,
    unsigned short* __restrict__ ctxl)
{
  int gid = blockIdx.x * 256 + threadIdx.x;
  int ds = gid & 3;
  int h  = (gid >> 2) & 15;
  int t  = gid >> 6;
  float m[NS], lv[NS];
  float mx = -1e30f;
  #pragma unroll
  for (int i = 0; i < NS; ++i) {
    size_t mb = (((size_t)i * TTOK + t) * NH + h) * 2;
    m[i] = parml[mb]; lv[i] = parml[mb + 1];
    mx = fmaxf(mx, m[i]);
  }
  float w[NS], lsum = 0.f;
  #pragma unroll
  for (int i = 0; i < NS; ++i) { w[i] = __expf(m[i] - mx); lsum += lv[i] * w[i]; }
  float inv = 1.0f / lsum;
  size_t ob = (size_t)t * DMODEL + (size_t)h * HDIM + ds * 16;
  #pragma unroll
  for (int i4 = 0; i4 < 4; ++i4) {
    f32x4 v = {0.f, 0.f, 0.f, 0.f};
    #pragma unroll
    for (int i = 0; i < NS; ++i) {
      const f32x4* oi = (const f32x4*)(paro + (size_t)i * TTOK * DMODEL + ob);
      v += oi[i4] * w[i];
    }
    v = v * inv;
    ushort4 hi, lo;
    unsigned short e0 = f2bf(v[0]); hi.x = e0; lo.x = f2bf(v[0] - bf2f(e0));
    unsigned short e1 = f2bf(v[1]); hi.y = e1; lo.y = f2bf(v[1] - bf2f(e1));
    unsigned short e2 = f2bf(v[2]); hi.z = e2; lo.z = f2bf(v[2] - bf2f(e2));
    unsigned short e3 = f2bf(v[3]); hi.w = e3; lo.w = f2bf(v[3] - bf2f(e3));
    *(ushort4*)(ctxh + ob + i4 * 4) = hi;
    *(ushort4*)(ctxl + ob + i4 * 4) = lo;
  }
}

// ---------------------------------------------------------------------------
// Router (fp32)
// ---------------------------------------------------------------------------
__global__ __launch_bounds__(256) void router_kernel(
    const float* __restrict__ x1,
    const float* __restrict__ gam,
    const float* __restrict__ bet,
    const float* __restrict__ wrt,
    int* __restrict__ ctrl,
    int2* __restrict__ t_e,
    float2* __restrict__ t_g)
{
  int w = threadIdx.x >> 6, l = threadIdx.x & 63;
  int t = blockIdx.x * 4 + w;
  const f32x4* row = (const f32x4*)(x1 + (size_t)t * DMODEL);
  f32x4 v[4];
  float s = 0.f, sq = 0.f;
  #pragma unroll
  for (int i = 0; i < 4; ++i) {
    v[i] = row[l + i * 64];
    #pragma unroll
    for (int j = 0; j < 4; ++j) { s += v[i][j]; sq += v[i][j] * v[i][j]; }
  }
  #pragma unroll
  for (int off = 1; off < 64; off <<= 1) {
    s  += __shfl_xor(s, off);
    sq += __shfl_xor(sq, off);
  }
  float mu  = s * (1.0f / DMODEL);
  float var = sq * (1.0f / DMODEL) - mu * mu;
  float rs  = rsqrtf(var + 1e-5f);

  float acc[NE] = {0.f, 0.f, 0.f, 0.f, 0.f, 0.f, 0.f, 0.f};
  #pragma unroll
  for (int i = 0; i < 4; ++i) {
    int base = (l + i * 64) * 4;
    #pragma unroll
    for (int j = 0; j < 4; ++j) {
      int idx = base + j;
      float xn = (v[i][j] - mu) * rs * gam[idx] + bet[idx];
      const f32x4* wr0 = (const f32x4*)(wrt + idx * NE);
      f32x4 w0 = wr0[0], w1v = wr0[1];
      acc[0] += xn * w0[0]; acc[1] += xn * w0[1];
      acc[2] += xn * w0[2]; acc[3] += xn * w0[3];
      acc[4] += xn * w1v[0]; acc[5] += xn * w1v[1];
      acc[6] += xn * w1v[2]; acc[7] += xn * w1v[3];
    }
  }
  #pragma unroll
  for (int e = 0; e < NE; ++e) {
    #pragma unroll
    for (int off = 1; off < 64; off <<= 1) acc[e] += __shfl_xor(acc[e], off);
  }
  if (l == 0) {
    int e0 = 0; float m0v = acc[0];
    #pragma unroll
    for (int e = 1; e < NE; ++e) if (acc[e] > m0v) { m0v = acc[e]; e0 = e; }
    int e1 = -1; float m1v = -1e30f;
    #pragma unroll
    for (int e = 0; e < NE; ++e) if (e != e0 && acc[e] > m1v) { m1v = acc[e]; e1 = e; }
    float r = __expf(m1v - m0v);
    float g0 = 1.0f / (1.0f + r);
    float g1 = r * g0;
    t_e[t] = make_int2(e0, e1);
    t_g[t] = make_float2(g0, g1);
    atomicAdd(&ctrl[C_CNT + e0], 1);
    atomicAdd(&ctrl[C_CNT + e1], 1);
  }
}

// ---------------------------------------------------------------------------
// Scan: 256-padded per-expert slot bases + 256-row m-tile table.
// ---------------------------------------------------------------------------
__global__ void scan_kernel(int* __restrict__ ctrl)
{
  if (threadIdx.x == 0 && blockIdx.x == 0) {
    int b = 0, m = 0;
    for (int e = 0; e < NE; ++e) {
      ctrl[C_BASE + e] = b;
      int pc = (ctrl[C_CNT + e] + 255) & ~255;
      int nt = pc >> 8;
      for (int i = 0; i < nt; ++i) {
        ctrl[C_MTE + m] = e;
        ctrl[C_MTS + m] = b + (i << 8);
        ++m;
      }
      b += pc;
    }
    ctrl[C_NMT] = m;
  }
}

// ---------------------------------------------------------------------------
__global__ __launch_bounds__(256) void gather_kernel(
    int* __restrict__ ctrl,
    const int2* __restrict__ t_e,
    const float2* __restrict__ t_g,
    int* __restrict__ slot_token,
    float* __restrict__ slot_gate)
{
  int t = blockIdx.x * 256 + threadIdx.x;
  int2 e = t_e[t];
  float2 g = t_g[t];
  int p0 = atomicAdd(&ctrl[C_FILL + e.x], 1);
  int s0 = ctrl[C_BASE + e.x] + p0;
  slot_token[s0] = t; slot_gate[s0] = g.x;
  int p1 = atomicAdd(&ctrl[C_FILL + e.y], 1);
  int s1 = ctrl[C_BASE + e.y] + p1;
  slot_token[s1] = t; slot_gate[s1] = g.y;
}

// ---------------------------------------------------------------------------
// Transpose + fp32->bf16: in [E][K][N] fp32 -> out [E][N][K] bf16.
// ---------------------------------------------------------------------------
__global__ __launch_bounds__(256) void transpose_conv(
    const float* __restrict__ in, unsigned short* __restrict__ outb,
    unsigned short* __restrict__ outlo, int K, int N)
{
  __shared__ float T[64][68];
  int e = blockIdx.z;
  int n0 = blockIdx.x * 64, k0 = blockIdx.y * 64;
  const float* src = in + (size_t)e * K * N;
  unsigned short* dst = outb + (size_t)e * K * N;
  unsigned short* dstl = outlo ? outlo + (size_t)e * K * N : nullptr;
  int tid = threadIdx.x;
  int r = tid >> 4, c4 = (tid & 15) * 4;
  #pragma unroll
  for (int i = 0; i < 4; ++i) {
    f32x4 v = *(const f32x4*)(src + (size_t)(k0 + r + i * 16) * N + n0 + c4);
    *(f32x4*)(&T[r + i * 16][c4]) = v;
  }
  __syncthreads();
  #pragma unroll
  for (int i = 0; i < 4; ++i) {
    int rr = r + i * 16;
    float v0 = T[c4 + 0][rr], v1 = T[c4 + 1][rr];
    float v2 = T[c4 + 2][rr], v3 = T[c4 + 3][rr];
    ushort4 o;
    o.x = f2bf(v0); o.y = f2bf(v1); o.z = f2bf(v2); o.w = f2bf(v3);
    *(ushort4*)(dst + (size_t)(n0 + rr) * K + k0 + c4) = o;
    if (dstl) {
      ushort4 lo;
      lo.x = f2bf(v0 - bf2f(o.x));
      lo.y = f2bf(v1 - bf2f(o.y));
      lo.z = f2bf(v2 - bf2f(o.z));
      lo.w = f2bf(v3 - bf2f(o.w));
      *(ushort4*)(dstl + (size_t)(n0 + rr) * K + k0 + c4) = lo;
    }
  }
}

// ---------------------------------------------------------------------------
// Sparse MoE w1, BM=256: Hs[slot] = gelu(h2[token(slot)] @ w1t[e]^T + b1[e]).
// Grid (MT_MAX, DFF/128): x = m-tile (XCD-grouped: gridDim.x % 8 == 0).
// ---------------------------------------------------------------------------
__global__ __launch_bounds__(256) void moe_w1g(
    const unsigned short* __restrict__ h2,
    const unsigned short* __restrict__ w1t,
    const float* __restrict__ b1,
    const int* __restrict__ ctrl,
    const int* __restrict__ slot_token,
    unsigned short* __restrict__ Hs)
{
  int mt = blockIdx.x;
  if (mt >= ctrl[C_NMT]) return;
  int e = ctrl[C_MTE + mt];
  int slot0 = ctrl[C_MTS + mt];
  const int N = DFF, K = DMODEL;
  const unsigned short* Bt = w1t + (size_t)e * K * N;
  const float* bias = b1 + (size_t)e * DFF;

  __shared__ unsigned short Al[256][32];
  __shared__ unsigned short Bl[128][32];
  __shared__ int tokrow[256];
  int tid = threadIdx.x;
  {
    int tk = slot_token[slot0 + tid];
    tokrow[tid] = tk < 0 ? 0 : tk;
  }
  __syncthreads();
  int l = tid & 63, wv = tid >> 6;
  int wr = wv >> 1, wc = wv & 1;
  int n0 = blockIdx.y * 128;
  int rsub = l >> 2, csub = (l & 3) * 8;
  const unsigned short* ga[4];
  #pragma unroll
  for (int j = 0; j < 4; ++j)
    ga[j] = h2 + (size_t)tokrow[wv * 64 + rsub + 16 * j] * DMODEL + csub;
  const unsigned short* gb0 = Bt + (size_t)(n0 + wv * 32 + rsub) * K + csub;
  const unsigned short* gb1 = Bt + (size_t)(n0 + wv * 32 + 16 + rsub) * K + csub;

  const f32x4 z = {0.f, 0.f, 0.f, 0.f};
  f32x4 acc[2][4][4];
  #pragma unroll
  for (int hh = 0; hh < 2; ++hh)
    #pragma unroll
    for (int i = 0; i < 4; ++i)
      #pragma unroll
      for (int j = 0; j < 4; ++j) acc[hh][i][j] = z;

  for (int k0 = 0; k0 < K; k0 += 32) {
    __syncthreads();
    #pragma unroll
    for (int j = 0; j < 4; ++j)
      gl_lds16(ga[j] + k0, &Al[wv * 64 + 16 * j][0]);
    gl_lds16(gb0 + k0, &Bl[wv * 32][0]);
    gl_lds16(gb1 + k0, &Bl[wv * 32 + 16][0]);
    __syncthreads();

    short8 af0[4], af1[4], bfr[4];
    #pragma unroll
    for (int m = 0; m < 4; ++m) {
      af0[m] = *(const short8*)(&Al[wr * 64 + m * 16 + (l & 15)][(l >> 4) << 3]);
      af1[m] = *(const short8*)(&Al[128 + wr * 64 + m * 16 + (l & 15)][(l >> 4) << 3]);
    }
    #pragma unroll
    for (int n = 0; n < 4; ++n)
      bfr[n] = *(const short8*)(&Bl[wc * 64 + n * 16 + (l & 15)][(l >> 4) << 3]);
    #pragma unroll
    for (int m = 0; m < 4; ++m)
      #pragma unroll
      for (int n = 0; n < 4; ++n) {
        acc[0][m][n] = __builtin_amdgcn_mfma_f32_16x16x32_bf16(af0[m], bfr[n], acc[0][m][n], 0, 0, 0);
        acc[1][m][n] = __builtin_amdgcn_mfma_f32_16x16x32_bf16(af1[m], bfr[n], acc[1][m][n], 0, 0, 0);
      }
  }

  int cbase = n0 + wc * 64 + (l & 15);
  #pragma unroll
  for (int hh = 0; hh < 2; ++hh) {
    int rbase = hh * 128 + wr * 64 + ((l >> 4) << 2);
    #pragma unroll
    for (int n = 0; n < 4; ++n) {
      int col = cbase + n * 16;
      float bv = bias[col];
      #pragma unroll
      for (int m = 0; m < 4; ++m) {
        #pragma unroll
        for (int r = 0; r < 4; ++r) {
          int srow = slot0 + rbase + m * 16 + r;
          float v = acc[hh][m][n][r] + bv;
          v = 0.5f * v * (1.0f + erff(v * 0.70710678118654752f));
          Hs[(size_t)srow * DFF + col] = f2bf(v);
        }
      }
    }
  }
}

// ---------------------------------------------------------------------------
// Sparse MoE w2, BM=256 + K-split (gridDim.z = 2):
//   ffn[token] += gate * (Hs[slot][kslice] @ w2t[e][kslice]^T + (ks==0)*b2[e]).
// Grid (MT_MAX, DMODEL/128, 2): x = m-tile; flat ID ≡ mt (mod 8) -> XCD-grouped.
// ---------------------------------------------------------------------------
__global__ __launch_bounds__(256) void moe_w2g(
    const unsigned short* __restrict__ Hs,
    const unsigned short* __restrict__ w2t,
    const float* __restrict__ b2,
    const int* __restrict__ ctrl,
    const int* __restrict__ slot_token,
    const float* __restrict__ slot_gate,
    float* __restrict__ ffn)
{
  int mt = blockIdx.x;
  if (mt >= ctrl[C_NMT]) return;
  int e = ctrl[C_MTE + mt];
  int slot0 = ctrl[C_MTS + mt];
  int ks = blockIdx.z;                 // K-split half: [ks*2048, ks*2048+2048)
  const int N = DMODEL, K = DFF;
  const unsigned short* Bt = w2t + (size_t)e * (size_t)K * N;
  const float* bias = b2 + (size_t)e * DMODEL;

  __shared__ unsigned short Al[256][32];
  __shared__ unsigned short Bl[128][32];
  int tid = threadIdx.x;
  int l = tid & 63, wv = tid >> 6;
  int wr = wv >> 1, wc = wv & 1;
  int n0 = blockIdx.y * 128;
  int rsub = l >> 2, csub = (l & 3) * 8;
  const unsigned short* ga[4];
  #pragma unroll
  for (int j = 0; j < 4; ++j)
    ga[j] = Hs + (size_t)(slot0 + wv * 64 + rsub + 16 * j) * DFF + csub;
  const unsigned short* gb0 = Bt + (size_t)(n0 + wv * 32 + rsub) * K + csub;
  const unsigned short* gb1 = Bt + (size_t)(n0 + wv * 32 + 16 + rsub) * K + csub;

  const f32x4 z = {0.f, 0.f, 0.f, 0.f};
  f32x4 acc[2][4][4];
  #pragma unroll
  for (int hh = 0; hh < 2; ++hh)
    #pragma unroll
    for (int i = 0; i < 4; ++i)
      #pragma unroll
      for (int j = 0; j < 4; ++j) acc[hh][i][j] = z;

  int kbeg = ks * (K / 2), kend = kbeg + (K / 2);
  for (int k0 = kbeg; k0 < kend; k0 += 32) {
    __syncthreads();
    #pragma unroll
    for (int j = 0; j < 4; ++j)
      gl_lds16(ga[j] + k0, &Al[wv * 64 + 16 * j][0]);
    gl_lds16(gb0 + k0, &Bl[wv * 32][0]);
    gl_lds16(gb1 + k0, &Bl[wv * 32 + 16][0]);
    __syncthreads();

    short8 af0[4], af1[4], bfr[4];
    #pragma unroll
    for (int m = 0; m < 4; ++m) {
      af0[m] = *(const short8*)(&Al[wr * 64 + m * 16 + (l & 15)][(l >> 4) << 3]);
      af1[m] = *(const short8*)(&Al[128 + wr * 64 + m * 16 + (l & 15)][(l >> 4) << 3]);
    }
    #pragma unroll
    for (int n = 0; n < 4; ++n)
      bfr[n] = *(const short8*)(&Bl[wc * 64 + n * 16 + (l & 15)][(l >> 4) << 3]);
    #pragma unroll
    for (int m = 0; m < 4; ++m)
      #pragma unroll
      for (int n = 0; n < 4; ++n) {
        acc[0][m][n] = __builtin_amdgcn_mfma_f32_16x16x32_bf16(af0[m], bfr[n], acc[0][m][n], 0, 0, 0);
        acc[1][m][n] = __builtin_amdgcn_mfma_f32_16x16x32_bf16(af1[m], bfr[n], acc[1][m][n], 0, 0, 0);
      }
  }

  int cbase = n0 + wc * 64 + (l & 15);
  #pragma unroll
  for (int hh = 0; hh < 2; ++hh) {
    int rbase = hh * 128 + wr * 64 + ((l >> 4) << 2);
    #pragma unroll
    for (int n = 0; n < 4; ++n) {
      int col = cbase + n * 16;
      float bv = (ks == 0) ? bias[col] : 0.0f;
      #pragma unroll
      for (int m = 0; m < 4; ++m) {
        #pragma unroll
        for (int r = 0; r < 4; ++r) {
          int srow = slot0 + rbase + m * 16 + r;
          int tok = slot_token[srow];
          if (tok >= 0) {
            float v = acc[hh][m][n][r] + bv;
            atomicAdd(&ffn[(size_t)tok * DMODEL + col], slot_gate[srow] * v);
          }
        }
      }
    }
  }
}

// ---------------------------------------------------------------------------
__global__ __launch_bounds__(256) void final_add(
    const float* __restrict__ x1,
    const float* __restrict__ ffn,
    float* __restrict__ out)
{
  int i = blockIdx.x * 256 + threadIdx.x;
  f32x4 xr = ((const f32x4*)x1)[i];
  f32x4 fr = ((const f32x4*)ffn)[i];
  f32x4 o;
  o[0] = xr[0] + fr[0];
  o[1] = xr[1] + fr[1];
  o[2] = xr[2] + fr[2];
  o[3] = xr[3] + fr[3];
  ((f32x4*)out)[i] = o;
}

// ---------------------------------------------------------------------------
extern "C" void kernel_launch(void* const* d_in, const int* in_sizes, int n_in,
                              void* d_out, int out_size, void* d_ws, size_t ws_size,
                              hipStream_t stream) {
  (void)in_sizes; (void)n_in; (void)out_size;
  const float* x     = (const float*)d_in[0];
  const float* ln1_g = (const float*)d_in[1];
  const float* ln1_b = (const float*)d_in[2];
  const float* ln2_g = (const float*)d_in[3];
  const float* ln2_b = (const float*)d_in[4];
  const float* wqkv  = (const float*)d_in[5];
  const float* bqkv  = (const float*)d_in[6];
  const float* wo    = (const float*)d_in[7];
  const float* bo    = (const float*)d_in[8];
  const float* wrt   = (const float*)d_in[9];
  const float* w1    = (const float*)d_in[10];
  const float* b1    = (const float*)d_in[11];
  const float* w2    = (const float*)d_in[12];
  const float* b2    = (const float*)d_in[13];
  float* out = (float*)d_out;

  char* ws = (char*)d_ws;
  size_t off = 0;
  auto alloc = [&](size_t bytes) -> void* {
    void* p = ws + off;
    off += (bytes + 255) & ~(size_t)255;
    return p;
  };
  float*          x1    = (float*)alloc((size_t)TTOK * DMODEL * 4);
  unsigned short* h2    = (unsigned short*)alloc((size_t)TTOK * DMODEL * 2);
  int*            ctrl  = (int*)alloc(1024);
  int2*           t_e   = (int2*)alloc((size_t)TTOK * 8);
  float2*         t_g   = (float2*)alloc((size_t)TTOK * 8);
  int*            slot_token = (int*)alloc((size_t)SLOT_MAX * 4);
  float*          slot_gate  = (float*)alloc((size_t)SLOT_MAX * 4);
  float*          P1    = (float*)alloc((size_t)TTOK * DMODEL * 4);
  char*           P2    = (char*)alloc((size_t)SLOT_MAX * DFF * 2);
  unsigned short* w1t   = (unsigned short*)alloc((size_t)NE * DMODEL * DFF * 2);
  unsigned short* w2t   = (unsigned short*)alloc((size_t)NE * DFF * DMODEL * 2);
  unsigned short* wqkvTh = (unsigned short*)alloc((size_t)DMODEL * 3 * DMODEL * 2);
  unsigned short* wqkvTl = (unsigned short*)alloc((size_t)DMODEL * 3 * DMODEL * 2);
  unsigned short* woTh  = (unsigned short*)alloc((size_t)DMODEL * DMODEL * 2);
  unsigned short* woTl  = (unsigned short*)alloc((size_t)DMODEL * DMODEL * 2);
  unsigned short* hh    = (unsigned short*)alloc((size_t)TTOK * DMODEL * 2);
  unsigned short* hl    = (unsigned short*)alloc((size_t)TTOK * DMODEL * 2);
  unsigned short* ctxh  = (unsigned short*)alloc((size_t)TTOK * DMODEL * 2);
  unsigned short* ctxl  = (unsigned short*)alloc((size_t)TTOK * DMODEL * 2);
  // MFMA attention split-qkv arrays + flash partials
  size_t headsz = (size_t)NB * NH * SEQ * HDIM;   // elems per array
  unsigned short* Qh  = (unsigned short*)alloc(headsz * 2);
  unsigned short* Ql  = (unsigned short*)alloc(headsz * 2);
  unsigned short* Khp = (unsigned short*)alloc(headsz * 2);
  unsigned short* Klp = (unsigned short*)alloc(headsz * 2);
  unsigned short* Vth = (unsigned short*)alloc(headsz * 2);
  unsigned short* Vtl = (unsigned short*)alloc(headsz * 2);
  float*          paro2  = (float*)alloc((size_t)2 * TTOK * DMODEL * 4);
  float*          parml2 = (float*)alloc((size_t)2 * TTOK * NH * 2 * 4);

  float*          qkv  = (float*)P2;        // dead before Hs is written
  float*          ffn  = P1;
  unsigned short* Hs   = (unsigned short*)P2;

  // 0) zero control counters, mark all slots invalid
  hipMemsetAsync(ctrl, 0, 16 * 4, stream);
  hipMemsetAsync(slot_token, 0xFF, (size_t)SLOT_MAX * 4, stream);

  // 0b) weight prep
  transpose_conv<<<dim3(DFF / 64, DMODEL / 64, NE), 256, 0, stream>>>(
      w1, w1t, nullptr, DMODEL, DFF);
  transpose_conv<<<dim3(DMODEL / 64, DFF / 64, NE), 256, 0, stream>>>(
      w2, w2t, nullptr, DFF, DMODEL);
  transpose_conv<<<dim3(3 * DMODEL / 64, DMODEL / 64, 1), 256, 0, stream>>>(
      wqkv, wqkvTh, wqkvTl, DMODEL, 3 * DMODEL);
  transpose_conv<<<dim3(DMODEL / 64, DMODEL / 64, 1), 256, 0, stream>>>(
      wo, woTh, woTl, DMODEL, DMODEL);

  // 1) h = LN1(x) -> split hi/lo
  ln_kernel<2><<<TTOK, 256, 0, stream>>>(x, ln1_g, ln1_b, nullptr, hh, hl);
  // 2) qkv = h @ wqkv + bqkv   (split-bf16 MFMA, fp32-grade)
  mgemm_split<0><<<dim3(3 * DMODEL / 128, TTOK / 128), 256, 0, stream>>>(
      hh, hl, wqkvTh, wqkvTl, bqkv, nullptr, qkv, TTOK, 3 * DMODEL, DMODEL);
  // 3) ctx = causal attention (split-bf16 MFMA flash, parity+fold) -> merge
  qkv_split<<<dim3(SEQ / 64, NB * NH), 256, 0, stream>>>(
      qkv, Qh, Ql, Khp, Klp, Vth, Vtl);
  attn_mf3<<<dim3(32, NB * NH), 256, 0, stream>>>(
      Qh, Ql, Khp, Klp, Vth, Vtl, paro2, parml2);
  attn_merge<2><<<(TTOK * NH * 4) / 256, 256, 0, stream>>>(
      paro2, parml2, ctxh, ctxl);
  // 4) x1 = x + ctx @ wo + bo  (split-bf16 MFMA)
  mgemm_split<1><<<dim3(DMODEL / 128, TTOK / 128), 256, 0, stream>>>(
      ctxh, ctxl, woTh, woTl, bo, x, x1, TTOK, DMODEL, DMODEL);

  // 5) h2 = LN2(x1)
  ln_kernel<1><<<TTOK, 256, 0, stream>>>(x1, ln2_g, ln2_b, nullptr, h2, nullptr);
  // 6) router -> scan -> gather
  router_kernel<<<TTOK / 4, 256, 0, stream>>>(x1, ln2_g, ln2_b, wrt, ctrl, t_e, t_g);
  scan_kernel<<<1, 64, 0, stream>>>(ctrl);
  gather_kernel<<<TTOK / 256, 256, 0, stream>>>(ctrl, t_e, t_g, slot_token, slot_gate);
  // 7) sparse MoE (BM=256; w2 K-split x2 restores memory parallelism)
  hipMemsetAsync(ffn, 0, (size_t)TTOK * DMODEL * 4, stream);
  moe_w1g<<<dim3(MT_MAX, DFF / 128), 256, 0, stream>>>(
      h2, w1t, b1, ctrl, slot_token, Hs);
  moe_w2g<<<dim3(MT_MAX, DMODEL / 128, 2), 256, 0, stream>>>(
      Hs, w2t, b2, ctrl, slot_token, slot_gate, ffn);
  // 8) out = x1 + ffn
  final_add<<<(TTOK * DMODEL / 4) / 256, 256, 0, stream>>>(x1, ffn, out);
}

// Round 18
// 921.202 us; speedup vs baseline: 1.3437x; 1.3311x over previous
//
#include <hip/hip_runtime.h>
#include <hip/hip_bf16.h>
#include <math.h>

// Problem constants
#define NB    2
#define SEQ   2048
#define DMODEL 1024
#define NH    16
#define HDIM  64
#define NE    8
#define DFF   4096
#define TTOK  4096   // NB*SEQ

#define MT_MAX   72
#define SLOT_MAX 9216

// ctrl block layout (ints)
#define C_CNT  0
#define C_FILL 8
#define C_BASE 16
#define C_NMT  24
#define C_MTE  32
#define C_MTS  104

typedef __attribute__((ext_vector_type(8))) short short8;
typedef __attribute__((ext_vector_type(4))) float f32x4;
typedef __attribute__((ext_vector_type(4))) unsigned int uint4v;

static __device__ __forceinline__ float bf2f(unsigned short u) {
  union { unsigned int i; float f; } c; c.i = ((unsigned int)u) << 16; return c.f;
}
static __device__ __forceinline__ unsigned short f2bf(float f) {
  unsigned int x = __float_as_uint(f);
  unsigned int r = (x + 0x7FFFu + ((x >> 16) & 1u)) >> 16;
  return (unsigned short)r;
}

// Async global->LDS, 16B per lane. LDS dest is WAVE-UNIFORM base + lane*16.
static __device__ __forceinline__ void gl_lds16(const void* g, void* l) {
  __builtin_amdgcn_global_load_lds(
      (const __attribute__((address_space(1))) unsigned int*)(uintptr_t)g,
      (__attribute__((address_space(3))) unsigned int*)(uintptr_t)l,
      16, 0, 0);
}

// ---------------------------------------------------------------------------
// LayerNorm. MODE 0: fp32 out. MODE 1: bf16 out. MODE 2: split hi/lo bf16.
// ---------------------------------------------------------------------------
template<int MODE>
__global__ __launch_bounds__(256) void ln_kernel(
    const float* __restrict__ x,
    const float* __restrict__ gam,
    const float* __restrict__ bet,
    float* __restrict__ outf,
    unsigned short* __restrict__ outb,
    unsigned short* __restrict__ outlo)
{
  int t = blockIdx.x, tid = threadIdx.x;
  f32x4 v = ((const f32x4*)(x + (size_t)t * DMODEL))[tid];
  float s  = v[0] + v[1] + v[2] + v[3];
  float sq = v[0]*v[0] + v[1]*v[1] + v[2]*v[2] + v[3]*v[3];
  #pragma unroll
  for (int off = 1; off < 64; off <<= 1) {
    s  += __shfl_xor(s, off);
    sq += __shfl_xor(sq, off);
  }
  __shared__ float red[8];
  int w = tid >> 6, l = tid & 63;
  if (l == 0) { red[w] = s; red[4 + w] = sq; }
  __syncthreads();
  s  = red[0] + red[1] + red[2] + red[3];
  sq = red[4] + red[5] + red[6] + red[7];
  float mu  = s * (1.0f / DMODEL);
  float var = sq * (1.0f / DMODEL) - mu * mu;
  float rs  = rsqrtf(var + 1e-5f);
  f32x4 g = ((const f32x4*)gam)[tid];
  f32x4 b = ((const f32x4*)bet)[tid];
  float r[4];
  r[0] = (v[0] - mu) * rs * g[0] + b[0];
  r[1] = (v[1] - mu) * rs * g[1] + b[1];
  r[2] = (v[2] - mu) * rs * g[2] + b[2];
  r[3] = (v[3] - mu) * rs * g[3] + b[3];
  if constexpr (MODE == 0) {
    f32x4 o = {r[0], r[1], r[2], r[3]};
    ((f32x4*)(outf + (size_t)t * DMODEL))[tid] = o;
  } else if constexpr (MODE == 1) {
    ushort4 o; o.x = f2bf(r[0]); o.y = f2bf(r[1]); o.z = f2bf(r[2]); o.w = f2bf(r[3]);
    ((ushort4*)(outb + (size_t)t * DMODEL))[tid] = o;
  } else {
    ushort4 hi, lo;
    unsigned short h0 = f2bf(r[0]); hi.x = h0; lo.x = f2bf(r[0] - bf2f(h0));
    unsigned short h1 = f2bf(r[1]); hi.y = h1; lo.y = f2bf(r[1] - bf2f(h1));
    unsigned short h2 = f2bf(r[2]); hi.z = h2; lo.z = f2bf(r[2] - bf2f(h2));
    unsigned short h3 = f2bf(r[3]); hi.w = h3; lo.w = f2bf(r[3] - bf2f(h3));
    ((ushort4*)(outb  + (size_t)t * DMODEL))[tid] = hi;
    ((ushort4*)(outlo + (size_t)t * DMODEL))[tid] = lo;
  }
}

// ---------------------------------------------------------------------------
// Split-bf16 MFMA GEMM (fp32-grade): C = (Ah+Al)(Bh+Bl) + bias [+resid].
// ---------------------------------------------------------------------------
template<int EPI>
__global__ __launch_bounds__(256) void mgemm_split(
    const unsigned short* __restrict__ Ah,
    const unsigned short* __restrict__ Alo,
    const unsigned short* __restrict__ Bth,
    const unsigned short* __restrict__ Btl,
    const float* __restrict__ bias,
    const float* __restrict__ resid,
    float* __restrict__ C, int M, int N, int K)
{
  __shared__ unsigned short AH[128][32];
  __shared__ unsigned short AL[128][32];
  __shared__ unsigned short BH[128][32];
  __shared__ unsigned short BL[128][32];
  int tid = threadIdx.x;
  int l = tid & 63, wv = tid >> 6;
  int wr = wv >> 1, wc = wv & 1;
  int m0 = blockIdx.y * 128, n0 = blockIdx.x * 128;
  int rsub = l >> 2, csub = (l & 3) * 8;
  int row0 = wv * 32 + rsub, row1 = row0 + 16;

  const unsigned short* gah0 = Ah  + (size_t)(m0 + row0) * K + csub;
  const unsigned short* gah1 = Ah  + (size_t)(m0 + row1) * K + csub;
  const unsigned short* gal0 = Alo + (size_t)(m0 + row0) * K + csub;
  const unsigned short* gal1 = Alo + (size_t)(m0 + row1) * K + csub;
  const unsigned short* gbh0 = Bth + (size_t)(n0 + row0) * K + csub;
  const unsigned short* gbh1 = Bth + (size_t)(n0 + row1) * K + csub;
  const unsigned short* gbl0 = Btl + (size_t)(n0 + row0) * K + csub;
  const unsigned short* gbl1 = Btl + (size_t)(n0 + row1) * K + csub;

  const f32x4 z = {0.f, 0.f, 0.f, 0.f};
  f32x4 acc[4][4];
  #pragma unroll
  for (int i = 0; i < 4; ++i)
    #pragma unroll
    for (int j = 0; j < 4; ++j) acc[i][j] = z;

  for (int k0 = 0; k0 < K; k0 += 32) {
    __syncthreads();
    gl_lds16(gah0 + k0, &AH[wv * 32][0]);
    gl_lds16(gah1 + k0, &AH[wv * 32 + 16][0]);
    gl_lds16(gal0 + k0, &AL[wv * 32][0]);
    gl_lds16(gal1 + k0, &AL[wv * 32 + 16][0]);
    gl_lds16(gbh0 + k0, &BH[wv * 32][0]);
    gl_lds16(gbh1 + k0, &BH[wv * 32 + 16][0]);
    gl_lds16(gbl0 + k0, &BL[wv * 32][0]);
    gl_lds16(gbl1 + k0, &BL[wv * 32 + 16][0]);
    __syncthreads();

    short8 afh[4], afl[4], bfh[4], bfl[4];
    #pragma unroll
    for (int m = 0; m < 4; ++m) {
      afh[m] = *(const short8*)(&AH[wr * 64 + m * 16 + (l & 15)][(l >> 4) << 3]);
      afl[m] = *(const short8*)(&AL[wr * 64 + m * 16 + (l & 15)][(l >> 4) << 3]);
    }
    #pragma unroll
    for (int n = 0; n < 4; ++n) {
      bfh[n] = *(const short8*)(&BH[wc * 64 + n * 16 + (l & 15)][(l >> 4) << 3]);
      bfl[n] = *(const short8*)(&BL[wc * 64 + n * 16 + (l & 15)][(l >> 4) << 3]);
    }
    #pragma unroll
    for (int m = 0; m < 4; ++m)
      #pragma unroll
      for (int n = 0; n < 4; ++n) {
        acc[m][n] = __builtin_amdgcn_mfma_f32_16x16x32_bf16(afh[m], bfh[n], acc[m][n], 0, 0, 0);
        acc[m][n] = __builtin_amdgcn_mfma_f32_16x16x32_bf16(afl[m], bfh[n], acc[m][n], 0, 0, 0);
        acc[m][n] = __builtin_amdgcn_mfma_f32_16x16x32_bf16(afh[m], bfl[n], acc[m][n], 0, 0, 0);
      }
  }

  int rbase = m0 + wr * 64 + ((l >> 4) << 2);
  int cbase = n0 + wc * 64 + (l & 15);
  #pragma unroll
  for (int n = 0; n < 4; ++n) {
    int col = cbase + n * 16;
    float bv = bias[col];
    #pragma unroll
    for (int m = 0; m < 4; ++m) {
      #pragma unroll
      for (int r = 0; r < 4; ++r) {
        int row = rbase + m * 16 + r;
        float v = acc[m][n][r] + bv;
        if constexpr (EPI == 1) v += resid[(size_t)row * N + col];
        C[(size_t)row * N + col] = v;
      }
    }
  }
}

// ---------------------------------------------------------------------------
// qkv_split: fp32 qkv [T][3][H][64] -> per-head split bf16 arrays.
// ---------------------------------------------------------------------------
__global__ __launch_bounds__(256) void qkv_split(
    const float* __restrict__ qkv,
    unsigned short* __restrict__ Qh, unsigned short* __restrict__ Ql,
    unsigned short* __restrict__ Kh, unsigned short* __restrict__ Kl,
    unsigned short* __restrict__ Vth, unsigned short* __restrict__ Vtl)
{
  __shared__ float Vt[64][68];
  int st = blockIdx.x, bh = blockIdx.y;
  int b = bh >> 4, h = bh & 15;
  int tid = threadIdx.x;
  int row = tid >> 2, cs = (tid & 3) * 16;
  size_t hb = (size_t)bh * SEQ * 64;
  int srow = st * 64 + row;
  size_t src = (size_t)(b * SEQ + srow) * 3072 + (size_t)h * HDIM + cs;

  #pragma unroll
  for (int qk = 0; qk < 2; ++qk) {
    const float* p = qkv + src + qk * 1024;
    unsigned short hi8[16], lo8[16];
    #pragma unroll
    for (int i = 0; i < 16; ++i) {
      float v = p[i];
      unsigned short hh_ = f2bf(v);
      hi8[i] = hh_; lo8[i] = f2bf(v - bf2f(hh_));
    }
    unsigned short* dh = (qk ? Kh : Qh) + hb + (size_t)srow * 64 + cs;
    unsigned short* dl = (qk ? Kl : Ql) + hb + (size_t)srow * 64 + cs;
    *(uint4v*)dh       = *(const uint4v*)&hi8[0];
    *(uint4v*)(dh + 8) = *(const uint4v*)&hi8[8];
    *(uint4v*)dl       = *(const uint4v*)&lo8[0];
    *(uint4v*)(dl + 8) = *(const uint4v*)&lo8[8];
  }
  {
    const float* p = qkv + src + 2048;
    #pragma unroll
    for (int i = 0; i < 4; ++i)
      *(f32x4*)&Vt[row][cs + i * 4] = *(const f32x4*)(p + i * 4);
  }
  __syncthreads();
  {
    int d = tid >> 2, ks = (tid & 3) * 16;
    unsigned short hi8[16], lo8[16];
    #pragma unroll
    for (int j = 0; j < 16; ++j) {
      float v = Vt[ks + j][d];
      unsigned short hh_ = f2bf(v);
      hi8[j] = hh_; lo8[j] = f2bf(v - bf2f(hh_));
    }
    size_t dst = hb + (size_t)d * SEQ + st * 64 + ks;
    *(uint4v*)(Vth + dst)     = *(const uint4v*)&hi8[0];
    *(uint4v*)(Vth + dst + 8) = *(const uint4v*)&hi8[8];
    *(uint4v*)(Vtl + dst)     = *(const uint4v*)&lo8[0];
    *(uint4v*)(Vtl + dst + 8) = *(const uint4v*)&lo8[8];
  }
}

// ---------------------------------------------------------------------------
// attn_mf3: split-bf16 MFMA flash attention, KV-parity + causal-fold.
// ---------------------------------------------------------------------------
__global__ __launch_bounds__(256) void attn_mf3(
    const unsigned short* __restrict__ Qh, const unsigned short* __restrict__ Ql,
    const unsigned short* __restrict__ Kh, const unsigned short* __restrict__ Kl,
    const unsigned short* __restrict__ Vth, const unsigned short* __restrict__ Vtl,
    float* __restrict__ paro,     // [2][TTOK][DMODEL] unnormalized o
    float* __restrict__ parml)    // [2][TTOK][NH][2]  (m, l)
{
  __shared__ unsigned short KVh[64][72], KVl[64][72];
  __shared__ unsigned short Phs[64][72], Pls[64][72];
  int bh = blockIdx.y;
  int b = bh >> 4, h = bh & 15;
  int bx = blockIdx.x;                 // 0..31
  int p  = bx >> 1, par = bx & 1;
  int tid = threadIdx.x, wv = tid >> 6, l = tid & 63;
  int lm = l & 15, lh = l >> 4;
  const size_t hb = (size_t)bh * SEQ * 64;
  int srow = tid >> 2, scs = (tid & 3) * 16;
  int qin = wv * 16 + lh * 4;          // + r = q row within tile
  const f32x4 z = {0.f, 0.f, 0.f, 0.f};

  #pragma unroll 1
  for (int job = 0; job < 2; ++job) {
    int qt = job ? (31 - p) : p;
    int q0 = qt * 64 + wv * 16;

    short8 aQh[2], aQl[2];
    {
      size_t qa = hb + (size_t)(q0 + lm) * 64 + (lh << 3);
      aQh[0] = *(const short8*)(Qh + qa);
      aQh[1] = *(const short8*)(Qh + qa + 32);
      aQl[0] = *(const short8*)(Ql + qa);
      aQl[1] = *(const short8*)(Ql + qa + 32);
    }
    f32x4 ctx[4] = {z, z, z, z};
    float mrun[4] = {-1e4f, -1e4f, -1e4f, -1e4f};
    float lrun[4] = {0.f, 0.f, 0.f, 0.f};

    for (int kt = par; kt <= qt; kt += 2) {
      uint4v vh0, vh1, vl0, vl1;
      {
        size_t vg = hb + (size_t)srow * SEQ + kt * 64 + scs;
        vh0 = *(const uint4v*)(Vth + vg);
        vh1 = *(const uint4v*)(Vth + vg + 8);
        vl0 = *(const uint4v*)(Vtl + vg);
        vl1 = *(const uint4v*)(Vtl + vg + 8);
      }
      __syncthreads();                       // prev PV reads done
      {
        size_t kg = hb + (size_t)(kt * 64 + srow) * 64 + scs;
        *(uint4v*)&KVh[srow][scs]     = *(const uint4v*)(Kh + kg);
        *(uint4v*)&KVh[srow][scs + 8] = *(const uint4v*)(Kh + kg + 8);
        *(uint4v*)&KVl[srow][scs]     = *(const uint4v*)(Kl + kg);
        *(uint4v*)&KVl[srow][scs + 8] = *(const uint4v*)(Kl + kg + 8);
      }
      __syncthreads();                       // K staged

      f32x4 S4[4] = {z, z, z, z};
      #pragma unroll
      for (int n = 0; n < 4; ++n) {
        #pragma unroll
        for (int c = 0; c < 2; ++c) {
          short8 kbh = *(const short8*)&KVh[n * 16 + lm][c * 32 + (lh << 3)];
          short8 kbl = *(const short8*)&KVl[n * 16 + lm][c * 32 + (lh << 3)];
          S4[n] = __builtin_amdgcn_mfma_f32_16x16x32_bf16(aQh[c], kbh, S4[n], 0, 0, 0);
          S4[n] = __builtin_amdgcn_mfma_f32_16x16x32_bf16(aQl[c], kbh, S4[n], 0, 0, 0);
          S4[n] = __builtin_amdgcn_mfma_f32_16x16x32_bf16(aQh[c], kbl, S4[n], 0, 0, 0);
        }
      }
      bool diag = (kt == qt);
      #pragma unroll
      for (int r = 0; r < 4; ++r) {
        float s0 = S4[0][r] * 0.125f, s1 = S4[1][r] * 0.125f;
        float s2 = S4[2][r] * 0.125f, s3 = S4[3][r] * 0.125f;
        if (diag) {
          int qq = qin + r;
          if (lm      > qq) s0 = -1e30f;
          if (16 + lm > qq) s1 = -1e30f;
          if (32 + lm > qq) s2 = -1e30f;
          if (48 + lm > qq) s3 = -1e30f;
        }
        float cm = fmaxf(fmaxf(s0, s1), fmaxf(s2, s3));
        cm = fmaxf(cm, __shfl_xor(cm, 1));
        cm = fmaxf(cm, __shfl_xor(cm, 2));
        cm = fmaxf(cm, __shfl_xor(cm, 4));
        cm = fmaxf(cm, __shfl_xor(cm, 8));
        if (cm > mrun[r] + 8.0f) {           // defer-max (THR=8)
          float sc = __expf(mrun[r] - cm);
          lrun[r] *= sc;
          ctx[0][r] *= sc; ctx[1][r] *= sc; ctx[2][r] *= sc; ctx[3][r] *= sc;
          mrun[r] = cm;
        }
        float p0 = __expf(s0 - mrun[r]), p1 = __expf(s1 - mrun[r]);
        float p2 = __expf(s2 - mrun[r]), p3 = __expf(s3 - mrun[r]);
        float rs = (p0 + p1) + (p2 + p3);
        rs += __shfl_xor(rs, 1); rs += __shfl_xor(rs, 2);
        rs += __shfl_xor(rs, 4); rs += __shfl_xor(rs, 8);
        lrun[r] += rs;
        int prow = qin + r;
        unsigned short e0 = f2bf(p0); Phs[prow][lm]      = e0; Pls[prow][lm]      = f2bf(p0 - bf2f(e0));
        unsigned short e1 = f2bf(p1); Phs[prow][16 + lm] = e1; Pls[prow][16 + lm] = f2bf(p1 - bf2f(e1));
        unsigned short e2 = f2bf(p2); Phs[prow][32 + lm] = e2; Pls[prow][32 + lm] = f2bf(p2 - bf2f(e2));
        unsigned short e3 = f2bf(p3); Phs[prow][48 + lm] = e3; Pls[prow][48 + lm] = f2bf(p3 - bf2f(e3));
      }
      __syncthreads();                       // QK^T reads of KV done
      {
        *(uint4v*)&KVh[srow][scs]     = vh0;
        *(uint4v*)&KVh[srow][scs + 8] = vh1;
        *(uint4v*)&KVl[srow][scs]     = vl0;
        *(uint4v*)&KVl[srow][scs + 8] = vl1;
      }
      __syncthreads();                       // V staged

      #pragma unroll
      for (int c = 0; c < 2; ++c) {
        short8 pah = *(const short8*)&Phs[wv * 16 + lm][c * 32 + (lh << 3)];
        short8 pal = *(const short8*)&Pls[wv * 16 + lm][c * 32 + (lh << 3)];
        #pragma unroll
        for (int n = 0; n < 4; ++n) {
          short8 vbh = *(const short8*)&KVh[n * 16 + lm][c * 32 + (lh << 3)];
          short8 vbl = *(const short8*)&KVl[n * 16 + lm][c * 32 + (lh << 3)];
          ctx[n] = __builtin_amdgcn_mfma_f32_16x16x32_bf16(pah, vbh, ctx[n], 0, 0, 0);
          ctx[n] = __builtin_amdgcn_mfma_f32_16x16x32_bf16(pal, vbh, ctx[n], 0, 0, 0);
          ctx[n] = __builtin_amdgcn_mfma_f32_16x16x32_bf16(pah, vbl, ctx[n], 0, 0, 0);
        }
      }
    }

    // write flash partials for this q-tile
    #pragma unroll
    for (int r = 0; r < 4; ++r) {
      int qg = b * SEQ + qt * 64 + wv * 16 + lh * 4 + r;
      size_t ob = ((size_t)par * TTOK + qg) * DMODEL + (size_t)h * HDIM + lm;
      #pragma unroll
      for (int n = 0; n < 4; ++n) paro[ob + n * 16] = ctx[n][r];
      if (lm == 0) {
        size_t mb = (((size_t)par * TTOK + qg) * NH + h) * 2;
        parml[mb] = mrun[r]; parml[mb + 1] = lrun[r];
      }
    }
  }
}

// ---------------------------------------------------------------------------
// attn_merge<NS>: exact flash merge of NS partials -> ctx hi/lo split.
// ---------------------------------------------------------------------------
template<int NS>
__global__ __launch_bounds__(256) void attn_merge(
    const float* __restrict__ paro,
    const float* __restrict__ parml,
    unsigned short* __restrict__ ctxh,
    unsigned short* __restrict__ ctxl)
{
  int gid = blockIdx.x * 256 + threadIdx.x;
  int ds = gid & 3;
  int h  = (gid >> 2) & 15;
  int t  = gid >> 6;
  float m[NS], lv[NS];
  float mx = -1e30f;
  #pragma unroll
  for (int i = 0; i < NS; ++i) {
    size_t mb = (((size_t)i * TTOK + t) * NH + h) * 2;
    m[i] = parml[mb]; lv[i] = parml[mb + 1];
    mx = fmaxf(mx, m[i]);
  }
  float w[NS], lsum = 0.f;
  #pragma unroll
  for (int i = 0; i < NS; ++i) { w[i] = __expf(m[i] - mx); lsum += lv[i] * w[i]; }
  float inv = 1.0f / lsum;
  size_t ob = (size_t)t * DMODEL + (size_t)h * HDIM + ds * 16;
  #pragma unroll
  for (int i4 = 0; i4 < 4; ++i4) {
    f32x4 v = {0.f, 0.f, 0.f, 0.f};
    #pragma unroll
    for (int i = 0; i < NS; ++i) {
      const f32x4* oi = (const f32x4*)(paro + (size_t)i * TTOK * DMODEL + ob);
      v += oi[i4] * w[i];
    }
    v = v * inv;
    ushort4 hi, lo;
    unsigned short e0 = f2bf(v[0]); hi.x = e0; lo.x = f2bf(v[0] - bf2f(e0));
    unsigned short e1 = f2bf(v[1]); hi.y = e1; lo.y = f2bf(v[1] - bf2f(e1));
    unsigned short e2 = f2bf(v[2]); hi.z = e2; lo.z = f2bf(v[2] - bf2f(e2));
    unsigned short e3 = f2bf(v[3]); hi.w = e3; lo.w = f2bf(v[3] - bf2f(e3));
    *(ushort4*)(ctxh + ob + i4 * 4) = hi;
    *(ushort4*)(ctxl + ob + i4 * 4) = lo;
  }
}

// ---------------------------------------------------------------------------
// Router (fp32)
// ---------------------------------------------------------------------------
__global__ __launch_bounds__(256) void router_kernel(
    const float* __restrict__ x1,
    const float* __restrict__ gam,
    const float* __restrict__ bet,
    const float* __restrict__ wrt,
    int* __restrict__ ctrl,
    int2* __restrict__ t_e,
    float2* __restrict__ t_g)
{
  int w = threadIdx.x >> 6, l = threadIdx.x & 63;
  int t = blockIdx.x * 4 + w;
  const f32x4* row = (const f32x4*)(x1 + (size_t)t * DMODEL);
  f32x4 v[4];
  float s = 0.f, sq = 0.f;
  #pragma unroll
  for (int i = 0; i < 4; ++i) {
    v[i] = row[l + i * 64];
    #pragma unroll
    for (int j = 0; j < 4; ++j) { s += v[i][j]; sq += v[i][j] * v[i][j]; }
  }
  #pragma unroll
  for (int off = 1; off < 64; off <<= 1) {
    s  += __shfl_xor(s, off);
    sq += __shfl_xor(sq, off);
  }
  float mu  = s * (1.0f / DMODEL);
  float var = sq * (1.0f / DMODEL) - mu * mu;
  float rs  = rsqrtf(var + 1e-5f);

  float acc[NE] = {0.f, 0.f, 0.f, 0.f, 0.f, 0.f, 0.f, 0.f};
  #pragma unroll
  for (int i = 0; i < 4; ++i) {
    int base = (l + i * 64) * 4;
    #pragma unroll
    for (int j = 0; j < 4; ++j) {
      int idx = base + j;
      float xn = (v[i][j] - mu) * rs * gam[idx] + bet[idx];
      const f32x4* wr0 = (const f32x4*)(wrt + idx * NE);
      f32x4 w0 = wr0[0], w1v = wr0[1];
      acc[0] += xn * w0[0]; acc[1] += xn * w0[1];
      acc[2] += xn * w0[2]; acc[3] += xn * w0[3];
      acc[4] += xn * w1v[0]; acc[5] += xn * w1v[1];
      acc[6] += xn * w1v[2]; acc[7] += xn * w1v[3];
    }
  }
  #pragma unroll
  for (int e = 0; e < NE; ++e) {
    #pragma unroll
    for (int off = 1; off < 64; off <<= 1) acc[e] += __shfl_xor(acc[e], off);
  }
  if (l == 0) {
    int e0 = 0; float m0v = acc[0];
    #pragma unroll
    for (int e = 1; e < NE; ++e) if (acc[e] > m0v) { m0v = acc[e]; e0 = e; }
    int e1 = -1; float m1v = -1e30f;
    #pragma unroll
    for (int e = 0; e < NE; ++e) if (e != e0 && acc[e] > m1v) { m1v = acc[e]; e1 = e; }
    float r = __expf(m1v - m0v);
    float g0 = 1.0f / (1.0f + r);
    float g1 = r * g0;
    t_e[t] = make_int2(e0, e1);
    t_g[t] = make_float2(g0, g1);
    atomicAdd(&ctrl[C_CNT + e0], 1);
    atomicAdd(&ctrl[C_CNT + e1], 1);
  }
}

// ---------------------------------------------------------------------------
// Scan: 128-padded per-expert slot bases + 128-row m-tile table.
// ---------------------------------------------------------------------------
__global__ void scan_kernel(int* __restrict__ ctrl)
{
  if (threadIdx.x == 0 && blockIdx.x == 0) {
    int b = 0, m = 0;
    for (int e = 0; e < NE; ++e) {
      ctrl[C_BASE + e] = b;
      int pc = (ctrl[C_CNT + e] + 127) & ~127;
      int nt = pc >> 7;
      for (int i = 0; i < nt; ++i) {
        ctrl[C_MTE + m] = e;
        ctrl[C_MTS + m] = b + (i << 7);
        ++m;
      }
      b += pc;
    }
    ctrl[C_NMT] = m;
  }
}

// ---------------------------------------------------------------------------
__global__ __launch_bounds__(256) void gather_kernel(
    int* __restrict__ ctrl,
    const int2* __restrict__ t_e,
    const float2* __restrict__ t_g,
    int* __restrict__ slot_token,
    float* __restrict__ slot_gate)
{
  int t = blockIdx.x * 256 + threadIdx.x;
  int2 e = t_e[t];
  float2 g = t_g[t];
  int p0 = atomicAdd(&ctrl[C_FILL + e.x], 1);
  int s0 = ctrl[C_BASE + e.x] + p0;
  slot_token[s0] = t; slot_gate[s0] = g.x;
  int p1 = atomicAdd(&ctrl[C_FILL + e.y], 1);
  int s1 = ctrl[C_BASE + e.y] + p1;
  slot_token[s1] = t; slot_gate[s1] = g.y;
}

// ---------------------------------------------------------------------------
// Transpose + fp32->bf16: in [E][K][N] fp32 -> out [E][N][K] bf16.
// ---------------------------------------------------------------------------
__global__ __launch_bounds__(256) void transpose_conv(
    const float* __restrict__ in, unsigned short* __restrict__ outb,
    unsigned short* __restrict__ outlo, int K, int N)
{
  __shared__ float T[64][68];
  int e = blockIdx.z;
  int n0 = blockIdx.x * 64, k0 = blockIdx.y * 64;
  const float* src = in + (size_t)e * K * N;
  unsigned short* dst = outb + (size_t)e * K * N;
  unsigned short* dstl = outlo ? outlo + (size_t)e * K * N : nullptr;
  int tid = threadIdx.x;
  int r = tid >> 4, c4 = (tid & 15) * 4;
  #pragma unroll
  for (int i = 0; i < 4; ++i) {
    f32x4 v = *(const f32x4*)(src + (size_t)(k0 + r + i * 16) * N + n0 + c4);
    *(f32x4*)(&T[r + i * 16][c4]) = v;
  }
  __syncthreads();
  #pragma unroll
  for (int i = 0; i < 4; ++i) {
    int rr = r + i * 16;
    float v0 = T[c4 + 0][rr], v1 = T[c4 + 1][rr];
    float v2 = T[c4 + 2][rr], v3 = T[c4 + 3][rr];
    ushort4 o;
    o.x = f2bf(v0); o.y = f2bf(v1); o.z = f2bf(v2); o.w = f2bf(v3);
    *(ushort4*)(dst + (size_t)(n0 + rr) * K + k0 + c4) = o;
    if (dstl) {
      ushort4 lo;
      lo.x = f2bf(v0 - bf2f(o.x));
      lo.y = f2bf(v1 - bf2f(o.y));
      lo.z = f2bf(v2 - bf2f(o.z));
      lo.w = f2bf(v3 - bf2f(o.w));
      *(ushort4*)(dstl + (size_t)(n0 + rr) * K + k0 + c4) = lo;
    }
  }
}

// ---------------------------------------------------------------------------
// Fast sparse MoE w1 (global_load_lds staging, unpadded [128][32] LDS).
// ---------------------------------------------------------------------------
__global__ __launch_bounds__(256) void moe_w1f(
    const unsigned short* __restrict__ h2,
    const unsigned short* __restrict__ w1t,
    const float* __restrict__ b1,
    const int* __restrict__ ctrl,
    const int* __restrict__ slot_token,
    unsigned short* __restrict__ Hs)
{
  int mt = blockIdx.y;
  if (mt >= ctrl[C_NMT]) return;
  int e = ctrl[C_MTE + mt];
  int slot0 = ctrl[C_MTS + mt];
  const int N = DFF, K = DMODEL;
  const unsigned short* Bt = w1t + (size_t)e * K * N;
  const float* bias = b1 + (size_t)e * DFF;

  __shared__ unsigned short Al[128][32];
  __shared__ unsigned short Bl[128][32];
  __shared__ int tokrow[128];
  int tid = threadIdx.x;
  if (tid < 128) {
    int tk = slot_token[slot0 + tid];
    tokrow[tid] = tk < 0 ? 0 : tk;
  }
  __syncthreads();
  int l = tid & 63, wv = tid >> 6;
  int wr = wv >> 1, wc = wv & 1;
  int n0 = blockIdx.x * 128;
  int rsub = l >> 2, csub = (l & 3) * 8;
  int row0 = wv * 32 + rsub, row1 = row0 + 16;
  const unsigned short* ga0 = h2 + (size_t)tokrow[row0] * DMODEL + csub;
  const unsigned short* ga1 = h2 + (size_t)tokrow[row1] * DMODEL + csub;
  const unsigned short* gb0 = Bt + (size_t)(n0 + row0) * K + csub;
  const unsigned short* gb1 = Bt + (size_t)(n0 + row1) * K + csub;

  const f32x4 z = {0.f, 0.f, 0.f, 0.f};
  f32x4 acc[4][4];
  #pragma unroll
  for (int i = 0; i < 4; ++i)
    #pragma unroll
    for (int j = 0; j < 4; ++j) acc[i][j] = z;

  for (int k0 = 0; k0 < K; k0 += 32) {
    __syncthreads();
    gl_lds16(ga0 + k0, &Al[wv * 32][0]);
    gl_lds16(ga1 + k0, &Al[wv * 32 + 16][0]);
    gl_lds16(gb0 + k0, &Bl[wv * 32][0]);
    gl_lds16(gb1 + k0, &Bl[wv * 32 + 16][0]);
    __syncthreads();

    short8 af[4], bfr[4];
    #pragma unroll
    for (int m = 0; m < 4; ++m)
      af[m] = *(const short8*)(&Al[wr * 64 + m * 16 + (l & 15)][(l >> 4) << 3]);
    #pragma unroll
    for (int n = 0; n < 4; ++n)
      bfr[n] = *(const short8*)(&Bl[wc * 64 + n * 16 + (l & 15)][(l >> 4) << 3]);
    #pragma unroll
    for (int m = 0; m < 4; ++m)
      #pragma unroll
      for (int n = 0; n < 4; ++n)
        acc[m][n] = __builtin_amdgcn_mfma_f32_16x16x32_bf16(af[m], bfr[n], acc[m][n], 0, 0, 0);
  }

  int rbase = wr * 64 + ((l >> 4) << 2);
  int cbase = n0 + wc * 64 + (l & 15);
  #pragma unroll
  for (int n = 0; n < 4; ++n) {
    int col = cbase + n * 16;
    float bv = bias[col];
    #pragma unroll
    for (int m = 0; m < 4; ++m) {
      #pragma unroll
      for (int r = 0; r < 4; ++r) {
        int srow = slot0 + rbase + m * 16 + r;
        float v = acc[m][n][r] + bv;
        v = 0.5f * v * (1.0f + erff(v * 0.70710678118654752f));
        Hs[(size_t)srow * DFF + col] = f2bf(v);
      }
    }
  }
}

// ---------------------------------------------------------------------------
// Fast sparse MoE w2, BM=128 + K-split (gridDim.z = 2):
//   ffn[token] += gate * (Hs[slot][ks] @ w2t[e][ks]^T + (ks==0)*b2[e]).
// ---------------------------------------------------------------------------
__global__ __launch_bounds__(256) void moe_w2f(
    const unsigned short* __restrict__ Hs,
    const unsigned short* __restrict__ w2t,
    const float* __restrict__ b2,
    const int* __restrict__ ctrl,
    const int* __restrict__ slot_token,
    const float* __restrict__ slot_gate,
    float* __restrict__ ffn)
{
  int mt = blockIdx.y;
  if (mt >= ctrl[C_NMT]) return;
  int e = ctrl[C_MTE + mt];
  int slot0 = ctrl[C_MTS + mt];
  int ks = blockIdx.z;                 // K half: [ks*2048, ks*2048+2048)
  const int N = DMODEL, K = DFF;
  const unsigned short* Bt = w2t + (size_t)e * (size_t)K * N;
  const float* bias = b2 + (size_t)e * DMODEL;

  __shared__ unsigned short Al[128][32];
  __shared__ unsigned short Bl[128][32];
  int tid = threadIdx.x;
  int l = tid & 63, wv = tid >> 6;
  int wr = wv >> 1, wc = wv & 1;
  int n0 = blockIdx.x * 128;
  int rsub = l >> 2, csub = (l & 3) * 8;
  int row0 = wv * 32 + rsub, row1 = row0 + 16;
  const unsigned short* ga0 = Hs + (size_t)(slot0 + row0) * DFF + csub;
  const unsigned short* ga1 = Hs + (size_t)(slot0 + row1) * DFF + csub;
  const unsigned short* gb0 = Bt + (size_t)(n0 + row0) * K + csub;
  const unsigned short* gb1 = Bt + (size_t)(n0 + row1) * K + csub;

  const f32x4 z = {0.f, 0.f, 0.f, 0.f};
  f32x4 acc[4][4];
  #pragma unroll
  for (int i = 0; i < 4; ++i)
    #pragma unroll
    for (int j = 0; j < 4; ++j) acc[i][j] = z;

  int kbeg = ks * (K / 2), kend = kbeg + (K / 2);
  for (int k0 = kbeg; k0 < kend; k0 += 32) {
    __syncthreads();
    gl_lds16(ga0 + k0, &Al[wv * 32][0]);
    gl_lds16(ga1 + k0, &Al[wv * 32 + 16][0]);
    gl_lds16(gb0 + k0, &Bl[wv * 32][0]);
    gl_lds16(gb1 + k0, &Bl[wv * 32 + 16][0]);
    __syncthreads();

    short8 af[4], bfr[4];
    #pragma unroll
    for (int m = 0; m < 4; ++m)
      af[m] = *(const short8*)(&Al[wr * 64 + m * 16 + (l & 15)][(l >> 4) << 3]);
    #pragma unroll
    for (int n = 0; n < 4; ++n)
      bfr[n] = *(const short8*)(&Bl[wc * 64 + n * 16 + (l & 15)][(l >> 4) << 3]);
    #pragma unroll
    for (int m = 0; m < 4; ++m)
      #pragma unroll
      for (int n = 0; n < 4; ++n)
        acc[m][n] = __builtin_amdgcn_mfma_f32_16x16x32_bf16(af[m], bfr[n], acc[m][n], 0, 0, 0);
  }

  int rbase = wr * 64 + ((l >> 4) << 2);
  int cbase = n0 + wc * 64 + (l & 15);
  #pragma unroll
  for (int n = 0; n < 4; ++n) {
    int col = cbase + n * 16;
    float bv = (ks == 0) ? bias[col] : 0.0f;
    #pragma unroll
    for (int m = 0; m < 4; ++m) {
      #pragma unroll
      for (int r = 0; r < 4; ++r) {
        int srow = slot0 + rbase + m * 16 + r;
        int tok = slot_token[srow];
        if (tok >= 0) {
          float v = acc[m][n][r] + bv;
          atomicAdd(&ffn[(size_t)tok * DMODEL + col], slot_gate[srow] * v);
        }
      }
    }
  }
}

// ---------------------------------------------------------------------------
__global__ __launch_bounds__(256) void final_add(
    const float* __restrict__ x1,
    const float* __restrict__ ffn,
    float* __restrict__ out)
{
  int i = blockIdx.x * 256 + threadIdx.x;
  f32x4 xr = ((const f32x4*)x1)[i];
  f32x4 fr = ((const f32x4*)ffn)[i];
  f32x4 o;
  o[0] = xr[0] + fr[0];
  o[1] = xr[1] + fr[1];
  o[2] = xr[2] + fr[2];
  o[3] = xr[3] + fr[3];
  ((f32x4*)out)[i] = o;
}

// ---------------------------------------------------------------------------
extern "C" void kernel_launch(void* const* d_in, const int* in_sizes, int n_in,
                              void* d_out, int out_size, void* d_ws, size_t ws_size,
                              hipStream_t stream) {
  (void)in_sizes; (void)n_in; (void)out_size;
  const float* x     = (const float*)d_in[0];
  const float* ln1_g = (const float*)d_in[1];
  const float* ln1_b = (const float*)d_in[2];
  const float* ln2_g = (const float*)d_in[3];
  const float* ln2_b = (const float*)d_in[4];
  const float* wqkv  = (const float*)d_in[5];
  const float* bqkv  = (const float*)d_in[6];
  const float* wo    = (const float*)d_in[7];
  const float* bo    = (const float*)d_in[8];
  const float* wrt   = (const float*)d_in[9];
  const float* w1    = (const float*)d_in[10];
  const float* b1    = (const float*)d_in[11];
  const float* w2    = (const float*)d_in[12];
  const float* b2    = (const float*)d_in[13];
  float* out = (float*)d_out;

  char* ws = (char*)d_ws;
  size_t off = 0;
  auto alloc = [&](size_t bytes) -> void* {
    void* p = ws + off;
    off += (bytes + 255) & ~(size_t)255;
    return p;
  };
  float*          x1    = (float*)alloc((size_t)TTOK * DMODEL * 4);
  unsigned short* h2    = (unsigned short*)alloc((size_t)TTOK * DMODEL * 2);
  int*            ctrl  = (int*)alloc(1024);
  int2*           t_e   = (int2*)alloc((size_t)TTOK * 8);
  float2*         t_g   = (float2*)alloc((size_t)TTOK * 8);
  int*            slot_token = (int*)alloc((size_t)SLOT_MAX * 4);
  float*          slot_gate  = (float*)alloc((size_t)SLOT_MAX * 4);
  float*          P1    = (float*)alloc((size_t)TTOK * DMODEL * 4);
  char*           P2    = (char*)alloc((size_t)SLOT_MAX * DFF * 2);
  unsigned short* w1t   = (unsigned short*)alloc((size_t)NE * DMODEL * DFF * 2);
  unsigned short* w2t   = (unsigned short*)alloc((size_t)NE * DFF * DMODEL * 2);
  unsigned short* wqkvTh = (unsigned short*)alloc((size_t)DMODEL * 3 * DMODEL * 2);
  unsigned short* wqkvTl = (unsigned short*)alloc((size_t)DMODEL * 3 * DMODEL * 2);
  unsigned short* woTh  = (unsigned short*)alloc((size_t)DMODEL * DMODEL * 2);
  unsigned short* woTl  = (unsigned short*)alloc((size_t)DMODEL * DMODEL * 2);
  unsigned short* hh    = (unsigned short*)alloc((size_t)TTOK * DMODEL * 2);
  unsigned short* hl    = (unsigned short*)alloc((size_t)TTOK * DMODEL * 2);
  unsigned short* ctxh  = (unsigned short*)alloc((size_t)TTOK * DMODEL * 2);
  unsigned short* ctxl  = (unsigned short*)alloc((size_t)TTOK * DMODEL * 2);
  // MFMA attention split-qkv arrays + flash partials
  size_t headsz = (size_t)NB * NH * SEQ * HDIM;   // elems per array
  unsigned short* Qh  = (unsigned short*)alloc(headsz * 2);
  unsigned short* Ql  = (unsigned short*)alloc(headsz * 2);
  unsigned short* Khp = (unsigned short*)alloc(headsz * 2);
  unsigned short* Klp = (unsigned short*)alloc(headsz * 2);
  unsigned short* Vth = (unsigned short*)alloc(headsz * 2);
  unsigned short* Vtl = (unsigned short*)alloc(headsz * 2);
  float*          paro2  = (float*)alloc((size_t)2 * TTOK * DMODEL * 4);
  float*          parml2 = (float*)alloc((size_t)2 * TTOK * NH * 2 * 4);

  float*          qkv  = (float*)P2;        // dead before Hs is written
  float*          ffn  = P1;
  unsigned short* Hs   = (unsigned short*)P2;

  // 0) zero control counters, mark all slots invalid
  hipMemsetAsync(ctrl, 0, 16 * 4, stream);
  hipMemsetAsync(slot_token, 0xFF, (size_t)SLOT_MAX * 4, stream);

  // 0b) weight prep
  transpose_conv<<<dim3(DFF / 64, DMODEL / 64, NE), 256, 0, stream>>>(
      w1, w1t, nullptr, DMODEL, DFF);
  transpose_conv<<<dim3(DMODEL / 64, DFF / 64, NE), 256, 0, stream>>>(
      w2, w2t, nullptr, DFF, DMODEL);
  transpose_conv<<<dim3(3 * DMODEL / 64, DMODEL / 64, 1), 256, 0, stream>>>(
      wqkv, wqkvTh, wqkvTl, DMODEL, 3 * DMODEL);
  transpose_conv<<<dim3(DMODEL / 64, DMODEL / 64, 1), 256, 0, stream>>>(
      wo, woTh, woTl, DMODEL, DMODEL);

  // 1) h = LN1(x) -> split hi/lo
  ln_kernel<2><<<TTOK, 256, 0, stream>>>(x, ln1_g, ln1_b, nullptr, hh, hl);
  // 2) qkv = h @ wqkv + bqkv   (split-bf16 MFMA, fp32-grade)
  mgemm_split<0><<<dim3(3 * DMODEL / 128, TTOK / 128), 256, 0, stream>>>(
      hh, hl, wqkvTh, wqkvTl, bqkv, nullptr, qkv, TTOK, 3 * DMODEL, DMODEL);
  // 3) ctx = causal attention (split-bf16 MFMA flash, parity+fold) -> merge
  qkv_split<<<dim3(SEQ / 64, NB * NH), 256, 0, stream>>>(
      qkv, Qh, Ql, Khp, Klp, Vth, Vtl);
  attn_mf3<<<dim3(32, NB * NH), 256, 0, stream>>>(
      Qh, Ql, Khp, Klp, Vth, Vtl, paro2, parml2);
  attn_merge<2><<<(TTOK * NH * 4) / 256, 256, 0, stream>>>(
      paro2, parml2, ctxh, ctxl);
  // 4) x1 = x + ctx @ wo + bo  (split-bf16 MFMA)
  mgemm_split<1><<<dim3(DMODEL / 128, TTOK / 128), 256, 0, stream>>>(
      ctxh, ctxl, woTh, woTl, bo, x, x1, TTOK, DMODEL, DMODEL);

  // 5) h2 = LN2(x1)
  ln_kernel<1><<<TTOK, 256, 0, stream>>>(x1, ln2_g, ln2_b, nullptr, h2, nullptr);
  // 6) router -> scan -> gather
  router_kernel<<<TTOK / 4, 256, 0, stream>>>(x1, ln2_g, ln2_b, wrt, ctrl, t_e, t_g);
  scan_kernel<<<1, 64, 0, stream>>>(ctrl);
  gather_kernel<<<TTOK / 256, 256, 0, stream>>>(ctrl, t_e, t_g, slot_token, slot_gate);
  // 7) sparse MoE (BM=128 proven config; w2 K-split x2 for latency hiding)
  hipMemsetAsync(ffn, 0, (size_t)TTOK * DMODEL * 4, stream);
  moe_w1f<<<dim3(DFF / 128, MT_MAX), 256, 0, stream>>>(
      h2, w1t, b1, ctrl, slot_token, Hs);
  moe_w2f<<<dim3(DMODEL / 128, MT_MAX, 2), 256, 0, stream>>>(
      Hs, w2t, b2, ctrl, slot_token, slot_gate, ffn);
  // 8) out = x1 + ffn
  final_add<<<(TTOK * DMODEL / 4) / 256, 256, 0, stream>>>(x1, ffn, out);
}

// Round 19
// 902.146 us; speedup vs baseline: 1.3721x; 1.0211x over previous
//
#include <hip/hip_runtime.h>
#include <hip/hip_bf16.h>
#include <math.h>

// Problem constants
#define NB    2
#define SEQ   2048
#define DMODEL 1024
#define NH    16
#define HDIM  64
#define NE    8
#define DFF   4096
#define TTOK  4096   // NB*SEQ

#define MT_MAX   72
#define SLOT_MAX 9216

// ctrl block layout (ints)
#define C_CNT  0
#define C_FILL 8
#define C_BASE 16
#define C_NMT  24
#define C_MTE  32
#define C_MTS  104

typedef __attribute__((ext_vector_type(8))) short short8;
typedef __attribute__((ext_vector_type(4))) float f32x4;
typedef __attribute__((ext_vector_type(4))) unsigned int uint4v;

static __device__ __forceinline__ float bf2f(unsigned short u) {
  union { unsigned int i; float f; } c; c.i = ((unsigned int)u) << 16; return c.f;
}
static __device__ __forceinline__ unsigned short f2bf(float f) {
  unsigned int x = __float_as_uint(f);
  unsigned int r = (x + 0x7FFFu + ((x >> 16) & 1u)) >> 16;
  return (unsigned short)r;
}

// Async global->LDS, 16B per lane. LDS dest is WAVE-UNIFORM base + lane*16.
static __device__ __forceinline__ void gl_lds16(const void* g, void* l) {
  __builtin_amdgcn_global_load_lds(
      (const __attribute__((address_space(1))) unsigned int*)(uintptr_t)g,
      (__attribute__((address_space(3))) unsigned int*)(uintptr_t)l,
      16, 0, 0);
}

// ---------------------------------------------------------------------------
// LayerNorm. MODE 0: fp32 out. MODE 1: bf16 out. MODE 2: split hi/lo bf16.
// ---------------------------------------------------------------------------
template<int MODE>
__global__ __launch_bounds__(256) void ln_kernel(
    const float* __restrict__ x,
    const float* __restrict__ gam,
    const float* __restrict__ bet,
    float* __restrict__ outf,
    unsigned short* __restrict__ outb,
    unsigned short* __restrict__ outlo)
{
  int t = blockIdx.x, tid = threadIdx.x;
  f32x4 v = ((const f32x4*)(x + (size_t)t * DMODEL))[tid];
  float s  = v[0] + v[1] + v[2] + v[3];
  float sq = v[0]*v[0] + v[1]*v[1] + v[2]*v[2] + v[3]*v[3];
  #pragma unroll
  for (int off = 1; off < 64; off <<= 1) {
    s  += __shfl_xor(s, off);
    sq += __shfl_xor(sq, off);
  }
  __shared__ float red[8];
  int w = tid >> 6, l = tid & 63;
  if (l == 0) { red[w] = s; red[4 + w] = sq; }
  __syncthreads();
  s  = red[0] + red[1] + red[2] + red[3];
  sq = red[4] + red[5] + red[6] + red[7];
  float mu  = s * (1.0f / DMODEL);
  float var = sq * (1.0f / DMODEL) - mu * mu;
  float rs  = rsqrtf(var + 1e-5f);
  f32x4 g = ((const f32x4*)gam)[tid];
  f32x4 b = ((const f32x4*)bet)[tid];
  float r[4];
  r[0] = (v[0] - mu) * rs * g[0] + b[0];
  r[1] = (v[1] - mu) * rs * g[1] + b[1];
  r[2] = (v[2] - mu) * rs * g[2] + b[2];
  r[3] = (v[3] - mu) * rs * g[3] + b[3];
  if constexpr (MODE == 0) {
    f32x4 o = {r[0], r[1], r[2], r[3]};
    ((f32x4*)(outf + (size_t)t * DMODEL))[tid] = o;
  } else if constexpr (MODE == 1) {
    ushort4 o; o.x = f2bf(r[0]); o.y = f2bf(r[1]); o.z = f2bf(r[2]); o.w = f2bf(r[3]);
    ((ushort4*)(outb + (size_t)t * DMODEL))[tid] = o;
  } else {
    ushort4 hi, lo;
    unsigned short h0 = f2bf(r[0]); hi.x = h0; lo.x = f2bf(r[0] - bf2f(h0));
    unsigned short h1 = f2bf(r[1]); hi.y = h1; lo.y = f2bf(r[1] - bf2f(h1));
    unsigned short h2 = f2bf(r[2]); hi.z = h2; lo.z = f2bf(r[2] - bf2f(h2));
    unsigned short h3 = f2bf(r[3]); hi.w = h3; lo.w = f2bf(r[3] - bf2f(h3));
    ((ushort4*)(outb  + (size_t)t * DMODEL))[tid] = hi;
    ((ushort4*)(outlo + (size_t)t * DMODEL))[tid] = lo;
  }
}

// ---------------------------------------------------------------------------
// Split-bf16 MFMA GEMM (fp32-grade): C = (Ah+Al)(Bh+Bl) + bias [+resid].
// ---------------------------------------------------------------------------
template<int EPI>
__global__ __launch_bounds__(256) void mgemm_split(
    const unsigned short* __restrict__ Ah,
    const unsigned short* __restrict__ Alo,
    const unsigned short* __restrict__ Bth,
    const unsigned short* __restrict__ Btl,
    const float* __restrict__ bias,
    const float* __restrict__ resid,
    float* __restrict__ C, int M, int N, int K)
{
  __shared__ unsigned short AH[128][32];
  __shared__ unsigned short AL[128][32];
  __shared__ unsigned short BH[128][32];
  __shared__ unsigned short BL[128][32];
  int tid = threadIdx.x;
  int l = tid & 63, wv = tid >> 6;
  int wr = wv >> 1, wc = wv & 1;
  int m0 = blockIdx.y * 128, n0 = blockIdx.x * 128;
  int rsub = l >> 2, csub = (l & 3) * 8;
  int row0 = wv * 32 + rsub, row1 = row0 + 16;

  const unsigned short* gah0 = Ah  + (size_t)(m0 + row0) * K + csub;
  const unsigned short* gah1 = Ah  + (size_t)(m0 + row1) * K + csub;
  const unsigned short* gal0 = Alo + (size_t)(m0 + row0) * K + csub;
  const unsigned short* gal1 = Alo + (size_t)(m0 + row1) * K + csub;
  const unsigned short* gbh0 = Bth + (size_t)(n0 + row0) * K + csub;
  const unsigned short* gbh1 = Bth + (size_t)(n0 + row1) * K + csub;
  const unsigned short* gbl0 = Btl + (size_t)(n0 + row0) * K + csub;
  const unsigned short* gbl1 = Btl + (size_t)(n0 + row1) * K + csub;

  const f32x4 z = {0.f, 0.f, 0.f, 0.f};
  f32x4 acc[4][4];
  #pragma unroll
  for (int i = 0; i < 4; ++i)
    #pragma unroll
    for (int j = 0; j < 4; ++j) acc[i][j] = z;

  for (int k0 = 0; k0 < K; k0 += 32) {
    __syncthreads();
    gl_lds16(gah0 + k0, &AH[wv * 32][0]);
    gl_lds16(gah1 + k0, &AH[wv * 32 + 16][0]);
    gl_lds16(gal0 + k0, &AL[wv * 32][0]);
    gl_lds16(gal1 + k0, &AL[wv * 32 + 16][0]);
    gl_lds16(gbh0 + k0, &BH[wv * 32][0]);
    gl_lds16(gbh1 + k0, &BH[wv * 32 + 16][0]);
    gl_lds16(gbl0 + k0, &BL[wv * 32][0]);
    gl_lds16(gbl1 + k0, &BL[wv * 32 + 16][0]);
    __syncthreads();

    short8 afh[4], afl[4], bfh[4], bfl[4];
    #pragma unroll
    for (int m = 0; m < 4; ++m) {
      afh[m] = *(const short8*)(&AH[wr * 64 + m * 16 + (l & 15)][(l >> 4) << 3]);
      afl[m] = *(const short8*)(&AL[wr * 64 + m * 16 + (l & 15)][(l >> 4) << 3]);
    }
    #pragma unroll
    for (int n = 0; n < 4; ++n) {
      bfh[n] = *(const short8*)(&BH[wc * 64 + n * 16 + (l & 15)][(l >> 4) << 3]);
      bfl[n] = *(const short8*)(&BL[wc * 64 + n * 16 + (l & 15)][(l >> 4) << 3]);
    }
    #pragma unroll
    for (int m = 0; m < 4; ++m)
      #pragma unroll
      for (int n = 0; n < 4; ++n) {
        acc[m][n] = __builtin_amdgcn_mfma_f32_16x16x32_bf16(afh[m], bfh[n], acc[m][n], 0, 0, 0);
        acc[m][n] = __builtin_amdgcn_mfma_f32_16x16x32_bf16(afl[m], bfh[n], acc[m][n], 0, 0, 0);
        acc[m][n] = __builtin_amdgcn_mfma_f32_16x16x32_bf16(afh[m], bfl[n], acc[m][n], 0, 0, 0);
      }
  }

  int rbase = m0 + wr * 64 + ((l >> 4) << 2);
  int cbase = n0 + wc * 64 + (l & 15);
  #pragma unroll
  for (int n = 0; n < 4; ++n) {
    int col = cbase + n * 16;
    float bv = bias[col];
    #pragma unroll
    for (int m = 0; m < 4; ++m) {
      #pragma unroll
      for (int r = 0; r < 4; ++r) {
        int row = rbase + m * 16 + r;
        float v = acc[m][n][r] + bv;
        if constexpr (EPI == 1) v += resid[(size_t)row * N + col];
        C[(size_t)row * N + col] = v;
      }
    }
  }
}

// ---------------------------------------------------------------------------
// qkv_split: fp32 qkv [T][3][H][64] -> per-head split bf16 arrays.
// ---------------------------------------------------------------------------
__global__ __launch_bounds__(256) void qkv_split(
    const float* __restrict__ qkv,
    unsigned short* __restrict__ Qh, unsigned short* __restrict__ Ql,
    unsigned short* __restrict__ Kh, unsigned short* __restrict__ Kl,
    unsigned short* __restrict__ Vth, unsigned short* __restrict__ Vtl)
{
  __shared__ float Vt[64][68];
  int st = blockIdx.x, bh = blockIdx.y;
  int b = bh >> 4, h = bh & 15;
  int tid = threadIdx.x;
  int row = tid >> 2, cs = (tid & 3) * 16;
  size_t hb = (size_t)bh * SEQ * 64;
  int srow = st * 64 + row;
  size_t src = (size_t)(b * SEQ + srow) * 3072 + (size_t)h * HDIM + cs;

  #pragma unroll
  for (int qk = 0; qk < 2; ++qk) {
    const float* p = qkv + src + qk * 1024;
    unsigned short hi8[16], lo8[16];
    #pragma unroll
    for (int i = 0; i < 16; ++i) {
      float v = p[i];
      unsigned short hh_ = f2bf(v);
      hi8[i] = hh_; lo8[i] = f2bf(v - bf2f(hh_));
    }
    unsigned short* dh = (qk ? Kh : Qh) + hb + (size_t)srow * 64 + cs;
    unsigned short* dl = (qk ? Kl : Ql) + hb + (size_t)srow * 64 + cs;
    *(uint4v*)dh       = *(const uint4v*)&hi8[0];
    *(uint4v*)(dh + 8) = *(const uint4v*)&hi8[8];
    *(uint4v*)dl       = *(const uint4v*)&lo8[0];
    *(uint4v*)(dl + 8) = *(const uint4v*)&lo8[8];
  }
  {
    const float* p = qkv + src + 2048;
    #pragma unroll
    for (int i = 0; i < 4; ++i)
      *(f32x4*)&Vt[row][cs + i * 4] = *(const f32x4*)(p + i * 4);
  }
  __syncthreads();
  {
    int d = tid >> 2, ks = (tid & 3) * 16;
    unsigned short hi8[16], lo8[16];
    #pragma unroll
    for (int j = 0; j < 16; ++j) {
      float v = Vt[ks + j][d];
      unsigned short hh_ = f2bf(v);
      hi8[j] = hh_; lo8[j] = f2bf(v - bf2f(hh_));
    }
    size_t dst = hb + (size_t)d * SEQ + st * 64 + ks;
    *(uint4v*)(Vth + dst)     = *(const uint4v*)&hi8[0];
    *(uint4v*)(Vth + dst + 8) = *(const uint4v*)&hi8[8];
    *(uint4v*)(Vtl + dst)     = *(const uint4v*)&lo8[0];
    *(uint4v*)(Vtl + dst + 8) = *(const uint4v*)&lo8[8];
  }
}

// ---------------------------------------------------------------------------
// attn_mf3: split-bf16 MFMA flash attention, KV-parity + causal-fold.
// ---------------------------------------------------------------------------
__global__ __launch_bounds__(256) void attn_mf3(
    const unsigned short* __restrict__ Qh, const unsigned short* __restrict__ Ql,
    const unsigned short* __restrict__ Kh, const unsigned short* __restrict__ Kl,
    const unsigned short* __restrict__ Vth, const unsigned short* __restrict__ Vtl,
    float* __restrict__ paro,     // [2][TTOK][DMODEL] unnormalized o
    float* __restrict__ parml)    // [2][TTOK][NH][2]  (m, l)
{
  __shared__ unsigned short KVh[64][72], KVl[64][72];
  __shared__ unsigned short Phs[64][72], Pls[64][72];
  int bh = blockIdx.y;
  int b = bh >> 4, h = bh & 15;
  int bx = blockIdx.x;                 // 0..31
  int p  = bx >> 1, par = bx & 1;
  int tid = threadIdx.x, wv = tid >> 6, l = tid & 63;
  int lm = l & 15, lh = l >> 4;
  const size_t hb = (size_t)bh * SEQ * 64;
  int srow = tid >> 2, scs = (tid & 3) * 16;
  int qin = wv * 16 + lh * 4;          // + r = q row within tile
  const f32x4 z = {0.f, 0.f, 0.f, 0.f};

  #pragma unroll 1
  for (int job = 0; job < 2; ++job) {
    int qt = job ? (31 - p) : p;
    int q0 = qt * 64 + wv * 16;

    short8 aQh[2], aQl[2];
    {
      size_t qa = hb + (size_t)(q0 + lm) * 64 + (lh << 3);
      aQh[0] = *(const short8*)(Qh + qa);
      aQh[1] = *(const short8*)(Qh + qa + 32);
      aQl[0] = *(const short8*)(Ql + qa);
      aQl[1] = *(const short8*)(Ql + qa + 32);
    }
    f32x4 ctx[4] = {z, z, z, z};
    float mrun[4] = {-1e4f, -1e4f, -1e4f, -1e4f};
    float lrun[4] = {0.f, 0.f, 0.f, 0.f};

    for (int kt = par; kt <= qt; kt += 2) {
      uint4v vh0, vh1, vl0, vl1;
      {
        size_t vg = hb + (size_t)srow * SEQ + kt * 64 + scs;
        vh0 = *(const uint4v*)(Vth + vg);
        vh1 = *(const uint4v*)(Vth + vg + 8);
        vl0 = *(const uint4v*)(Vtl + vg);
        vl1 = *(const uint4v*)(Vtl + vg + 8);
      }
      __syncthreads();                       // prev PV reads done
      {
        size_t kg = hb + (size_t)(kt * 64 + srow) * 64 + scs;
        *(uint4v*)&KVh[srow][scs]     = *(const uint4v*)(Kh + kg);
        *(uint4v*)&KVh[srow][scs + 8] = *(const uint4v*)(Kh + kg + 8);
        *(uint4v*)&KVl[srow][scs]     = *(const uint4v*)(Kl + kg);
        *(uint4v*)&KVl[srow][scs + 8] = *(const uint4v*)(Kl + kg + 8);
      }
      __syncthreads();                       // K staged

      f32x4 S4[4] = {z, z, z, z};
      #pragma unroll
      for (int n = 0; n < 4; ++n) {
        #pragma unroll
        for (int c = 0; c < 2; ++c) {
          short8 kbh = *(const short8*)&KVh[n * 16 + lm][c * 32 + (lh << 3)];
          short8 kbl = *(const short8*)&KVl[n * 16 + lm][c * 32 + (lh << 3)];
          S4[n] = __builtin_amdgcn_mfma_f32_16x16x32_bf16(aQh[c], kbh, S4[n], 0, 0, 0);
          S4[n] = __builtin_amdgcn_mfma_f32_16x16x32_bf16(aQl[c], kbh, S4[n], 0, 0, 0);
          S4[n] = __builtin_amdgcn_mfma_f32_16x16x32_bf16(aQh[c], kbl, S4[n], 0, 0, 0);
        }
      }
      bool diag = (kt == qt);
      #pragma unroll
      for (int r = 0; r < 4; ++r) {
        float s0 = S4[0][r] * 0.125f, s1 = S4[1][r] * 0.125f;
        float s2 = S4[2][r] * 0.125f, s3 = S4[3][r] * 0.125f;
        if (diag) {
          int qq = qin + r;
          if (lm      > qq) s0 = -1e30f;
          if (16 + lm > qq) s1 = -1e30f;
          if (32 + lm > qq) s2 = -1e30f;
          if (48 + lm > qq) s3 = -1e30f;
        }
        float cm = fmaxf(fmaxf(s0, s1), fmaxf(s2, s3));
        cm = fmaxf(cm, __shfl_xor(cm, 1));
        cm = fmaxf(cm, __shfl_xor(cm, 2));
        cm = fmaxf(cm, __shfl_xor(cm, 4));
        cm = fmaxf(cm, __shfl_xor(cm, 8));
        if (cm > mrun[r] + 8.0f) {           // defer-max (THR=8)
          float sc = __expf(mrun[r] - cm);
          lrun[r] *= sc;
          ctx[0][r] *= sc; ctx[1][r] *= sc; ctx[2][r] *= sc; ctx[3][r] *= sc;
          mrun[r] = cm;
        }
        float p0 = __expf(s0 - mrun[r]), p1 = __expf(s1 - mrun[r]);
        float p2 = __expf(s2 - mrun[r]), p3 = __expf(s3 - mrun[r]);
        float rs = (p0 + p1) + (p2 + p3);
        rs += __shfl_xor(rs, 1); rs += __shfl_xor(rs, 2);
        rs += __shfl_xor(rs, 4); rs += __shfl_xor(rs, 8);
        lrun[r] += rs;
        int prow = qin + r;
        unsigned short e0 = f2bf(p0); Phs[prow][lm]      = e0; Pls[prow][lm]      = f2bf(p0 - bf2f(e0));
        unsigned short e1 = f2bf(p1); Phs[prow][16 + lm] = e1; Pls[prow][16 + lm] = f2bf(p1 - bf2f(e1));
        unsigned short e2 = f2bf(p2); Phs[prow][32 + lm] = e2; Pls[prow][32 + lm] = f2bf(p2 - bf2f(e2));
        unsigned short e3 = f2bf(p3); Phs[prow][48 + lm] = e3; Pls[prow][48 + lm] = f2bf(p3 - bf2f(e3));
      }
      __syncthreads();                       // QK^T reads of KV done
      {
        *(uint4v*)&KVh[srow][scs]     = vh0;
        *(uint4v*)&KVh[srow][scs + 8] = vh1;
        *(uint4v*)&KVl[srow][scs]     = vl0;
        *(uint4v*)&KVl[srow][scs + 8] = vl1;
      }
      __syncthreads();                       // V staged

      #pragma unroll
      for (int c = 0; c < 2; ++c) {
        short8 pah = *(const short8*)&Phs[wv * 16 + lm][c * 32 + (lh << 3)];
        short8 pal = *(const short8*)&Pls[wv * 16 + lm][c * 32 + (lh << 3)];
        #pragma unroll
        for (int n = 0; n < 4; ++n) {
          short8 vbh = *(const short8*)&KVh[n * 16 + lm][c * 32 + (lh << 3)];
          short8 vbl = *(const short8*)&KVl[n * 16 + lm][c * 32 + (lh << 3)];
          ctx[n] = __builtin_amdgcn_mfma_f32_16x16x32_bf16(pah, vbh, ctx[n], 0, 0, 0);
          ctx[n] = __builtin_amdgcn_mfma_f32_16x16x32_bf16(pal, vbh, ctx[n], 0, 0, 0);
          ctx[n] = __builtin_amdgcn_mfma_f32_16x16x32_bf16(pah, vbl, ctx[n], 0, 0, 0);
        }
      }
    }

    // write flash partials for this q-tile
    #pragma unroll
    for (int r = 0; r < 4; ++r) {
      int qg = b * SEQ + qt * 64 + wv * 16 + lh * 4 + r;
      size_t ob = ((size_t)par * TTOK + qg) * DMODEL + (size_t)h * HDIM + lm;
      #pragma unroll
      for (int n = 0; n < 4; ++n) paro[ob + n * 16] = ctx[n][r];
      if (lm == 0) {
        size_t mb = (((size_t)par * TTOK + qg) * NH + h) * 2;
        parml[mb] = mrun[r]; parml[mb + 1] = lrun[r];
      }
    }
  }
}

// ---------------------------------------------------------------------------
// attn_merge<NS>: exact flash merge of NS partials -> ctx hi/lo split.
// ---------------------------------------------------------------------------
template<int NS>
__global__ __launch_bounds__(256) void attn_merge(
    const float* __restrict__ paro,
    const float* __restrict__ parml,
    unsigned short* __restrict__ ctxh,
    unsigned short* __restrict__ ctxl)
{
  int gid = blockIdx.x * 256 + threadIdx.x;
  int ds = gid & 3;
  int h  = (gid >> 2) & 15;
  int t  = gid >> 6;
  float m[NS], lv[NS];
  float mx = -1e30f;
  #pragma unroll
  for (int i = 0; i < NS; ++i) {
    size_t mb = (((size_t)i * TTOK + t) * NH + h) * 2;
    m[i] = parml[mb]; lv[i] = parml[mb + 1];
    mx = fmaxf(mx, m[i]);
  }
  float w[NS], lsum = 0.f;
  #pragma unroll
  for (int i = 0; i < NS; ++i) { w[i] = __expf(m[i] - mx); lsum += lv[i] * w[i]; }
  float inv = 1.0f / lsum;
  size_t ob = (size_t)t * DMODEL + (size_t)h * HDIM + ds * 16;
  #pragma unroll
  for (int i4 = 0; i4 < 4; ++i4) {
    f32x4 v = {0.f, 0.f, 0.f, 0.f};
    #pragma unroll
    for (int i = 0; i < NS; ++i) {
      const f32x4* oi = (const f32x4*)(paro + (size_t)i * TTOK * DMODEL + ob);
      v += oi[i4] * w[i];
    }
    v = v * inv;
    ushort4 hi, lo;
    unsigned short e0 = f2bf(v[0]); hi.x = e0; lo.x = f2bf(v[0] - bf2f(e0));
    unsigned short e1 = f2bf(v[1]); hi.y = e1; lo.y = f2bf(v[1] - bf2f(e1));
    unsigned short e2 = f2bf(v[2]); hi.z = e2; lo.z = f2bf(v[2] - bf2f(e2));
    unsigned short e3 = f2bf(v[3]); hi.w = e3; lo.w = f2bf(v[3] - bf2f(e3));
    *(ushort4*)(ctxh + ob + i4 * 4) = hi;
    *(ushort4*)(ctxl + ob + i4 * 4) = lo;
  }
}

// ---------------------------------------------------------------------------
// Router (fp32)
// ---------------------------------------------------------------------------
__global__ __launch_bounds__(256) void router_kernel(
    const float* __restrict__ x1,
    const float* __restrict__ gam,
    const float* __restrict__ bet,
    const float* __restrict__ wrt,
    int* __restrict__ ctrl,
    int2* __restrict__ t_e,
    float2* __restrict__ t_g)
{
  int w = threadIdx.x >> 6, l = threadIdx.x & 63;
  int t = blockIdx.x * 4 + w;
  const f32x4* row = (const f32x4*)(x1 + (size_t)t * DMODEL);
  f32x4 v[4];
  float s = 0.f, sq = 0.f;
  #pragma unroll
  for (int i = 0; i < 4; ++i) {
    v[i] = row[l + i * 64];
    #pragma unroll
    for (int j = 0; j < 4; ++j) { s += v[i][j]; sq += v[i][j] * v[i][j]; }
  }
  #pragma unroll
  for (int off = 1; off < 64; off <<= 1) {
    s  += __shfl_xor(s, off);
    sq += __shfl_xor(sq, off);
  }
  float mu  = s * (1.0f / DMODEL);
  float var = sq * (1.0f / DMODEL) - mu * mu;
  float rs  = rsqrtf(var + 1e-5f);

  float acc[NE] = {0.f, 0.f, 0.f, 0.f, 0.f, 0.f, 0.f, 0.f};
  #pragma unroll
  for (int i = 0; i < 4; ++i) {
    int base = (l + i * 64) * 4;
    #pragma unroll
    for (int j = 0; j < 4; ++j) {
      int idx = base + j;
      float xn = (v[i][j] - mu) * rs * gam[idx] + bet[idx];
      const f32x4* wr0 = (const f32x4*)(wrt + idx * NE);
      f32x4 w0 = wr0[0], w1v = wr0[1];
      acc[0] += xn * w0[0]; acc[1] += xn * w0[1];
      acc[2] += xn * w0[2]; acc[3] += xn * w0[3];
      acc[4] += xn * w1v[0]; acc[5] += xn * w1v[1];
      acc[6] += xn * w1v[2]; acc[7] += xn * w1v[3];
    }
  }
  #pragma unroll
  for (int e = 0; e < NE; ++e) {
    #pragma unroll
    for (int off = 1; off < 64; off <<= 1) acc[e] += __shfl_xor(acc[e], off);
  }
  if (l == 0) {
    int e0 = 0; float m0v = acc[0];
    #pragma unroll
    for (int e = 1; e < NE; ++e) if (acc[e] > m0v) { m0v = acc[e]; e0 = e; }
    int e1 = -1; float m1v = -1e30f;
    #pragma unroll
    for (int e = 0; e < NE; ++e) if (e != e0 && acc[e] > m1v) { m1v = acc[e]; e1 = e; }
    float r = __expf(m1v - m0v);
    float g0 = 1.0f / (1.0f + r);
    float g1 = r * g0;
    t_e[t] = make_int2(e0, e1);
    t_g[t] = make_float2(g0, g1);
    atomicAdd(&ctrl[C_CNT + e0], 1);
    atomicAdd(&ctrl[C_CNT + e1], 1);
  }
}

// ---------------------------------------------------------------------------
// Scan: 128-padded per-expert slot bases + 128-row m-tile table.
// ---------------------------------------------------------------------------
__global__ void scan_kernel(int* __restrict__ ctrl)
{
  if (threadIdx.x == 0 && blockIdx.x == 0) {
    int b = 0, m = 0;
    for (int e = 0; e < NE; ++e) {
      ctrl[C_BASE + e] = b;
      int pc = (ctrl[C_CNT + e] + 127) & ~127;
      int nt = pc >> 7;
      for (int i = 0; i < nt; ++i) {
        ctrl[C_MTE + m] = e;
        ctrl[C_MTS + m] = b + (i << 7);
        ++m;
      }
      b += pc;
    }
    ctrl[C_NMT] = m;
  }
}

// ---------------------------------------------------------------------------
__global__ __launch_bounds__(256) void gather_kernel(
    int* __restrict__ ctrl,
    const int2* __restrict__ t_e,
    const float2* __restrict__ t_g,
    int* __restrict__ slot_token,
    float* __restrict__ slot_gate)
{
  int t = blockIdx.x * 256 + threadIdx.x;
  int2 e = t_e[t];
  float2 g = t_g[t];
  int p0 = atomicAdd(&ctrl[C_FILL + e.x], 1);
  int s0 = ctrl[C_BASE + e.x] + p0;
  slot_token[s0] = t; slot_gate[s0] = g.x;
  int p1 = atomicAdd(&ctrl[C_FILL + e.y], 1);
  int s1 = ctrl[C_BASE + e.y] + p1;
  slot_token[s1] = t; slot_gate[s1] = g.y;
}

// ---------------------------------------------------------------------------
// Transpose + fp32->bf16: in [E][K][N] fp32 -> out [E][N][K] bf16.
// ---------------------------------------------------------------------------
__global__ __launch_bounds__(256) void transpose_conv(
    const float* __restrict__ in, unsigned short* __restrict__ outb,
    unsigned short* __restrict__ outlo, int K, int N)
{
  __shared__ float T[64][68];
  int e = blockIdx.z;
  int n0 = blockIdx.x * 64, k0 = blockIdx.y * 64;
  const float* src = in + (size_t)e * K * N;
  unsigned short* dst = outb + (size_t)e * K * N;
  unsigned short* dstl = outlo ? outlo + (size_t)e * K * N : nullptr;
  int tid = threadIdx.x;
  int r = tid >> 4, c4 = (tid & 15) * 4;
  #pragma unroll
  for (int i = 0; i < 4; ++i) {
    f32x4 v = *(const f32x4*)(src + (size_t)(k0 + r + i * 16) * N + n0 + c4);
    *(f32x4*)(&T[r + i * 16][c4]) = v;
  }
  __syncthreads();
  #pragma unroll
  for (int i = 0; i < 4; ++i) {
    int rr = r + i * 16;
    float v0 = T[c4 + 0][rr], v1 = T[c4 + 1][rr];
    float v2 = T[c4 + 2][rr], v3 = T[c4 + 3][rr];
    ushort4 o;
    o.x = f2bf(v0); o.y = f2bf(v1); o.z = f2bf(v2); o.w = f2bf(v3);
    *(ushort4*)(dst + (size_t)(n0 + rr) * K + k0 + c4) = o;
    if (dstl) {
      ushort4 lo;
      lo.x = f2bf(v0 - bf2f(o.x));
      lo.y = f2bf(v1 - bf2f(o.y));
      lo.z = f2bf(v2 - bf2f(o.z));
      lo.w = f2bf(v3 - bf2f(o.w));
      *(ushort4*)(dstl + (size_t)(n0 + rr) * K + k0 + c4) = lo;
    }
  }
}

// ---------------------------------------------------------------------------
// Fast sparse MoE w1 (global_load_lds staging, unpadded [128][32] LDS).
// ---------------------------------------------------------------------------
__global__ __launch_bounds__(256) void moe_w1f(
    const unsigned short* __restrict__ h2,
    const unsigned short* __restrict__ w1t,
    const float* __restrict__ b1,
    const int* __restrict__ ctrl,
    const int* __restrict__ slot_token,
    unsigned short* __restrict__ Hs)
{
  int mt = blockIdx.y;
  if (mt >= ctrl[C_NMT]) return;
  int e = ctrl[C_MTE + mt];
  int slot0 = ctrl[C_MTS + mt];
  const int N = DFF, K = DMODEL;
  const unsigned short* Bt = w1t + (size_t)e * K * N;
  const float* bias = b1 + (size_t)e * DFF;

  __shared__ unsigned short Al[128][32];
  __shared__ unsigned short Bl[128][32];
  __shared__ int tokrow[128];
  int tid = threadIdx.x;
  if (tid < 128) {
    int tk = slot_token[slot0 + tid];
    tokrow[tid] = tk < 0 ? 0 : tk;
  }
  __syncthreads();
  int l = tid & 63, wv = tid >> 6;
  int wr = wv >> 1, wc = wv & 1;
  int n0 = blockIdx.x * 128;
  int rsub = l >> 2, csub = (l & 3) * 8;
  int row0 = wv * 32 + rsub, row1 = row0 + 16;
  const unsigned short* ga0 = h2 + (size_t)tokrow[row0] * DMODEL + csub;
  const unsigned short* ga1 = h2 + (size_t)tokrow[row1] * DMODEL + csub;
  const unsigned short* gb0 = Bt + (size_t)(n0 + row0) * K + csub;
  const unsigned short* gb1 = Bt + (size_t)(n0 + row1) * K + csub;

  const f32x4 z = {0.f, 0.f, 0.f, 0.f};
  f32x4 acc[4][4];
  #pragma unroll
  for (int i = 0; i < 4; ++i)
    #pragma unroll
    for (int j = 0; j < 4; ++j) acc[i][j] = z;

  for (int k0 = 0; k0 < K; k0 += 32) {
    __syncthreads();
    gl_lds16(ga0 + k0, &Al[wv * 32][0]);
    gl_lds16(ga1 + k0, &Al[wv * 32 + 16][0]);
    gl_lds16(gb0 + k0, &Bl[wv * 32][0]);
    gl_lds16(gb1 + k0, &Bl[wv * 32 + 16][0]);
    __syncthreads();

    short8 af[4], bfr[4];
    #pragma unroll
    for (int m = 0; m < 4; ++m)
      af[m] = *(const short8*)(&Al[wr * 64 + m * 16 + (l & 15)][(l >> 4) << 3]);
    #pragma unroll
    for (int n = 0; n < 4; ++n)
      bfr[n] = *(const short8*)(&Bl[wc * 64 + n * 16 + (l & 15)][(l >> 4) << 3]);
    #pragma unroll
    for (int m = 0; m < 4; ++m)
      #pragma unroll
      for (int n = 0; n < 4; ++n)
        acc[m][n] = __builtin_amdgcn_mfma_f32_16x16x32_bf16(af[m], bfr[n], acc[m][n], 0, 0, 0);
  }

  int rbase = wr * 64 + ((l >> 4) << 2);
  int cbase = n0 + wc * 64 + (l & 15);
  #pragma unroll
  for (int n = 0; n < 4; ++n) {
    int col = cbase + n * 16;
    float bv = bias[col];
    #pragma unroll
    for (int m = 0; m < 4; ++m) {
      #pragma unroll
      for (int r = 0; r < 4; ++r) {
        int srow = slot0 + rbase + m * 16 + r;
        float v = acc[m][n][r] + bv;
        v = 0.5f * v * (1.0f + erff(v * 0.70710678118654752f));
        Hs[(size_t)srow * DFF + col] = f2bf(v);
      }
    }
  }
}

// ---------------------------------------------------------------------------
// Fast sparse MoE w2.
// ---------------------------------------------------------------------------
__global__ __launch_bounds__(256) void moe_w2f(
    const unsigned short* __restrict__ Hs,
    const unsigned short* __restrict__ w2t,
    const float* __restrict__ b2,
    const int* __restrict__ ctrl,
    const int* __restrict__ slot_token,
    const float* __restrict__ slot_gate,
    float* __restrict__ ffn)
{
  int mt = blockIdx.y;
  if (mt >= ctrl[C_NMT]) return;
  int e = ctrl[C_MTE + mt];
  int slot0 = ctrl[C_MTS + mt];
  const int N = DMODEL, K = DFF;
  const unsigned short* Bt = w2t + (size_t)e * (size_t)K * N;
  const float* bias = b2 + (size_t)e * DMODEL;

  __shared__ unsigned short Al[128][32];
  __shared__ unsigned short Bl[128][32];
  int tid = threadIdx.x;
  int l = tid & 63, wv = tid >> 6;
  int wr = wv >> 1, wc = wv & 1;
  int n0 = blockIdx.x * 128;
  int rsub = l >> 2, csub = (l & 3) * 8;
  int row0 = wv * 32 + rsub, row1 = row0 + 16;
  const unsigned short* ga0 = Hs + (size_t)(slot0 + row0) * DFF + csub;
  const unsigned short* ga1 = Hs + (size_t)(slot0 + row1) * DFF + csub;
  const unsigned short* gb0 = Bt + (size_t)(n0 + row0) * K + csub;
  const unsigned short* gb1 = Bt + (size_t)(n0 + row1) * K + csub;

  const f32x4 z = {0.f, 0.f, 0.f, 0.f};
  f32x4 acc[4][4];
  #pragma unroll
  for (int i = 0; i < 4; ++i)
    #pragma unroll
    for (int j = 0; j < 4; ++j) acc[i][j] = z;

  for (int k0 = 0; k0 < K; k0 += 32) {
    __syncthreads();
    gl_lds16(ga0 + k0, &Al[wv * 32][0]);
    gl_lds16(ga1 + k0, &Al[wv * 32 + 16][0]);
    gl_lds16(gb0 + k0, &Bl[wv * 32][0]);
    gl_lds16(gb1 + k0, &Bl[wv * 32 + 16][0]);
    __syncthreads();

    short8 af[4], bfr[4];
    #pragma unroll
    for (int m = 0; m < 4; ++m)
      af[m] = *(const short8*)(&Al[wr * 64 + m * 16 + (l & 15)][(l >> 4) << 3]);
    #pragma unroll
    for (int n = 0; n < 4; ++n)
      bfr[n] = *(const short8*)(&Bl[wc * 64 + n * 16 + (l & 15)][(l >> 4) << 3]);
    #pragma unroll
    for (int m = 0; m < 4; ++m)
      #pragma unroll
      for (int n = 0; n < 4; ++n)
        acc[m][n] = __builtin_amdgcn_mfma_f32_16x16x32_bf16(af[m], bfr[n], acc[m][n], 0, 0, 0);
  }

  int rbase = wr * 64 + ((l >> 4) << 2);
  int cbase = n0 + wc * 64 + (l & 15);
  #pragma unroll
  for (int n = 0; n < 4; ++n) {
    int col = cbase + n * 16;
    float bv = bias[col];
    #pragma unroll
    for (int m = 0; m < 4; ++m) {
      #pragma unroll
      for (int r = 0; r < 4; ++r) {
        int srow = slot0 + rbase + m * 16 + r;
        int tok = slot_token[srow];
        if (tok >= 0) {
          float v = acc[m][n][r] + bv;
          atomicAdd(&ffn[(size_t)tok * DMODEL + col], slot_gate[srow] * v);
        }
      }
    }
  }
}

// ---------------------------------------------------------------------------
__global__ __launch_bounds__(256) void final_add(
    const float* __restrict__ x1,
    const float* __restrict__ ffn,
    float* __restrict__ out)
{
  int i = blockIdx.x * 256 + threadIdx.x;
  f32x4 xr = ((const f32x4*)x1)[i];
  f32x4 fr = ((const f32x4*)ffn)[i];
  f32x4 o;
  o[0] = xr[0] + fr[0];
  o[1] = xr[1] + fr[1];
  o[2] = xr[2] + fr[2];
  o[3] = xr[3] + fr[3];
  ((f32x4*)out)[i] = o;
}

// ---------------------------------------------------------------------------
extern "C" void kernel_launch(void* const* d_in, const int* in_sizes, int n_in,
                              void* d_out, int out_size, void* d_ws, size_t ws_size,
                              hipStream_t stream) {
  (void)in_sizes; (void)n_in; (void)out_size;
  const float* x     = (const float*)d_in[0];
  const float* ln1_g = (const float*)d_in[1];
  const float* ln1_b = (const float*)d_in[2];
  const float* ln2_g = (const float*)d_in[3];
  const float* ln2_b = (const float*)d_in[4];
  const float* wqkv  = (const float*)d_in[5];
  const float* bqkv  = (const float*)d_in[6];
  const float* wo    = (const float*)d_in[7];
  const float* bo    = (const float*)d_in[8];
  const float* wrt   = (const float*)d_in[9];
  const float* w1    = (const float*)d_in[10];
  const float* b1    = (const float*)d_in[11];
  const float* w2    = (const float*)d_in[12];
  const float* b2    = (const float*)d_in[13];
  float* out = (float*)d_out;

  char* ws = (char*)d_ws;
  size_t off = 0;
  auto alloc = [&](size_t bytes) -> void* {
    void* p = ws + off;
    off += (bytes + 255) & ~(size_t)255;
    return p;
  };
  float*          x1    = (float*)alloc((size_t)TTOK * DMODEL * 4);
  unsigned short* h2    = (unsigned short*)alloc((size_t)TTOK * DMODEL * 2);
  int*            ctrl  = (int*)alloc(1024);
  int2*           t_e   = (int2*)alloc((size_t)TTOK * 8);
  float2*         t_g   = (float2*)alloc((size_t)TTOK * 8);
  int*            slot_token = (int*)alloc((size_t)SLOT_MAX * 4);
  float*          slot_gate  = (float*)alloc((size_t)SLOT_MAX * 4);
  float*          P1    = (float*)alloc((size_t)TTOK * DMODEL * 4);
  char*           P2    = (char*)alloc((size_t)SLOT_MAX * DFF * 2);
  unsigned short* w1t   = (unsigned short*)alloc((size_t)NE * DMODEL * DFF * 2);
  unsigned short* w2t   = (unsigned short*)alloc((size_t)NE * DFF * DMODEL * 2);
  unsigned short* wqkvTh = (unsigned short*)alloc((size_t)DMODEL * 3 * DMODEL * 2);
  unsigned short* wqkvTl = (unsigned short*)alloc((size_t)DMODEL * 3 * DMODEL * 2);
  unsigned short* woTh  = (unsigned short*)alloc((size_t)DMODEL * DMODEL * 2);
  unsigned short* woTl  = (unsigned short*)alloc((size_t)DMODEL * DMODEL * 2);
  unsigned short* hh    = (unsigned short*)alloc((size_t)TTOK * DMODEL * 2);
  unsigned short* hl    = (unsigned short*)alloc((size_t)TTOK * DMODEL * 2);
  unsigned short* ctxh  = (unsigned short*)alloc((size_t)TTOK * DMODEL * 2);
  unsigned short* ctxl  = (unsigned short*)alloc((size_t)TTOK * DMODEL * 2);
  // MFMA attention split-qkv arrays + flash partials
  size_t headsz = (size_t)NB * NH * SEQ * HDIM;   // elems per array
  unsigned short* Qh  = (unsigned short*)alloc(headsz * 2);
  unsigned short* Ql  = (unsigned short*)alloc(headsz * 2);
  unsigned short* Khp = (unsigned short*)alloc(headsz * 2);
  unsigned short* Klp = (unsigned short*)alloc(headsz * 2);
  unsigned short* Vth = (unsigned short*)alloc(headsz * 2);
  unsigned short* Vtl = (unsigned short*)alloc(headsz * 2);
  float*          paro2  = (float*)alloc((size_t)2 * TTOK * DMODEL * 4);
  float*          parml2 = (float*)alloc((size_t)2 * TTOK * NH * 2 * 4);

  float*          qkv  = (float*)P2;        // dead before Hs is written
  float*          ffn  = P1;
  unsigned short* Hs   = (unsigned short*)P2;

  // 0) zero control counters, mark all slots invalid
  hipMemsetAsync(ctrl, 0, 16 * 4, stream);
  hipMemsetAsync(slot_token, 0xFF, (size_t)SLOT_MAX * 4, stream);

  // 0b) weight prep
  transpose_conv<<<dim3(DFF / 64, DMODEL / 64, NE), 256, 0, stream>>>(
      w1, w1t, nullptr, DMODEL, DFF);
  transpose_conv<<<dim3(DMODEL / 64, DFF / 64, NE), 256, 0, stream>>>(
      w2, w2t, nullptr, DFF, DMODEL);
  transpose_conv<<<dim3(3 * DMODEL / 64, DMODEL / 64, 1), 256, 0, stream>>>(
      wqkv, wqkvTh, wqkvTl, DMODEL, 3 * DMODEL);
  transpose_conv<<<dim3(DMODEL / 64, DMODEL / 64, 1), 256, 0, stream>>>(
      wo, woTh, woTl, DMODEL, DMODEL);

  // 1) h = LN1(x) -> split hi/lo
  ln_kernel<2><<<TTOK, 256, 0, stream>>>(x, ln1_g, ln1_b, nullptr, hh, hl);
  // 2) qkv = h @ wqkv + bqkv   (split-bf16 MFMA, fp32-grade)
  mgemm_split<0><<<dim3(3 * DMODEL / 128, TTOK / 128), 256, 0, stream>>>(
      hh, hl, wqkvTh, wqkvTl, bqkv, nullptr, qkv, TTOK, 3 * DMODEL, DMODEL);
  // 3) ctx = causal attention (split-bf16 MFMA flash, parity+fold) -> merge
  qkv_split<<<dim3(SEQ / 64, NB * NH), 256, 0, stream>>>(
      qkv, Qh, Ql, Khp, Klp, Vth, Vtl);
  attn_mf3<<<dim3(32, NB * NH), 256, 0, stream>>>(
      Qh, Ql, Khp, Klp, Vth, Vtl, paro2, parml2);
  attn_merge<2><<<(TTOK * NH * 4) / 256, 256, 0, stream>>>(
      paro2, parml2, ctxh, ctxl);
  // 4) x1 = x + ctx @ wo + bo  (split-bf16 MFMA)
  mgemm_split<1><<<dim3(DMODEL / 128, TTOK / 128), 256, 0, stream>>>(
      ctxh, ctxl, woTh, woTl, bo, x, x1, TTOK, DMODEL, DMODEL);

  // 5) h2 = LN2(x1)
  ln_kernel<1><<<TTOK, 256, 0, stream>>>(x1, ln2_g, ln2_b, nullptr, h2, nullptr);
  // 6) router -> scan -> gather
  router_kernel<<<TTOK / 4, 256, 0, stream>>>(x1, ln2_g, ln2_b, wrt, ctrl, t_e, t_g);
  scan_kernel<<<1, 64, 0, stream>>>(ctrl);
  gather_kernel<<<TTOK / 256, 256, 0, stream>>>(ctrl, t_e, t_g, slot_token, slot_gate);
  // 7) sparse MoE (BM=128, no K-split — measured best: r15 config)
  hipMemsetAsync(ffn, 0, (size_t)TTOK * DMODEL * 4, stream);
  moe_w1f<<<dim3(DFF / 128, MT_MAX), 256, 0, stream>>>(
      h2, w1t, b1, ctrl, slot_token, Hs);
  moe_w2f<<<dim3(DMODEL / 128, MT_MAX), 256, 0, stream>>>(
      Hs, w2t, b2, ctrl, slot_token, slot_gate, ffn);
  // 8) out = x1 + ffn
  final_add<<<(TTOK * DMODEL / 4) / 256, 256, 0, stream>>>(x1, ffn, out);
}

// Round 20
// 892.865 us; speedup vs baseline: 1.3864x; 1.0104x over previous
//
#include <hip/hip_runtime.h>
#include <hip/hip_bf16.h>
#include <math.h>

// Problem constants
#define NB    2
#define SEQ   2048
#define DMODEL 1024
#define NH    16
#define HDIM  64
#define NE    8
#define DFF   4096
#define TTOK  4096   // NB*SEQ

#define MT_MAX   72
#define SLOT_MAX 9216

// ctrl block layout (ints)
#define C_CNT  0
#define C_FILL 8
#define C_BASE 16
#define C_NMT  24
#define C_MTE  32
#define C_MTS  104

typedef __attribute__((ext_vector_type(8))) short short8;
typedef __attribute__((ext_vector_type(4))) float f32x4;
typedef __attribute__((ext_vector_type(4))) unsigned int uint4v;

static __device__ __forceinline__ float bf2f(unsigned short u) {
  union { unsigned int i; float f; } c; c.i = ((unsigned int)u) << 16; return c.f;
}
static __device__ __forceinline__ unsigned short f2bf(float f) {
  unsigned int x = __float_as_uint(f);
  unsigned int r = (x + 0x7FFFu + ((x >> 16) & 1u)) >> 16;
  return (unsigned short)r;
}

// Async global->LDS, 16B per lane. LDS dest is WAVE-UNIFORM base + lane*16.
static __device__ __forceinline__ void gl_lds16(const void* g, void* l) {
  __builtin_amdgcn_global_load_lds(
      (const __attribute__((address_space(1))) unsigned int*)(uintptr_t)g,
      (__attribute__((address_space(3))) unsigned int*)(uintptr_t)l,
      16, 0, 0);
}

// ---------------------------------------------------------------------------
// LayerNorm. MODE 0: fp32 out. MODE 1: bf16 out. MODE 2: split hi/lo bf16.
// ---------------------------------------------------------------------------
template<int MODE>
__global__ __launch_bounds__(256) void ln_kernel(
    const float* __restrict__ x,
    const float* __restrict__ gam,
    const float* __restrict__ bet,
    float* __restrict__ outf,
    unsigned short* __restrict__ outb,
    unsigned short* __restrict__ outlo)
{
  int t = blockIdx.x, tid = threadIdx.x;
  f32x4 v = ((const f32x4*)(x + (size_t)t * DMODEL))[tid];
  float s  = v[0] + v[1] + v[2] + v[3];
  float sq = v[0]*v[0] + v[1]*v[1] + v[2]*v[2] + v[3]*v[3];
  #pragma unroll
  for (int off = 1; off < 64; off <<= 1) {
    s  += __shfl_xor(s, off);
    sq += __shfl_xor(sq, off);
  }
  __shared__ float red[8];
  int w = tid >> 6, l = tid & 63;
  if (l == 0) { red[w] = s; red[4 + w] = sq; }
  __syncthreads();
  s  = red[0] + red[1] + red[2] + red[3];
  sq = red[4] + red[5] + red[6] + red[7];
  float mu  = s * (1.0f / DMODEL);
  float var = sq * (1.0f / DMODEL) - mu * mu;
  float rs  = rsqrtf(var + 1e-5f);
  f32x4 g = ((const f32x4*)gam)[tid];
  f32x4 b = ((const f32x4*)bet)[tid];
  float r[4];
  r[0] = (v[0] - mu) * rs * g[0] + b[0];
  r[1] = (v[1] - mu) * rs * g[1] + b[1];
  r[2] = (v[2] - mu) * rs * g[2] + b[2];
  r[3] = (v[3] - mu) * rs * g[3] + b[3];
  if constexpr (MODE == 0) {
    f32x4 o = {r[0], r[1], r[2], r[3]};
    ((f32x4*)(outf + (size_t)t * DMODEL))[tid] = o;
  } else if constexpr (MODE == 1) {
    ushort4 o; o.x = f2bf(r[0]); o.y = f2bf(r[1]); o.z = f2bf(r[2]); o.w = f2bf(r[3]);
    ((ushort4*)(outb + (size_t)t * DMODEL))[tid] = o;
  } else {
    ushort4 hi, lo;
    unsigned short h0 = f2bf(r[0]); hi.x = h0; lo.x = f2bf(r[0] - bf2f(h0));
    unsigned short h1 = f2bf(r[1]); hi.y = h1; lo.y = f2bf(r[1] - bf2f(h1));
    unsigned short h2 = f2bf(r[2]); hi.z = h2; lo.z = f2bf(r[2] - bf2f(h2));
    unsigned short h3 = f2bf(r[3]); hi.w = h3; lo.w = f2bf(r[3] - bf2f(h3));
    ((ushort4*)(outb  + (size_t)t * DMODEL))[tid] = hi;
    ((ushort4*)(outlo + (size_t)t * DMODEL))[tid] = lo;
  }
}

// ---------------------------------------------------------------------------
// Split-bf16 MFMA GEMM (fp32-grade): C = (Ah+Al)(Bh+Bl) + bias [+resid].
// ---------------------------------------------------------------------------
template<int EPI>
__global__ __launch_bounds__(256) void mgemm_split(
    const unsigned short* __restrict__ Ah,
    const unsigned short* __restrict__ Alo,
    const unsigned short* __restrict__ Bth,
    const unsigned short* __restrict__ Btl,
    const float* __restrict__ bias,
    const float* __restrict__ resid,
    float* __restrict__ C, int M, int N, int K)
{
  __shared__ unsigned short AH[128][32];
  __shared__ unsigned short AL[128][32];
  __shared__ unsigned short BH[128][32];
  __shared__ unsigned short BL[128][32];
  int tid = threadIdx.x;
  int l = tid & 63, wv = tid >> 6;
  int wr = wv >> 1, wc = wv & 1;
  int m0 = blockIdx.y * 128, n0 = blockIdx.x * 128;
  int rsub = l >> 2, csub = (l & 3) * 8;
  int row0 = wv * 32 + rsub, row1 = row0 + 16;

  const unsigned short* gah0 = Ah  + (size_t)(m0 + row0) * K + csub;
  const unsigned short* gah1 = Ah  + (size_t)(m0 + row1) * K + csub;
  const unsigned short* gal0 = Alo + (size_t)(m0 + row0) * K + csub;
  const unsigned short* gal1 = Alo + (size_t)(m0 + row1) * K + csub;
  const unsigned short* gbh0 = Bth + (size_t)(n0 + row0) * K + csub;
  const unsigned short* gbh1 = Bth + (size_t)(n0 + row1) * K + csub;
  const unsigned short* gbl0 = Btl + (size_t)(n0 + row0) * K + csub;
  const unsigned short* gbl1 = Btl + (size_t)(n0 + row1) * K + csub;

  const f32x4 z = {0.f, 0.f, 0.f, 0.f};
  f32x4 acc[4][4];
  #pragma unroll
  for (int i = 0; i < 4; ++i)
    #pragma unroll
    for (int j = 0; j < 4; ++j) acc[i][j] = z;

  for (int k0 = 0; k0 < K; k0 += 32) {
    __syncthreads();
    gl_lds16(gah0 + k0, &AH[wv * 32][0]);
    gl_lds16(gah1 + k0, &AH[wv * 32 + 16][0]);
    gl_lds16(gal0 + k0, &AL[wv * 32][0]);
    gl_lds16(gal1 + k0, &AL[wv * 32 + 16][0]);
    gl_lds16(gbh0 + k0, &BH[wv * 32][0]);
    gl_lds16(gbh1 + k0, &BH[wv * 32 + 16][0]);
    gl_lds16(gbl0 + k0, &BL[wv * 32][0]);
    gl_lds16(gbl1 + k0, &BL[wv * 32 + 16][0]);
    __syncthreads();

    short8 afh[4], afl[4], bfh[4], bfl[4];
    #pragma unroll
    for (int m = 0; m < 4; ++m) {
      afh[m] = *(const short8*)(&AH[wr * 64 + m * 16 + (l & 15)][(l >> 4) << 3]);
      afl[m] = *(const short8*)(&AL[wr * 64 + m * 16 + (l & 15)][(l >> 4) << 3]);
    }
    #pragma unroll
    for (int n = 0; n < 4; ++n) {
      bfh[n] = *(const short8*)(&BH[wc * 64 + n * 16 + (l & 15)][(l >> 4) << 3]);
      bfl[n] = *(const short8*)(&BL[wc * 64 + n * 16 + (l & 15)][(l >> 4) << 3]);
    }
    #pragma unroll
    for (int m = 0; m < 4; ++m)
      #pragma unroll
      for (int n = 0; n < 4; ++n) {
        acc[m][n] = __builtin_amdgcn_mfma_f32_16x16x32_bf16(afh[m], bfh[n], acc[m][n], 0, 0, 0);
        acc[m][n] = __builtin_amdgcn_mfma_f32_16x16x32_bf16(afl[m], bfh[n], acc[m][n], 0, 0, 0);
        acc[m][n] = __builtin_amdgcn_mfma_f32_16x16x32_bf16(afh[m], bfl[n], acc[m][n], 0, 0, 0);
      }
  }

  int rbase = m0 + wr * 64 + ((l >> 4) << 2);
  int cbase = n0 + wc * 64 + (l & 15);
  #pragma unroll
  for (int n = 0; n < 4; ++n) {
    int col = cbase + n * 16;
    float bv = bias[col];
    #pragma unroll
    for (int m = 0; m < 4; ++m) {
      #pragma unroll
      for (int r = 0; r < 4; ++r) {
        int row = rbase + m * 16 + r;
        float v = acc[m][n][r] + bv;
        if constexpr (EPI == 1) v += resid[(size_t)row * N + col];
        C[(size_t)row * N + col] = v;
      }
    }
  }
}

// ---------------------------------------------------------------------------
// qkv_split: fp32 qkv [T][3][H][64] -> per-head split bf16 arrays.
// ---------------------------------------------------------------------------
__global__ __launch_bounds__(256) void qkv_split(
    const float* __restrict__ qkv,
    unsigned short* __restrict__ Qh, unsigned short* __restrict__ Ql,
    unsigned short* __restrict__ Kh, unsigned short* __restrict__ Kl,
    unsigned short* __restrict__ Vth, unsigned short* __restrict__ Vtl)
{
  __shared__ float Vt[64][68];
  int st = blockIdx.x, bh = blockIdx.y;
  int b = bh >> 4, h = bh & 15;
  int tid = threadIdx.x;
  int row = tid >> 2, cs = (tid & 3) * 16;
  size_t hb = (size_t)bh * SEQ * 64;
  int srow = st * 64 + row;
  size_t src = (size_t)(b * SEQ + srow) * 3072 + (size_t)h * HDIM + cs;

  #pragma unroll
  for (int qk = 0; qk < 2; ++qk) {
    const float* p = qkv + src + qk * 1024;
    unsigned short hi8[16], lo8[16];
    #pragma unroll
    for (int i = 0; i < 16; ++i) {
      float v = p[i];
      unsigned short hh_ = f2bf(v);
      hi8[i] = hh_; lo8[i] = f2bf(v - bf2f(hh_));
    }
    unsigned short* dh = (qk ? Kh : Qh) + hb + (size_t)srow * 64 + cs;
    unsigned short* dl = (qk ? Kl : Ql) + hb + (size_t)srow * 64 + cs;
    *(uint4v*)dh       = *(const uint4v*)&hi8[0];
    *(uint4v*)(dh + 8) = *(const uint4v*)&hi8[8];
    *(uint4v*)dl       = *(const uint4v*)&lo8[0];
    *(uint4v*)(dl + 8) = *(const uint4v*)&lo8[8];
  }
  {
    const float* p = qkv + src + 2048;
    #pragma unroll
    for (int i = 0; i < 4; ++i)
      *(f32x4*)&Vt[row][cs + i * 4] = *(const f32x4*)(p + i * 4);
  }
  __syncthreads();
  {
    int d = tid >> 2, ks = (tid & 3) * 16;
    unsigned short hi8[16], lo8[16];
    #pragma unroll
    for (int j = 0; j < 16; ++j) {
      float v = Vt[ks + j][d];
      unsigned short hh_ = f2bf(v);
      hi8[j] = hh_; lo8[j] = f2bf(v - bf2f(hh_));
    }
    size_t dst = hb + (size_t)d * SEQ + st * 64 + ks;
    *(uint4v*)(Vth + dst)     = *(const uint4v*)&hi8[0];
    *(uint4v*)(Vth + dst + 8) = *(const uint4v*)&hi8[8];
    *(uint4v*)(Vtl + dst)     = *(const uint4v*)&lo8[0];
    *(uint4v*)(Vtl + dst + 8) = *(const uint4v*)&lo8[8];
  }
}

// ---------------------------------------------------------------------------
// attn_mf3: split-bf16 MFMA flash attention, KV-parity + causal-fold.
// ---------------------------------------------------------------------------
__global__ __launch_bounds__(256) void attn_mf3(
    const unsigned short* __restrict__ Qh, const unsigned short* __restrict__ Ql,
    const unsigned short* __restrict__ Kh, const unsigned short* __restrict__ Kl,
    const unsigned short* __restrict__ Vth, const unsigned short* __restrict__ Vtl,
    float* __restrict__ paro,     // [2][TTOK][DMODEL] unnormalized o
    float* __restrict__ parml)    // [2][TTOK][NH][2]  (m, l)
{
  __shared__ unsigned short KVh[64][72], KVl[64][72];
  __shared__ unsigned short Phs[64][72], Pls[64][72];
  int bh = blockIdx.y;
  int b = bh >> 4, h = bh & 15;
  int bx = blockIdx.x;                 // 0..31
  int p  = bx >> 1, par = bx & 1;
  int tid = threadIdx.x, wv = tid >> 6, l = tid & 63;
  int lm = l & 15, lh = l >> 4;
  const size_t hb = (size_t)bh * SEQ * 64;
  int srow = tid >> 2, scs = (tid & 3) * 16;
  int qin = wv * 16 + lh * 4;          // + r = q row within tile
  const f32x4 z = {0.f, 0.f, 0.f, 0.f};

  #pragma unroll 1
  for (int job = 0; job < 2; ++job) {
    int qt = job ? (31 - p) : p;
    int q0 = qt * 64 + wv * 16;

    short8 aQh[2], aQl[2];
    {
      size_t qa = hb + (size_t)(q0 + lm) * 64 + (lh << 3);
      aQh[0] = *(const short8*)(Qh + qa);
      aQh[1] = *(const short8*)(Qh + qa + 32);
      aQl[0] = *(const short8*)(Ql + qa);
      aQl[1] = *(const short8*)(Ql + qa + 32);
    }
    f32x4 ctx[4] = {z, z, z, z};
    float mrun[4] = {-1e4f, -1e4f, -1e4f, -1e4f};
    float lrun[4] = {0.f, 0.f, 0.f, 0.f};

    for (int kt = par; kt <= qt; kt += 2) {
      uint4v vh0, vh1, vl0, vl1;
      {
        size_t vg = hb + (size_t)srow * SEQ + kt * 64 + scs;
        vh0 = *(const uint4v*)(Vth + vg);
        vh1 = *(const uint4v*)(Vth + vg + 8);
        vl0 = *(const uint4v*)(Vtl + vg);
        vl1 = *(const uint4v*)(Vtl + vg + 8);
      }
      __syncthreads();                       // prev PV reads done
      {
        size_t kg = hb + (size_t)(kt * 64 + srow) * 64 + scs;
        *(uint4v*)&KVh[srow][scs]     = *(const uint4v*)(Kh + kg);
        *(uint4v*)&KVh[srow][scs + 8] = *(const uint4v*)(Kh + kg + 8);
        *(uint4v*)&KVl[srow][scs]     = *(const uint4v*)(Kl + kg);
        *(uint4v*)&KVl[srow][scs + 8] = *(const uint4v*)(Kl + kg + 8);
      }
      __syncthreads();                       // K staged

      f32x4 S4[4] = {z, z, z, z};
      #pragma unroll
      for (int n = 0; n < 4; ++n) {
        #pragma unroll
        for (int c = 0; c < 2; ++c) {
          short8 kbh = *(const short8*)&KVh[n * 16 + lm][c * 32 + (lh << 3)];
          short8 kbl = *(const short8*)&KVl[n * 16 + lm][c * 32 + (lh << 3)];
          S4[n] = __builtin_amdgcn_mfma_f32_16x16x32_bf16(aQh[c], kbh, S4[n], 0, 0, 0);
          S4[n] = __builtin_amdgcn_mfma_f32_16x16x32_bf16(aQl[c], kbh, S4[n], 0, 0, 0);
          S4[n] = __builtin_amdgcn_mfma_f32_16x16x32_bf16(aQh[c], kbl, S4[n], 0, 0, 0);
        }
      }
      bool diag = (kt == qt);
      #pragma unroll
      for (int r = 0; r < 4; ++r) {
        float s0 = S4[0][r] * 0.125f, s1 = S4[1][r] * 0.125f;
        float s2 = S4[2][r] * 0.125f, s3 = S4[3][r] * 0.125f;
        if (diag) {
          int qq = qin + r;
          if (lm      > qq) s0 = -1e30f;
          if (16 + lm > qq) s1 = -1e30f;
          if (32 + lm > qq) s2 = -1e30f;
          if (48 + lm > qq) s3 = -1e30f;
        }
        float cm = fmaxf(fmaxf(s0, s1), fmaxf(s2, s3));
        cm = fmaxf(cm, __shfl_xor(cm, 1));
        cm = fmaxf(cm, __shfl_xor(cm, 2));
        cm = fmaxf(cm, __shfl_xor(cm, 4));
        cm = fmaxf(cm, __shfl_xor(cm, 8));
        if (cm > mrun[r] + 8.0f) {           // defer-max (THR=8)
          float sc = __expf(mrun[r] - cm);
          lrun[r] *= sc;
          ctx[0][r] *= sc; ctx[1][r] *= sc; ctx[2][r] *= sc; ctx[3][r] *= sc;
          mrun[r] = cm;
        }
        float p0 = __expf(s0 - mrun[r]), p1 = __expf(s1 - mrun[r]);
        float p2 = __expf(s2 - mrun[r]), p3 = __expf(s3 - mrun[r]);
        float rs = (p0 + p1) + (p2 + p3);
        rs += __shfl_xor(rs, 1); rs += __shfl_xor(rs, 2);
        rs += __shfl_xor(rs, 4); rs += __shfl_xor(rs, 8);
        lrun[r] += rs;
        int prow = qin + r;
        unsigned short e0 = f2bf(p0); Phs[prow][lm]      = e0; Pls[prow][lm]      = f2bf(p0 - bf2f(e0));
        unsigned short e1 = f2bf(p1); Phs[prow][16 + lm] = e1; Pls[prow][16 + lm] = f2bf(p1 - bf2f(e1));
        unsigned short e2 = f2bf(p2); Phs[prow][32 + lm] = e2; Pls[prow][32 + lm] = f2bf(p2 - bf2f(e2));
        unsigned short e3 = f2bf(p3); Phs[prow][48 + lm] = e3; Pls[prow][48 + lm] = f2bf(p3 - bf2f(e3));
      }
      __syncthreads();                       // QK^T reads of KV done
      {
        *(uint4v*)&KVh[srow][scs]     = vh0;
        *(uint4v*)&KVh[srow][scs + 8] = vh1;
        *(uint4v*)&KVl[srow][scs]     = vl0;
        *(uint4v*)&KVl[srow][scs + 8] = vl1;
      }
      __syncthreads();                       // V staged

      #pragma unroll
      for (int c = 0; c < 2; ++c) {
        short8 pah = *(const short8*)&Phs[wv * 16 + lm][c * 32 + (lh << 3)];
        short8 pal = *(const short8*)&Pls[wv * 16 + lm][c * 32 + (lh << 3)];
        #pragma unroll
        for (int n = 0; n < 4; ++n) {
          short8 vbh = *(const short8*)&KVh[n * 16 + lm][c * 32 + (lh << 3)];
          short8 vbl = *(const short8*)&KVl[n * 16 + lm][c * 32 + (lh << 3)];
          ctx[n] = __builtin_amdgcn_mfma_f32_16x16x32_bf16(pah, vbh, ctx[n], 0, 0, 0);
          ctx[n] = __builtin_amdgcn_mfma_f32_16x16x32_bf16(pal, vbh, ctx[n], 0, 0, 0);
          ctx[n] = __builtin_amdgcn_mfma_f32_16x16x32_bf16(pah, vbl, ctx[n], 0, 0, 0);
        }
      }
    }

    // write flash partials for this q-tile
    #pragma unroll
    for (int r = 0; r < 4; ++r) {
      int qg = b * SEQ + qt * 64 + wv * 16 + lh * 4 + r;
      size_t ob = ((size_t)par * TTOK + qg) * DMODEL + (size_t)h * HDIM + lm;
      #pragma unroll
      for (int n = 0; n < 4; ++n) paro[ob + n * 16] = ctx[n][r];
      if (lm == 0) {
        size_t mb = (((size_t)par * TTOK + qg) * NH + h) * 2;
        parml[mb] = mrun[r]; parml[mb + 1] = lrun[r];
      }
    }
  }
}

// ---------------------------------------------------------------------------
// attn_merge<NS>: exact flash merge of NS partials -> ctx hi/lo split.
// ---------------------------------------------------------------------------
template<int NS>
__global__ __launch_bounds__(256) void attn_merge(
    const float* __restrict__ paro,
    const float* __restrict__ parml,
    unsigned short* __restrict__ ctxh,
    unsigned short* __restrict__ ctxl)
{
  int gid = blockIdx.x * 256 + threadIdx.x;
  int ds = gid & 3;
  int h  = (gid >> 2) & 15;
  int t  = gid >> 6;
  float m[NS], lv[NS];
  float mx = -1e30f;
  #pragma unroll
  for (int i = 0; i < NS; ++i) {
    size_t mb = (((size_t)i * TTOK + t) * NH + h) * 2;
    m[i] = parml[mb]; lv[i] = parml[mb + 1];
    mx = fmaxf(mx, m[i]);
  }
  float w[NS], lsum = 0.f;
  #pragma unroll
  for (int i = 0; i < NS; ++i) { w[i] = __expf(m[i] - mx); lsum += lv[i] * w[i]; }
  float inv = 1.0f / lsum;
  size_t ob = (size_t)t * DMODEL + (size_t)h * HDIM + ds * 16;
  #pragma unroll
  for (int i4 = 0; i4 < 4; ++i4) {
    f32x4 v = {0.f, 0.f, 0.f, 0.f};
    #pragma unroll
    for (int i = 0; i < NS; ++i) {
      const f32x4* oi = (const f32x4*)(paro + (size_t)i * TTOK * DMODEL + ob);
      v += oi[i4] * w[i];
    }
    v = v * inv;
    ushort4 hi, lo;
    unsigned short e0 = f2bf(v[0]); hi.x = e0; lo.x = f2bf(v[0] - bf2f(e0));
    unsigned short e1 = f2bf(v[1]); hi.y = e1; lo.y = f2bf(v[1] - bf2f(e1));
    unsigned short e2 = f2bf(v[2]); hi.z = e2; lo.z = f2bf(v[2] - bf2f(e2));
    unsigned short e3 = f2bf(v[3]); hi.w = e3; lo.w = f2bf(v[3] - bf2f(e3));
    *(ushort4*)(ctxh + ob + i4 * 4) = hi;
    *(ushort4*)(ctxl + ob + i4 * 4) = lo;
  }
}

// ---------------------------------------------------------------------------
// Router (fp32)
// ---------------------------------------------------------------------------
__global__ __launch_bounds__(256) void router_kernel(
    const float* __restrict__ x1,
    const float* __restrict__ gam,
    const float* __restrict__ bet,
    const float* __restrict__ wrt,
    int* __restrict__ ctrl,
    int2* __restrict__ t_e,
    float2* __restrict__ t_g)
{
  int w = threadIdx.x >> 6, l = threadIdx.x & 63;
  int t = blockIdx.x * 4 + w;
  const f32x4* row = (const f32x4*)(x1 + (size_t)t * DMODEL);
  f32x4 v[4];
  float s = 0.f, sq = 0.f;
  #pragma unroll
  for (int i = 0; i < 4; ++i) {
    v[i] = row[l + i * 64];
    #pragma unroll
    for (int j = 0; j < 4; ++j) { s += v[i][j]; sq += v[i][j] * v[i][j]; }
  }
  #pragma unroll
  for (int off = 1; off < 64; off <<= 1) {
    s  += __shfl_xor(s, off);
    sq += __shfl_xor(sq, off);
  }
  float mu  = s * (1.0f / DMODEL);
  float var = sq * (1.0f / DMODEL) - mu * mu;
  float rs  = rsqrtf(var + 1e-5f);

  float acc[NE] = {0.f, 0.f, 0.f, 0.f, 0.f, 0.f, 0.f, 0.f};
  #pragma unroll
  for (int i = 0; i < 4; ++i) {
    int base = (l + i * 64) * 4;
    #pragma unroll
    for (int j = 0; j < 4; ++j) {
      int idx = base + j;
      float xn = (v[i][j] - mu) * rs * gam[idx] + bet[idx];
      const f32x4* wr0 = (const f32x4*)(wrt + idx * NE);
      f32x4 w0 = wr0[0], w1v = wr0[1];
      acc[0] += xn * w0[0]; acc[1] += xn * w0[1];
      acc[2] += xn * w0[2]; acc[3] += xn * w0[3];
      acc[4] += xn * w1v[0]; acc[5] += xn * w1v[1];
      acc[6] += xn * w1v[2]; acc[7] += xn * w1v[3];
    }
  }
  #pragma unroll
  for (int e = 0; e < NE; ++e) {
    #pragma unroll
    for (int off = 1; off < 64; off <<= 1) acc[e] += __shfl_xor(acc[e], off);
  }
  if (l == 0) {
    int e0 = 0; float m0v = acc[0];
    #pragma unroll
    for (int e = 1; e < NE; ++e) if (acc[e] > m0v) { m0v = acc[e]; e0 = e; }
    int e1 = -1; float m1v = -1e30f;
    #pragma unroll
    for (int e = 0; e < NE; ++e) if (e != e0 && acc[e] > m1v) { m1v = acc[e]; e1 = e; }
    float r = __expf(m1v - m0v);
    float g0 = 1.0f / (1.0f + r);
    float g1 = r * g0;
    t_e[t] = make_int2(e0, e1);
    t_g[t] = make_float2(g0, g1);
    atomicAdd(&ctrl[C_CNT + e0], 1);
    atomicAdd(&ctrl[C_CNT + e1], 1);
  }
}

// ---------------------------------------------------------------------------
// Scan: 128-padded per-expert slot bases + 128-row m-tile table.
// ---------------------------------------------------------------------------
__global__ void scan_kernel(int* __restrict__ ctrl)
{
  if (threadIdx.x == 0 && blockIdx.x == 0) {
    int b = 0, m = 0;
    for (int e = 0; e < NE; ++e) {
      ctrl[C_BASE + e] = b;
      int pc = (ctrl[C_CNT + e] + 127) & ~127;
      int nt = pc >> 7;
      for (int i = 0; i < nt; ++i) {
        ctrl[C_MTE + m] = e;
        ctrl[C_MTS + m] = b + (i << 7);
        ++m;
      }
      b += pc;
    }
    ctrl[C_NMT] = m;
  }
}

// ---------------------------------------------------------------------------
__global__ __launch_bounds__(256) void gather_kernel(
    int* __restrict__ ctrl,
    const int2* __restrict__ t_e,
    const float2* __restrict__ t_g,
    int* __restrict__ slot_token,
    float* __restrict__ slot_gate)
{
  int t = blockIdx.x * 256 + threadIdx.x;
  int2 e = t_e[t];
  float2 g = t_g[t];
  int p0 = atomicAdd(&ctrl[C_FILL + e.x], 1);
  int s0 = ctrl[C_BASE + e.x] + p0;
  slot_token[s0] = t; slot_gate[s0] = g.x;
  int p1 = atomicAdd(&ctrl[C_FILL + e.y], 1);
  int s1 = ctrl[C_BASE + e.y] + p1;
  slot_token[s1] = t; slot_gate[s1] = g.y;
}

// ---------------------------------------------------------------------------
// Transpose + fp32->bf16: in [E][K][N] fp32 -> out [E][N][K] bf16.
// ---------------------------------------------------------------------------
__global__ __launch_bounds__(256) void transpose_conv(
    const float* __restrict__ in, unsigned short* __restrict__ outb,
    unsigned short* __restrict__ outlo, int K, int N)
{
  __shared__ float T[64][68];
  int e = blockIdx.z;
  int n0 = blockIdx.x * 64, k0 = blockIdx.y * 64;
  const float* src = in + (size_t)e * K * N;
  unsigned short* dst = outb + (size_t)e * K * N;
  unsigned short* dstl = outlo ? outlo + (size_t)e * K * N : nullptr;
  int tid = threadIdx.x;
  int r = tid >> 4, c4 = (tid & 15) * 4;
  #pragma unroll
  for (int i = 0; i < 4; ++i) {
    f32x4 v = *(const f32x4*)(src + (size_t)(k0 + r + i * 16) * N + n0 + c4);
    *(f32x4*)(&T[r + i * 16][c4]) = v;
  }
  __syncthreads();
  #pragma unroll
  for (int i = 0; i < 4; ++i) {
    int rr = r + i * 16;
    float v0 = T[c4 + 0][rr], v1 = T[c4 + 1][rr];
    float v2 = T[c4 + 2][rr], v3 = T[c4 + 3][rr];
    ushort4 o;
    o.x = f2bf(v0); o.y = f2bf(v1); o.z = f2bf(v2); o.w = f2bf(v3);
    *(ushort4*)(dst + (size_t)(n0 + rr) * K + k0 + c4) = o;
    if (dstl) {
      ushort4 lo;
      lo.x = f2bf(v0 - bf2f(o.x));
      lo.y = f2bf(v1 - bf2f(o.y));
      lo.z = f2bf(v2 - bf2f(o.z));
      lo.w = f2bf(v3 - bf2f(o.w));
      *(ushort4*)(dstl + (size_t)(n0 + rr) * K + k0 + c4) = lo;
    }
  }
}

// ---------------------------------------------------------------------------
// Fast sparse MoE w1 (global_load_lds staging, unpadded [128][32] LDS).
// ---------------------------------------------------------------------------
__global__ __launch_bounds__(256) void moe_w1f(
    const unsigned short* __restrict__ h2,
    const unsigned short* __restrict__ w1t,
    const float* __restrict__ b1,
    const int* __restrict__ ctrl,
    const int* __restrict__ slot_token,
    unsigned short* __restrict__ Hs)
{
  int mt = blockIdx.y;
  if (mt >= ctrl[C_NMT]) return;
  int e = ctrl[C_MTE + mt];
  int slot0 = ctrl[C_MTS + mt];
  const int N = DFF, K = DMODEL;
  const unsigned short* Bt = w1t + (size_t)e * K * N;
  const float* bias = b1 + (size_t)e * DFF;

  __shared__ unsigned short Al[128][32];
  __shared__ unsigned short Bl[128][32];
  __shared__ int tokrow[128];
  int tid = threadIdx.x;
  if (tid < 128) {
    int tk = slot_token[slot0 + tid];
    tokrow[tid] = tk < 0 ? 0 : tk;
  }
  __syncthreads();
  int l = tid & 63, wv = tid >> 6;
  int wr = wv >> 1, wc = wv & 1;
  int n0 = blockIdx.x * 128;
  int rsub = l >> 2, csub = (l & 3) * 8;
  int row0 = wv * 32 + rsub, row1 = row0 + 16;
  const unsigned short* ga0 = h2 + (size_t)tokrow[row0] * DMODEL + csub;
  const unsigned short* ga1 = h2 + (size_t)tokrow[row1] * DMODEL + csub;
  const unsigned short* gb0 = Bt + (size_t)(n0 + row0) * K + csub;
  const unsigned short* gb1 = Bt + (size_t)(n0 + row1) * K + csub;

  const f32x4 z = {0.f, 0.f, 0.f, 0.f};
  f32x4 acc[4][4];
  #pragma unroll
  for (int i = 0; i < 4; ++i)
    #pragma unroll
    for (int j = 0; j < 4; ++j) acc[i][j] = z;

  for (int k0 = 0; k0 < K; k0 += 32) {
    __syncthreads();
    gl_lds16(ga0 + k0, &Al[wv * 32][0]);
    gl_lds16(ga1 + k0, &Al[wv * 32 + 16][0]);
    gl_lds16(gb0 + k0, &Bl[wv * 32][0]);
    gl_lds16(gb1 + k0, &Bl[wv * 32 + 16][0]);
    __syncthreads();

    short8 af[4], bfr[4];
    #pragma unroll
    for (int m = 0; m < 4; ++m)
      af[m] = *(const short8*)(&Al[wr * 64 + m * 16 + (l & 15)][(l >> 4) << 3]);
    #pragma unroll
    for (int n = 0; n < 4; ++n)
      bfr[n] = *(const short8*)(&Bl[wc * 64 + n * 16 + (l & 15)][(l >> 4) << 3]);
    #pragma unroll
    for (int m = 0; m < 4; ++m)
      #pragma unroll
      for (int n = 0; n < 4; ++n)
        acc[m][n] = __builtin_amdgcn_mfma_f32_16x16x32_bf16(af[m], bfr[n], acc[m][n], 0, 0, 0);
  }

  int rbase = wr * 64 + ((l >> 4) << 2);
  int cbase = n0 + wc * 64 + (l & 15);
  #pragma unroll
  for (int n = 0; n < 4; ++n) {
    int col = cbase + n * 16;
    float bv = bias[col];
    #pragma unroll
    for (int m = 0; m < 4; ++m) {
      #pragma unroll
      for (int r = 0; r < 4; ++r) {
        int srow = slot0 + rbase + m * 16 + r;
        float v = acc[m][n][r] + bv;
        v = 0.5f * v * (1.0f + erff(v * 0.70710678118654752f));
        Hs[(size_t)srow * DFF + col] = f2bf(v);
      }
    }
  }
}

// ---------------------------------------------------------------------------
// Fast sparse MoE w2 — 2-phase double-buffered staging (T3 minimum recipe +
// T4 counted vmcnt): issue step k+1's loads before computing step k; wait
// vmcnt(4) (older group) at a RAW s_barrier (no __syncthreads vmcnt(0) drain).
// ---------------------------------------------------------------------------
__global__ __launch_bounds__(256) void moe_w2f(
    const unsigned short* __restrict__ Hs,
    const unsigned short* __restrict__ w2t,
    const float* __restrict__ b2,
    const int* __restrict__ ctrl,
    const int* __restrict__ slot_token,
    const float* __restrict__ slot_gate,
    float* __restrict__ ffn)
{
  int mt = blockIdx.y;
  if (mt >= ctrl[C_NMT]) return;
  int e = ctrl[C_MTE + mt];
  int slot0 = ctrl[C_MTS + mt];
  const int N = DMODEL, K = DFF;
  const unsigned short* Bt = w2t + (size_t)e * (size_t)K * N;
  const float* bias = b2 + (size_t)e * DMODEL;

  __shared__ unsigned short Al[2][128][32];
  __shared__ unsigned short Bl[2][128][32];
  int tid = threadIdx.x;
  int l = tid & 63, wv = tid >> 6;
  int wr = wv >> 1, wc = wv & 1;
  int n0 = blockIdx.x * 128;
  int rsub = l >> 2, csub = (l & 3) * 8;
  int row0 = wv * 32 + rsub, row1 = row0 + 16;
  const unsigned short* ga0 = Hs + (size_t)(slot0 + row0) * DFF + csub;
  const unsigned short* ga1 = Hs + (size_t)(slot0 + row1) * DFF + csub;
  const unsigned short* gb0 = Bt + (size_t)(n0 + row0) * K + csub;
  const unsigned short* gb1 = Bt + (size_t)(n0 + row1) * K + csub;

  const f32x4 z = {0.f, 0.f, 0.f, 0.f};
  f32x4 acc[4][4];
  #pragma unroll
  for (int i = 0; i < 4; ++i)
    #pragma unroll
    for (int j = 0; j < 4; ++j) acc[i][j] = z;

  // prologue: stage step 0 into buf 0 (4 loads outstanding)
  gl_lds16(ga0, &Al[0][wv * 32][0]);
  gl_lds16(ga1, &Al[0][wv * 32 + 16][0]);
  gl_lds16(gb0, &Bl[0][wv * 32][0]);
  gl_lds16(gb1, &Bl[0][wv * 32 + 16][0]);

  const int nst = K / 32;            // 128 steps
  #pragma unroll 1
  for (int s = 0; s < nst; ++s) {
    int cur = s & 1, nxt = cur ^ 1;
    // issue next step's loads (clamped re-stage on last iter; harmless)
    int k0n = (s + 1 < nst ? s + 1 : s) * 32;
    gl_lds16(ga0 + k0n, &Al[nxt][wv * 32][0]);
    gl_lds16(ga1 + k0n, &Al[nxt][wv * 32 + 16][0]);
    gl_lds16(gb0 + k0n, &Bl[nxt][wv * 32][0]);
    gl_lds16(gb1 + k0n, &Bl[nxt][wv * 32 + 16][0]);
    // wait only for the OLDER 4 loads (buf cur ready), then barrier
    asm volatile("s_waitcnt vmcnt(4)" ::: "memory");
    __builtin_amdgcn_sched_barrier(0);
    __builtin_amdgcn_s_barrier();

    short8 af[4], bfr[4];
    #pragma unroll
    for (int m = 0; m < 4; ++m)
      af[m] = *(const short8*)(&Al[cur][wr * 64 + m * 16 + (l & 15)][(l >> 4) << 3]);
    #pragma unroll
    for (int n = 0; n < 4; ++n)
      bfr[n] = *(const short8*)(&Bl[cur][wc * 64 + n * 16 + (l & 15)][(l >> 4) << 3]);
    #pragma unroll
    for (int m = 0; m < 4; ++m)
      #pragma unroll
      for (int n = 0; n < 4; ++n)
        acc[m][n] = __builtin_amdgcn_mfma_f32_16x16x32_bf16(af[m], bfr[n], acc[m][n], 0, 0, 0);

    // all waves done reading buf cur before it is overwritten (in iter s+2)
    __builtin_amdgcn_s_barrier();
  }

  int rbase = wr * 64 + ((l >> 4) << 2);
  int cbase = n0 + wc * 64 + (l & 15);
  #pragma unroll
  for (int n = 0; n < 4; ++n) {
    int col = cbase + n * 16;
    float bv = bias[col];
    #pragma unroll
    for (int m = 0; m < 4; ++m) {
      #pragma unroll
      for (int r = 0; r < 4; ++r) {
        int srow = slot0 + rbase + m * 16 + r;
        int tok = slot_token[srow];
        if (tok >= 0) {
          float v = acc[m][n][r] + bv;
          atomicAdd(&ffn[(size_t)tok * DMODEL + col], slot_gate[srow] * v);
        }
      }
    }
  }
}

// ---------------------------------------------------------------------------
__global__ __launch_bounds__(256) void final_add(
    const float* __restrict__ x1,
    const float* __restrict__ ffn,
    float* __restrict__ out)
{
  int i = blockIdx.x * 256 + threadIdx.x;
  f32x4 xr = ((const f32x4*)x1)[i];
  f32x4 fr = ((const f32x4*)ffn)[i];
  f32x4 o;
  o[0] = xr[0] + fr[0];
  o[1] = xr[1] + fr[1];
  o[2] = xr[2] + fr[2];
  o[3] = xr[3] + fr[3];
  ((f32x4*)out)[i] = o;
}

// ---------------------------------------------------------------------------
extern "C" void kernel_launch(void* const* d_in, const int* in_sizes, int n_in,
                              void* d_out, int out_size, void* d_ws, size_t ws_size,
                              hipStream_t stream) {
  (void)in_sizes; (void)n_in; (void)out_size;
  const float* x     = (const float*)d_in[0];
  const float* ln1_g = (const float*)d_in[1];
  const float* ln1_b = (const float*)d_in[2];
  const float* ln2_g = (const float*)d_in[3];
  const float* ln2_b = (const float*)d_in[4];
  const float* wqkv  = (const float*)d_in[5];
  const float* bqkv  = (const float*)d_in[6];
  const float* wo    = (const float*)d_in[7];
  const float* bo    = (const float*)d_in[8];
  const float* wrt   = (const float*)d_in[9];
  const float* w1    = (const float*)d_in[10];
  const float* b1    = (const float*)d_in[11];
  const float* w2    = (const float*)d_in[12];
  const float* b2    = (const float*)d_in[13];
  float* out = (float*)d_out;

  char* ws = (char*)d_ws;
  size_t off = 0;
  auto alloc = [&](size_t bytes) -> void* {
    void* p = ws + off;
    off += (bytes + 255) & ~(size_t)255;
    return p;
  };
  float*          x1    = (float*)alloc((size_t)TTOK * DMODEL * 4);
  unsigned short* h2    = (unsigned short*)alloc((size_t)TTOK * DMODEL * 2);
  int*            ctrl  = (int*)alloc(1024);
  int2*           t_e   = (int2*)alloc((size_t)TTOK * 8);
  float2*         t_g   = (float2*)alloc((size_t)TTOK * 8);
  int*            slot_token = (int*)alloc((size_t)SLOT_MAX * 4);
  float*          slot_gate  = (float*)alloc((size_t)SLOT_MAX * 4);
  float*          P1    = (float*)alloc((size_t)TTOK * DMODEL * 4);
  char*           P2    = (char*)alloc((size_t)SLOT_MAX * DFF * 2);
  unsigned short* w1t   = (unsigned short*)alloc((size_t)NE * DMODEL * DFF * 2);
  unsigned short* w2t   = (unsigned short*)alloc((size_t)NE * DFF * DMODEL * 2);
  unsigned short* wqkvTh = (unsigned short*)alloc((size_t)DMODEL * 3 * DMODEL * 2);
  unsigned short* wqkvTl = (unsigned short*)alloc((size_t)DMODEL * 3 * DMODEL * 2);
  unsigned short* woTh  = (unsigned short*)alloc((size_t)DMODEL * DMODEL * 2);
  unsigned short* woTl  = (unsigned short*)alloc((size_t)DMODEL * DMODEL * 2);
  unsigned short* hh    = (unsigned short*)alloc((size_t)TTOK * DMODEL * 2);
  unsigned short* hl    = (unsigned short*)alloc((size_t)TTOK * DMODEL * 2);
  unsigned short* ctxh  = (unsigned short*)alloc((size_t)TTOK * DMODEL * 2);
  unsigned short* ctxl  = (unsigned short*)alloc((size_t)TTOK * DMODEL * 2);
  // MFMA attention split-qkv arrays + flash partials
  size_t headsz = (size_t)NB * NH * SEQ * HDIM;   // elems per array
  unsigned short* Qh  = (unsigned short*)alloc(headsz * 2);
  unsigned short* Ql  = (unsigned short*)alloc(headsz * 2);
  unsigned short* Khp = (unsigned short*)alloc(headsz * 2);
  unsigned short* Klp = (unsigned short*)alloc(headsz * 2);
  unsigned short* Vth = (unsigned short*)alloc(headsz * 2);
  unsigned short* Vtl = (unsigned short*)alloc(headsz * 2);
  float*          paro2  = (float*)alloc((size_t)2 * TTOK * DMODEL * 4);
  float*          parml2 = (float*)alloc((size_t)2 * TTOK * NH * 2 * 4);

  float*          qkv  = (float*)P2;        // dead before Hs is written
  float*          ffn  = P1;
  unsigned short* Hs   = (unsigned short*)P2;

  // 0) zero control counters, mark all slots invalid
  hipMemsetAsync(ctrl, 0, 16 * 4, stream);
  hipMemsetAsync(slot_token, 0xFF, (size_t)SLOT_MAX * 4, stream);

  // 0b) weight prep
  transpose_conv<<<dim3(DFF / 64, DMODEL / 64, NE), 256, 0, stream>>>(
      w1, w1t, nullptr, DMODEL, DFF);
  transpose_conv<<<dim3(DMODEL / 64, DFF / 64, NE), 256, 0, stream>>>(
      w2, w2t, nullptr, DFF, DMODEL);
  transpose_conv<<<dim3(3 * DMODEL / 64, DMODEL / 64, 1), 256, 0, stream>>>(
      wqkv, wqkvTh, wqkvTl, DMODEL, 3 * DMODEL);
  transpose_conv<<<dim3(DMODEL / 64, DMODEL / 64, 1), 256, 0, stream>>>(
      wo, woTh, woTl, DMODEL, DMODEL);

  // 1) h = LN1(x) -> split hi/lo
  ln_kernel<2><<<TTOK, 256, 0, stream>>>(x, ln1_g, ln1_b, nullptr, hh, hl);
  // 2) qkv = h @ wqkv + bqkv   (split-bf16 MFMA, fp32-grade)
  mgemm_split<0><<<dim3(3 * DMODEL / 128, TTOK / 128), 256, 0, stream>>>(
      hh, hl, wqkvTh, wqkvTl, bqkv, nullptr, qkv, TTOK, 3 * DMODEL, DMODEL);
  // 3) ctx = causal attention (split-bf16 MFMA flash, parity+fold) -> merge
  qkv_split<<<dim3(SEQ / 64, NB * NH), 256, 0, stream>>>(
      qkv, Qh, Ql, Khp, Klp, Vth, Vtl);
  attn_mf3<<<dim3(32, NB * NH), 256, 0, stream>>>(
      Qh, Ql, Khp, Klp, Vth, Vtl, paro2, parml2);
  attn_merge<2><<<(TTOK * NH * 4) / 256, 256, 0, stream>>>(
      paro2, parml2, ctxh, ctxl);
  // 4) x1 = x + ctx @ wo + bo  (split-bf16 MFMA)
  mgemm_split<1><<<dim3(DMODEL / 128, TTOK / 128), 256, 0, stream>>>(
      ctxh, ctxl, woTh, woTl, bo, x, x1, TTOK, DMODEL, DMODEL);

  // 5) h2 = LN2(x1)
  ln_kernel<1><<<TTOK, 256, 0, stream>>>(x1, ln2_g, ln2_b, nullptr, h2, nullptr);
  // 6) router -> scan -> gather
  router_kernel<<<TTOK / 4, 256, 0, stream>>>(x1, ln2_g, ln2_b, wrt, ctrl, t_e, t_g);
  scan_kernel<<<1, 64, 0, stream>>>(ctrl);
  gather_kernel<<<TTOK / 256, 256, 0, stream>>>(ctrl, t_e, t_g, slot_token, slot_gate);
  // 7) sparse MoE (w1 unchanged; w2 = 2-phase pipelined staging)
  hipMemsetAsync(ffn, 0, (size_t)TTOK * DMODEL * 4, stream);
  moe_w1f<<<dim3(DFF / 128, MT_MAX), 256, 0, stream>>>(
      h2, w1t, b1, ctrl, slot_token, Hs);
  moe_w2f<<<dim3(DMODEL / 128, MT_MAX), 256, 0, stream>>>(
      Hs, w2t, b2, ctrl, slot_token, slot_gate, ffn);
  // 8) out = x1 + ffn
  final_add<<<(TTOK * DMODEL / 4) / 256, 256, 0, stream>>>(x1, ffn, out);
}

// Round 21
// 885.965 us; speedup vs baseline: 1.3972x; 1.0078x over previous
//
#include <hip/hip_runtime.h>
#include <hip/hip_bf16.h>
#include <math.h>

// Problem constants
#define NB    2
#define SEQ   2048
#define DMODEL 1024
#define NH    16
#define HDIM  64
#define NE    8
#define DFF   4096
#define TTOK  4096   // NB*SEQ

#define MT_MAX   72
#define SLOT_MAX 9216

// ctrl block layout (ints)
#define C_CNT  0
#define C_FILL 8
#define C_BASE 16
#define C_NMT  24
#define C_MTE  32
#define C_MTS  104

typedef __attribute__((ext_vector_type(8))) short short8;
typedef __attribute__((ext_vector_type(4))) float f32x4;
typedef __attribute__((ext_vector_type(4))) unsigned int uint4v;

static __device__ __forceinline__ float bf2f(unsigned short u) {
  union { unsigned int i; float f; } c; c.i = ((unsigned int)u) << 16; return c.f;
}
static __device__ __forceinline__ unsigned short f2bf(float f) {
  unsigned int x = __float_as_uint(f);
  unsigned int r = (x + 0x7FFFu + ((x >> 16) & 1u)) >> 16;
  return (unsigned short)r;
}

// Async global->LDS, 16B per lane. LDS dest is WAVE-UNIFORM base + lane*16.
static __device__ __forceinline__ void gl_lds16(const void* g, void* l) {
  __builtin_amdgcn_global_load_lds(
      (const __attribute__((address_space(1))) unsigned int*)(uintptr_t)g,
      (__attribute__((address_space(3))) unsigned int*)(uintptr_t)l,
      16, 0, 0);
}

// ---------------------------------------------------------------------------
// LayerNorm. MODE 0: fp32 out. MODE 1: bf16 out. MODE 2: split hi/lo bf16.
// ---------------------------------------------------------------------------
template<int MODE>
__global__ __launch_bounds__(256) void ln_kernel(
    const float* __restrict__ x,
    const float* __restrict__ gam,
    const float* __restrict__ bet,
    float* __restrict__ outf,
    unsigned short* __restrict__ outb,
    unsigned short* __restrict__ outlo)
{
  int t = blockIdx.x, tid = threadIdx.x;
  f32x4 v = ((const f32x4*)(x + (size_t)t * DMODEL))[tid];
  float s  = v[0] + v[1] + v[2] + v[3];
  float sq = v[0]*v[0] + v[1]*v[1] + v[2]*v[2] + v[3]*v[3];
  #pragma unroll
  for (int off = 1; off < 64; off <<= 1) {
    s  += __shfl_xor(s, off);
    sq += __shfl_xor(sq, off);
  }
  __shared__ float red[8];
  int w = tid >> 6, l = tid & 63;
  if (l == 0) { red[w] = s; red[4 + w] = sq; }
  __syncthreads();
  s  = red[0] + red[1] + red[2] + red[3];
  sq = red[4] + red[5] + red[6] + red[7];
  float mu  = s * (1.0f / DMODEL);
  float var = sq * (1.0f / DMODEL) - mu * mu;
  float rs  = rsqrtf(var + 1e-5f);
  f32x4 g = ((const f32x4*)gam)[tid];
  f32x4 b = ((const f32x4*)bet)[tid];
  float r[4];
  r[0] = (v[0] - mu) * rs * g[0] + b[0];
  r[1] = (v[1] - mu) * rs * g[1] + b[1];
  r[2] = (v[2] - mu) * rs * g[2] + b[2];
  r[3] = (v[3] - mu) * rs * g[3] + b[3];
  if constexpr (MODE == 0) {
    f32x4 o = {r[0], r[1], r[2], r[3]};
    ((f32x4*)(outf + (size_t)t * DMODEL))[tid] = o;
  } else if constexpr (MODE == 1) {
    ushort4 o; o.x = f2bf(r[0]); o.y = f2bf(r[1]); o.z = f2bf(r[2]); o.w = f2bf(r[3]);
    ((ushort4*)(outb + (size_t)t * DMODEL))[tid] = o;
  } else {
    ushort4 hi, lo;
    unsigned short h0 = f2bf(r[0]); hi.x = h0; lo.x = f2bf(r[0] - bf2f(h0));
    unsigned short h1 = f2bf(r[1]); hi.y = h1; lo.y = f2bf(r[1] - bf2f(h1));
    unsigned short h2 = f2bf(r[2]); hi.z = h2; lo.z = f2bf(r[2] - bf2f(h2));
    unsigned short h3 = f2bf(r[3]); hi.w = h3; lo.w = f2bf(r[3] - bf2f(h3));
    ((ushort4*)(outb  + (size_t)t * DMODEL))[tid] = hi;
    ((ushort4*)(outlo + (size_t)t * DMODEL))[tid] = lo;
  }
}

// ---------------------------------------------------------------------------
// Split-bf16 MFMA GEMM (fp32-grade): C = (Ah+Al)(Bh+Bl) + bias [+resid].
// ---------------------------------------------------------------------------
template<int EPI>
__global__ __launch_bounds__(256) void mgemm_split(
    const unsigned short* __restrict__ Ah,
    const unsigned short* __restrict__ Alo,
    const unsigned short* __restrict__ Bth,
    const unsigned short* __restrict__ Btl,
    const float* __restrict__ bias,
    const float* __restrict__ resid,
    float* __restrict__ C, int M, int N, int K)
{
  __shared__ unsigned short AH[128][32];
  __shared__ unsigned short AL[128][32];
  __shared__ unsigned short BH[128][32];
  __shared__ unsigned short BL[128][32];
  int tid = threadIdx.x;
  int l = tid & 63, wv = tid >> 6;
  int wr = wv >> 1, wc = wv & 1;
  int m0 = blockIdx.y * 128, n0 = blockIdx.x * 128;
  int rsub = l >> 2, csub = (l & 3) * 8;
  int row0 = wv * 32 + rsub, row1 = row0 + 16;

  const unsigned short* gah0 = Ah  + (size_t)(m0 + row0) * K + csub;
  const unsigned short* gah1 = Ah  + (size_t)(m0 + row1) * K + csub;
  const unsigned short* gal0 = Alo + (size_t)(m0 + row0) * K + csub;
  const unsigned short* gal1 = Alo + (size_t)(m0 + row1) * K + csub;
  const unsigned short* gbh0 = Bth + (size_t)(n0 + row0) * K + csub;
  const unsigned short* gbh1 = Bth + (size_t)(n0 + row1) * K + csub;
  const unsigned short* gbl0 = Btl + (size_t)(n0 + row0) * K + csub;
  const unsigned short* gbl1 = Btl + (size_t)(n0 + row1) * K + csub;

  const f32x4 z = {0.f, 0.f, 0.f, 0.f};
  f32x4 acc[4][4];
  #pragma unroll
  for (int i = 0; i < 4; ++i)
    #pragma unroll
    for (int j = 0; j < 4; ++j) acc[i][j] = z;

  for (int k0 = 0; k0 < K; k0 += 32) {
    __syncthreads();
    gl_lds16(gah0 + k0, &AH[wv * 32][0]);
    gl_lds16(gah1 + k0, &AH[wv * 32 + 16][0]);
    gl_lds16(gal0 + k0, &AL[wv * 32][0]);
    gl_lds16(gal1 + k0, &AL[wv * 32 + 16][0]);
    gl_lds16(gbh0 + k0, &BH[wv * 32][0]);
    gl_lds16(gbh1 + k0, &BH[wv * 32 + 16][0]);
    gl_lds16(gbl0 + k0, &BL[wv * 32][0]);
    gl_lds16(gbl1 + k0, &BL[wv * 32 + 16][0]);
    __syncthreads();

    short8 afh[4], afl[4], bfh[4], bfl[4];
    #pragma unroll
    for (int m = 0; m < 4; ++m) {
      afh[m] = *(const short8*)(&AH[wr * 64 + m * 16 + (l & 15)][(l >> 4) << 3]);
      afl[m] = *(const short8*)(&AL[wr * 64 + m * 16 + (l & 15)][(l >> 4) << 3]);
    }
    #pragma unroll
    for (int n = 0; n < 4; ++n) {
      bfh[n] = *(const short8*)(&BH[wc * 64 + n * 16 + (l & 15)][(l >> 4) << 3]);
      bfl[n] = *(const short8*)(&BL[wc * 64 + n * 16 + (l & 15)][(l >> 4) << 3]);
    }
    #pragma unroll
    for (int m = 0; m < 4; ++m)
      #pragma unroll
      for (int n = 0; n < 4; ++n) {
        acc[m][n] = __builtin_amdgcn_mfma_f32_16x16x32_bf16(afh[m], bfh[n], acc[m][n], 0, 0, 0);
        acc[m][n] = __builtin_amdgcn_mfma_f32_16x16x32_bf16(afl[m], bfh[n], acc[m][n], 0, 0, 0);
        acc[m][n] = __builtin_amdgcn_mfma_f32_16x16x32_bf16(afh[m], bfl[n], acc[m][n], 0, 0, 0);
      }
  }

  int rbase = m0 + wr * 64 + ((l >> 4) << 2);
  int cbase = n0 + wc * 64 + (l & 15);
  #pragma unroll
  for (int n = 0; n < 4; ++n) {
    int col = cbase + n * 16;
    float bv = bias[col];
    #pragma unroll
    for (int m = 0; m < 4; ++m) {
      #pragma unroll
      for (int r = 0; r < 4; ++r) {
        int row = rbase + m * 16 + r;
        float v = acc[m][n][r] + bv;
        if constexpr (EPI == 1) v += resid[(size_t)row * N + col];
        C[(size_t)row * N + col] = v;
      }
    }
  }
}

// ---------------------------------------------------------------------------
// qkv_split: fp32 qkv [T][3][H][64] -> per-head split bf16 arrays.
// ---------------------------------------------------------------------------
__global__ __launch_bounds__(256) void qkv_split(
    const float* __restrict__ qkv,
    unsigned short* __restrict__ Qh, unsigned short* __restrict__ Ql,
    unsigned short* __restrict__ Kh, unsigned short* __restrict__ Kl,
    unsigned short* __restrict__ Vth, unsigned short* __restrict__ Vtl)
{
  __shared__ float Vt[64][68];
  int st = blockIdx.x, bh = blockIdx.y;
  int b = bh >> 4, h = bh & 15;
  int tid = threadIdx.x;
  int row = tid >> 2, cs = (tid & 3) * 16;
  size_t hb = (size_t)bh * SEQ * 64;
  int srow = st * 64 + row;
  size_t src = (size_t)(b * SEQ + srow) * 3072 + (size_t)h * HDIM + cs;

  #pragma unroll
  for (int qk = 0; qk < 2; ++qk) {
    const float* p = qkv + src + qk * 1024;
    unsigned short hi8[16], lo8[16];
    #pragma unroll
    for (int i = 0; i < 16; ++i) {
      float v = p[i];
      unsigned short hh_ = f2bf(v);
      hi8[i] = hh_; lo8[i] = f2bf(v - bf2f(hh_));
    }
    unsigned short* dh = (qk ? Kh : Qh) + hb + (size_t)srow * 64 + cs;
    unsigned short* dl = (qk ? Kl : Ql) + hb + (size_t)srow * 64 + cs;
    *(uint4v*)dh       = *(const uint4v*)&hi8[0];
    *(uint4v*)(dh + 8) = *(const uint4v*)&hi8[8];
    *(uint4v*)dl       = *(const uint4v*)&lo8[0];
    *(uint4v*)(dl + 8) = *(const uint4v*)&lo8[8];
  }
  {
    const float* p = qkv + src + 2048;
    #pragma unroll
    for (int i = 0; i < 4; ++i)
      *(f32x4*)&Vt[row][cs + i * 4] = *(const f32x4*)(p + i * 4);
  }
  __syncthreads();
  {
    int d = tid >> 2, ks = (tid & 3) * 16;
    unsigned short hi8[16], lo8[16];
    #pragma unroll
    for (int j = 0; j < 16; ++j) {
      float v = Vt[ks + j][d];
      unsigned short hh_ = f2bf(v);
      hi8[j] = hh_; lo8[j] = f2bf(v - bf2f(hh_));
    }
    size_t dst = hb + (size_t)d * SEQ + st * 64 + ks;
    *(uint4v*)(Vth + dst)     = *(const uint4v*)&hi8[0];
    *(uint4v*)(Vth + dst + 8) = *(const uint4v*)&hi8[8];
    *(uint4v*)(Vtl + dst)     = *(const uint4v*)&lo8[0];
    *(uint4v*)(Vtl + dst + 8) = *(const uint4v*)&lo8[8];
  }
}

// ---------------------------------------------------------------------------
// attn_mf3: split-bf16 MFMA flash attention, KV-parity + causal-fold.
// ---------------------------------------------------------------------------
__global__ __launch_bounds__(256) void attn_mf3(
    const unsigned short* __restrict__ Qh, const unsigned short* __restrict__ Ql,
    const unsigned short* __restrict__ Kh, const unsigned short* __restrict__ Kl,
    const unsigned short* __restrict__ Vth, const unsigned short* __restrict__ Vtl,
    float* __restrict__ paro,     // [2][TTOK][DMODEL] unnormalized o
    float* __restrict__ parml)    // [2][TTOK][NH][2]  (m, l)
{
  __shared__ unsigned short KVh[64][72], KVl[64][72];
  __shared__ unsigned short Phs[64][72], Pls[64][72];
  int bh = blockIdx.y;
  int b = bh >> 4, h = bh & 15;
  int bx = blockIdx.x;                 // 0..31
  int p  = bx >> 1, par = bx & 1;
  int tid = threadIdx.x, wv = tid >> 6, l = tid & 63;
  int lm = l & 15, lh = l >> 4;
  const size_t hb = (size_t)bh * SEQ * 64;
  int srow = tid >> 2, scs = (tid & 3) * 16;
  int qin = wv * 16 + lh * 4;          // + r = q row within tile
  const f32x4 z = {0.f, 0.f, 0.f, 0.f};

  #pragma unroll 1
  for (int job = 0; job < 2; ++job) {
    int qt = job ? (31 - p) : p;
    int q0 = qt * 64 + wv * 16;

    short8 aQh[2], aQl[2];
    {
      size_t qa = hb + (size_t)(q0 + lm) * 64 + (lh << 3);
      aQh[0] = *(const short8*)(Qh + qa);
      aQh[1] = *(const short8*)(Qh + qa + 32);
      aQl[0] = *(const short8*)(Ql + qa);
      aQl[1] = *(const short8*)(Ql + qa + 32);
    }
    f32x4 ctx[4] = {z, z, z, z};
    float mrun[4] = {-1e4f, -1e4f, -1e4f, -1e4f};
    float lrun[4] = {0.f, 0.f, 0.f, 0.f};

    for (int kt = par; kt <= qt; kt += 2) {
      uint4v vh0, vh1, vl0, vl1;
      {
        size_t vg = hb + (size_t)srow * SEQ + kt * 64 + scs;
        vh0 = *(const uint4v*)(Vth + vg);
        vh1 = *(const uint4v*)(Vth + vg + 8);
        vl0 = *(const uint4v*)(Vtl + vg);
        vl1 = *(const uint4v*)(Vtl + vg + 8);
      }
      __syncthreads();                       // prev PV reads done
      {
        size_t kg = hb + (size_t)(kt * 64 + srow) * 64 + scs;
        *(uint4v*)&KVh[srow][scs]     = *(const uint4v*)(Kh + kg);
        *(uint4v*)&KVh[srow][scs + 8] = *(const uint4v*)(Kh + kg + 8);
        *(uint4v*)&KVl[srow][scs]     = *(const uint4v*)(Kl + kg);
        *(uint4v*)&KVl[srow][scs + 8] = *(const uint4v*)(Kl + kg + 8);
      }
      __syncthreads();                       // K staged

      f32x4 S4[4] = {z, z, z, z};
      #pragma unroll
      for (int n = 0; n < 4; ++n) {
        #pragma unroll
        for (int c = 0; c < 2; ++c) {
          short8 kbh = *(const short8*)&KVh[n * 16 + lm][c * 32 + (lh << 3)];
          short8 kbl = *(const short8*)&KVl[n * 16 + lm][c * 32 + (lh << 3)];
          S4[n] = __builtin_amdgcn_mfma_f32_16x16x32_bf16(aQh[c], kbh, S4[n], 0, 0, 0);
          S4[n] = __builtin_amdgcn_mfma_f32_16x16x32_bf16(aQl[c], kbh, S4[n], 0, 0, 0);
          S4[n] = __builtin_amdgcn_mfma_f32_16x16x32_bf16(aQh[c], kbl, S4[n], 0, 0, 0);
        }
      }
      bool diag = (kt == qt);
      #pragma unroll
      for (int r = 0; r < 4; ++r) {
        float s0 = S4[0][r] * 0.125f, s1 = S4[1][r] * 0.125f;
        float s2 = S4[2][r] * 0.125f, s3 = S4[3][r] * 0.125f;
        if (diag) {
          int qq = qin + r;
          if (lm      > qq) s0 = -1e30f;
          if (16 + lm > qq) s1 = -1e30f;
          if (32 + lm > qq) s2 = -1e30f;
          if (48 + lm > qq) s3 = -1e30f;
        }
        float cm = fmaxf(fmaxf(s0, s1), fmaxf(s2, s3));
        cm = fmaxf(cm, __shfl_xor(cm, 1));
        cm = fmaxf(cm, __shfl_xor(cm, 2));
        cm = fmaxf(cm, __shfl_xor(cm, 4));
        cm = fmaxf(cm, __shfl_xor(cm, 8));
        if (cm > mrun[r] + 8.0f) {           // defer-max (THR=8)
          float sc = __expf(mrun[r] - cm);
          lrun[r] *= sc;
          ctx[0][r] *= sc; ctx[1][r] *= sc; ctx[2][r] *= sc; ctx[3][r] *= sc;
          mrun[r] = cm;
        }
        float p0 = __expf(s0 - mrun[r]), p1 = __expf(s1 - mrun[r]);
        float p2 = __expf(s2 - mrun[r]), p3 = __expf(s3 - mrun[r]);
        float rs = (p0 + p1) + (p2 + p3);
        rs += __shfl_xor(rs, 1); rs += __shfl_xor(rs, 2);
        rs += __shfl_xor(rs, 4); rs += __shfl_xor(rs, 8);
        lrun[r] += rs;
        int prow = qin + r;
        unsigned short e0 = f2bf(p0); Phs[prow][lm]      = e0; Pls[prow][lm]      = f2bf(p0 - bf2f(e0));
        unsigned short e1 = f2bf(p1); Phs[prow][16 + lm] = e1; Pls[prow][16 + lm] = f2bf(p1 - bf2f(e1));
        unsigned short e2 = f2bf(p2); Phs[prow][32 + lm] = e2; Pls[prow][32 + lm] = f2bf(p2 - bf2f(e2));
        unsigned short e3 = f2bf(p3); Phs[prow][48 + lm] = e3; Pls[prow][48 + lm] = f2bf(p3 - bf2f(e3));
      }
      __syncthreads();                       // QK^T reads of KV done
      {
        *(uint4v*)&KVh[srow][scs]     = vh0;
        *(uint4v*)&KVh[srow][scs + 8] = vh1;
        *(uint4v*)&KVl[srow][scs]     = vl0;
        *(uint4v*)&KVl[srow][scs + 8] = vl1;
      }
      __syncthreads();                       // V staged

      #pragma unroll
      for (int c = 0; c < 2; ++c) {
        short8 pah = *(const short8*)&Phs[wv * 16 + lm][c * 32 + (lh << 3)];
        short8 pal = *(const short8*)&Pls[wv * 16 + lm][c * 32 + (lh << 3)];
        #pragma unroll
        for (int n = 0; n < 4; ++n) {
          short8 vbh = *(const short8*)&KVh[n * 16 + lm][c * 32 + (lh << 3)];
          short8 vbl = *(const short8*)&KVl[n * 16 + lm][c * 32 + (lh << 3)];
          ctx[n] = __builtin_amdgcn_mfma_f32_16x16x32_bf16(pah, vbh, ctx[n], 0, 0, 0);
          ctx[n] = __builtin_amdgcn_mfma_f32_16x16x32_bf16(pal, vbh, ctx[n], 0, 0, 0);
          ctx[n] = __builtin_amdgcn_mfma_f32_16x16x32_bf16(pah, vbl, ctx[n], 0, 0, 0);
        }
      }
    }

    // write flash partials for this q-tile
    #pragma unroll
    for (int r = 0; r < 4; ++r) {
      int qg = b * SEQ + qt * 64 + wv * 16 + lh * 4 + r;
      size_t ob = ((size_t)par * TTOK + qg) * DMODEL + (size_t)h * HDIM + lm;
      #pragma unroll
      for (int n = 0; n < 4; ++n) paro[ob + n * 16] = ctx[n][r];
      if (lm == 0) {
        size_t mb = (((size_t)par * TTOK + qg) * NH + h) * 2;
        parml[mb] = mrun[r]; parml[mb + 1] = lrun[r];
      }
    }
  }
}

// ---------------------------------------------------------------------------
// attn_merge<NS>: exact flash merge of NS partials -> ctx hi/lo split.
// ---------------------------------------------------------------------------
template<int NS>
__global__ __launch_bounds__(256) void attn_merge(
    const float* __restrict__ paro,
    const float* __restrict__ parml,
    unsigned short* __restrict__ ctxh,
    unsigned short* __restrict__ ctxl)
{
  int gid = blockIdx.x * 256 + threadIdx.x;
  int ds = gid & 3;
  int h  = (gid >> 2) & 15;
  int t  = gid >> 6;
  float m[NS], lv[NS];
  float mx = -1e30f;
  #pragma unroll
  for (int i = 0; i < NS; ++i) {
    size_t mb = (((size_t)i * TTOK + t) * NH + h) * 2;
    m[i] = parml[mb]; lv[i] = parml[mb + 1];
    mx = fmaxf(mx, m[i]);
  }
  float w[NS], lsum = 0.f;
  #pragma unroll
  for (int i = 0; i < NS; ++i) { w[i] = __expf(m[i] - mx); lsum += lv[i] * w[i]; }
  float inv = 1.0f / lsum;
  size_t ob = (size_t)t * DMODEL + (size_t)h * HDIM + ds * 16;
  #pragma unroll
  for (int i4 = 0; i4 < 4; ++i4) {
    f32x4 v = {0.f, 0.f, 0.f, 0.f};
    #pragma unroll
    for (int i = 0; i < NS; ++i) {
      const f32x4* oi = (const f32x4*)(paro + (size_t)i * TTOK * DMODEL + ob);
      v += oi[i4] * w[i];
    }
    v = v * inv;
    ushort4 hi, lo;
    unsigned short e0 = f2bf(v[0]); hi.x = e0; lo.x = f2bf(v[0] - bf2f(e0));
    unsigned short e1 = f2bf(v[1]); hi.y = e1; lo.y = f2bf(v[1] - bf2f(e1));
    unsigned short e2 = f2bf(v[2]); hi.z = e2; lo.z = f2bf(v[2] - bf2f(e2));
    unsigned short e3 = f2bf(v[3]); hi.w = e3; lo.w = f2bf(v[3] - bf2f(e3));
    *(ushort4*)(ctxh + ob + i4 * 4) = hi;
    *(ushort4*)(ctxl + ob + i4 * 4) = lo;
  }
}

// ---------------------------------------------------------------------------
// Router (fp32)
// ---------------------------------------------------------------------------
__global__ __launch_bounds__(256) void router_kernel(
    const float* __restrict__ x1,
    const float* __restrict__ gam,
    const float* __restrict__ bet,
    const float* __restrict__ wrt,
    int* __restrict__ ctrl,
    int2* __restrict__ t_e,
    float2* __restrict__ t_g)
{
  int w = threadIdx.x >> 6, l = threadIdx.x & 63;
  int t = blockIdx.x * 4 + w;
  const f32x4* row = (const f32x4*)(x1 + (size_t)t * DMODEL);
  f32x4 v[4];
  float s = 0.f, sq = 0.f;
  #pragma unroll
  for (int i = 0; i < 4; ++i) {
    v[i] = row[l + i * 64];
    #pragma unroll
    for (int j = 0; j < 4; ++j) { s += v[i][j]; sq += v[i][j] * v[i][j]; }
  }
  #pragma unroll
  for (int off = 1; off < 64; off <<= 1) {
    s  += __shfl_xor(s, off);
    sq += __shfl_xor(sq, off);
  }
  float mu  = s * (1.0f / DMODEL);
  float var = sq * (1.0f / DMODEL) - mu * mu;
  float rs  = rsqrtf(var + 1e-5f);

  float acc[NE] = {0.f, 0.f, 0.f, 0.f, 0.f, 0.f, 0.f, 0.f};
  #pragma unroll
  for (int i = 0; i < 4; ++i) {
    int base = (l + i * 64) * 4;
    #pragma unroll
    for (int j = 0; j < 4; ++j) {
      int idx = base + j;
      float xn = (v[i][j] - mu) * rs * gam[idx] + bet[idx];
      const f32x4* wr0 = (const f32x4*)(wrt + idx * NE);
      f32x4 w0 = wr0[0], w1v = wr0[1];
      acc[0] += xn * w0[0]; acc[1] += xn * w0[1];
      acc[2] += xn * w0[2]; acc[3] += xn * w0[3];
      acc[4] += xn * w1v[0]; acc[5] += xn * w1v[1];
      acc[6] += xn * w1v[2]; acc[7] += xn * w1v[3];
    }
  }
  #pragma unroll
  for (int e = 0; e < NE; ++e) {
    #pragma unroll
    for (int off = 1; off < 64; off <<= 1) acc[e] += __shfl_xor(acc[e], off);
  }
  if (l == 0) {
    int e0 = 0; float m0v = acc[0];
    #pragma unroll
    for (int e = 1; e < NE; ++e) if (acc[e] > m0v) { m0v = acc[e]; e0 = e; }
    int e1 = -1; float m1v = -1e30f;
    #pragma unroll
    for (int e = 0; e < NE; ++e) if (e != e0 && acc[e] > m1v) { m1v = acc[e]; e1 = e; }
    float r = __expf(m1v - m0v);
    float g0 = 1.0f / (1.0f + r);
    float g1 = r * g0;
    t_e[t] = make_int2(e0, e1);
    t_g[t] = make_float2(g0, g1);
    atomicAdd(&ctrl[C_CNT + e0], 1);
    atomicAdd(&ctrl[C_CNT + e1], 1);
  }
}

// ---------------------------------------------------------------------------
// Scan: 128-padded per-expert slot bases + 128-row m-tile table.
// ---------------------------------------------------------------------------
__global__ void scan_kernel(int* __restrict__ ctrl)
{
  if (threadIdx.x == 0 && blockIdx.x == 0) {
    int b = 0, m = 0;
    for (int e = 0; e < NE; ++e) {
      ctrl[C_BASE + e] = b;
      int pc = (ctrl[C_CNT + e] + 127) & ~127;
      int nt = pc >> 7;
      for (int i = 0; i < nt; ++i) {
        ctrl[C_MTE + m] = e;
        ctrl[C_MTS + m] = b + (i << 7);
        ++m;
      }
      b += pc;
    }
    ctrl[C_NMT] = m;
  }
}

// ---------------------------------------------------------------------------
__global__ __launch_bounds__(256) void gather_kernel(
    int* __restrict__ ctrl,
    const int2* __restrict__ t_e,
    const float2* __restrict__ t_g,
    int* __restrict__ slot_token,
    float* __restrict__ slot_gate)
{
  int t = blockIdx.x * 256 + threadIdx.x;
  int2 e = t_e[t];
  float2 g = t_g[t];
  int p0 = atomicAdd(&ctrl[C_FILL + e.x], 1);
  int s0 = ctrl[C_BASE + e.x] + p0;
  slot_token[s0] = t; slot_gate[s0] = g.x;
  int p1 = atomicAdd(&ctrl[C_FILL + e.y], 1);
  int s1 = ctrl[C_BASE + e.y] + p1;
  slot_token[s1] = t; slot_gate[s1] = g.y;
}

// ---------------------------------------------------------------------------
// Transpose + fp32->bf16: in [E][K][N] fp32 -> out [E][N][K] bf16.
// ---------------------------------------------------------------------------
__global__ __launch_bounds__(256) void transpose_conv(
    const float* __restrict__ in, unsigned short* __restrict__ outb,
    unsigned short* __restrict__ outlo, int K, int N)
{
  __shared__ float T[64][68];
  int e = blockIdx.z;
  int n0 = blockIdx.x * 64, k0 = blockIdx.y * 64;
  const float* src = in + (size_t)e * K * N;
  unsigned short* dst = outb + (size_t)e * K * N;
  unsigned short* dstl = outlo ? outlo + (size_t)e * K * N : nullptr;
  int tid = threadIdx.x;
  int r = tid >> 4, c4 = (tid & 15) * 4;
  #pragma unroll
  for (int i = 0; i < 4; ++i) {
    f32x4 v = *(const f32x4*)(src + (size_t)(k0 + r + i * 16) * N + n0 + c4);
    *(f32x4*)(&T[r + i * 16][c4]) = v;
  }
  __syncthreads();
  #pragma unroll
  for (int i = 0; i < 4; ++i) {
    int rr = r + i * 16;
    float v0 = T[c4 + 0][rr], v1 = T[c4 + 1][rr];
    float v2 = T[c4 + 2][rr], v3 = T[c4 + 3][rr];
    ushort4 o;
    o.x = f2bf(v0); o.y = f2bf(v1); o.z = f2bf(v2); o.w = f2bf(v3);
    *(ushort4*)(dst + (size_t)(n0 + rr) * K + k0 + c4) = o;
    if (dstl) {
      ushort4 lo;
      lo.x = f2bf(v0 - bf2f(o.x));
      lo.y = f2bf(v1 - bf2f(o.y));
      lo.z = f2bf(v2 - bf2f(o.z));
      lo.w = f2bf(v3 - bf2f(o.w));
      *(ushort4*)(dstl + (size_t)(n0 + rr) * K + k0 + c4) = lo;
    }
  }
}

// ---------------------------------------------------------------------------
// Fast sparse MoE w1 — 2-phase double-buffered staging (round-20 w2f recipe).
// ---------------------------------------------------------------------------
__global__ __launch_bounds__(256) void moe_w1f(
    const unsigned short* __restrict__ h2,
    const unsigned short* __restrict__ w1t,
    const float* __restrict__ b1,
    const int* __restrict__ ctrl,
    const int* __restrict__ slot_token,
    unsigned short* __restrict__ Hs)
{
  int mt = blockIdx.y;
  if (mt >= ctrl[C_NMT]) return;
  int e = ctrl[C_MTE + mt];
  int slot0 = ctrl[C_MTS + mt];
  const int N = DFF, K = DMODEL;
  const unsigned short* Bt = w1t + (size_t)e * K * N;
  const float* bias = b1 + (size_t)e * DFF;

  __shared__ unsigned short Al[2][128][32];
  __shared__ unsigned short Bl[2][128][32];
  __shared__ int tokrow[128];
  int tid = threadIdx.x;
  if (tid < 128) {
    int tk = slot_token[slot0 + tid];
    tokrow[tid] = tk < 0 ? 0 : tk;
  }
  __syncthreads();
  int l = tid & 63, wv = tid >> 6;
  int wr = wv >> 1, wc = wv & 1;
  int n0 = blockIdx.x * 128;
  int rsub = l >> 2, csub = (l & 3) * 8;
  int row0 = wv * 32 + rsub, row1 = row0 + 16;
  const unsigned short* ga0 = h2 + (size_t)tokrow[row0] * DMODEL + csub;
  const unsigned short* ga1 = h2 + (size_t)tokrow[row1] * DMODEL + csub;
  const unsigned short* gb0 = Bt + (size_t)(n0 + row0) * K + csub;
  const unsigned short* gb1 = Bt + (size_t)(n0 + row1) * K + csub;

  const f32x4 z = {0.f, 0.f, 0.f, 0.f};
  f32x4 acc[4][4];
  #pragma unroll
  for (int i = 0; i < 4; ++i)
    #pragma unroll
    for (int j = 0; j < 4; ++j) acc[i][j] = z;

  // prologue: stage step 0 into buf 0
  gl_lds16(ga0, &Al[0][wv * 32][0]);
  gl_lds16(ga1, &Al[0][wv * 32 + 16][0]);
  gl_lds16(gb0, &Bl[0][wv * 32][0]);
  gl_lds16(gb1, &Bl[0][wv * 32 + 16][0]);

  const int nst = K / 32;            // 32 steps
  #pragma unroll 1
  for (int s = 0; s < nst; ++s) {
    int cur = s & 1, nxt = cur ^ 1;
    int k0n = (s + 1 < nst ? s + 1 : s) * 32;
    gl_lds16(ga0 + k0n, &Al[nxt][wv * 32][0]);
    gl_lds16(ga1 + k0n, &Al[nxt][wv * 32 + 16][0]);
    gl_lds16(gb0 + k0n, &Bl[nxt][wv * 32][0]);
    gl_lds16(gb1 + k0n, &Bl[nxt][wv * 32 + 16][0]);
    asm volatile("s_waitcnt vmcnt(4)" ::: "memory");
    __builtin_amdgcn_sched_barrier(0);
    __builtin_amdgcn_s_barrier();

    short8 af[4], bfr[4];
    #pragma unroll
    for (int m = 0; m < 4; ++m)
      af[m] = *(const short8*)(&Al[cur][wr * 64 + m * 16 + (l & 15)][(l >> 4) << 3]);
    #pragma unroll
    for (int n = 0; n < 4; ++n)
      bfr[n] = *(const short8*)(&Bl[cur][wc * 64 + n * 16 + (l & 15)][(l >> 4) << 3]);
    #pragma unroll
    for (int m = 0; m < 4; ++m)
      #pragma unroll
      for (int n = 0; n < 4; ++n)
        acc[m][n] = __builtin_amdgcn_mfma_f32_16x16x32_bf16(af[m], bfr[n], acc[m][n], 0, 0, 0);

    __builtin_amdgcn_s_barrier();
  }

  int rbase = wr * 64 + ((l >> 4) << 2);
  int cbase = n0 + wc * 64 + (l & 15);
  #pragma unroll
  for (int n = 0; n < 4; ++n) {
    int col = cbase + n * 16;
    float bv = bias[col];
    #pragma unroll
    for (int m = 0; m < 4; ++m) {
      #pragma unroll
      for (int r = 0; r < 4; ++r) {
        int srow = slot0 + rbase + m * 16 + r;
        float v = acc[m][n][r] + bv;
        v = 0.5f * v * (1.0f + erff(v * 0.70710678118654752f));
        Hs[(size_t)srow * DFF + col] = f2bf(v);
      }
    }
  }
}

// ---------------------------------------------------------------------------
// Fast sparse MoE w2 — 3-buffer, 2-steps-ahead staging (T3+T4 deepened):
// issue step s+2's loads; wait vmcnt(8) (step s's group) at a raw s_barrier.
// Race safety: write-buf (s+2)%3 == (s-1)%3 was consumed before iter s-1's
// second barrier; per-wave vmcnt(8) before barrier1 => all step-s loads landed.
// ---------------------------------------------------------------------------
__global__ __launch_bounds__(256) void moe_w2f(
    const unsigned short* __restrict__ Hs,
    const unsigned short* __restrict__ w2t,
    const float* __restrict__ b2,
    const int* __restrict__ ctrl,
    const int* __restrict__ slot_token,
    const float* __restrict__ slot_gate,
    float* __restrict__ ffn)
{
  int mt = blockIdx.y;
  if (mt >= ctrl[C_NMT]) return;
  int e = ctrl[C_MTE + mt];
  int slot0 = ctrl[C_MTS + mt];
  const int N = DMODEL, K = DFF;
  const unsigned short* Bt = w2t + (size_t)e * (size_t)K * N;
  const float* bias = b2 + (size_t)e * DMODEL;

  __shared__ unsigned short Al[3][128][32];
  __shared__ unsigned short Bl[3][128][32];
  int tid = threadIdx.x;
  int l = tid & 63, wv = tid >> 6;
  int wr = wv >> 1, wc = wv & 1;
  int n0 = blockIdx.x * 128;
  int rsub = l >> 2, csub = (l & 3) * 8;
  int row0 = wv * 32 + rsub, row1 = row0 + 16;
  const unsigned short* ga0 = Hs + (size_t)(slot0 + row0) * DFF + csub;
  const unsigned short* ga1 = Hs + (size_t)(slot0 + row1) * DFF + csub;
  const unsigned short* gb0 = Bt + (size_t)(n0 + row0) * K + csub;
  const unsigned short* gb1 = Bt + (size_t)(n0 + row1) * K + csub;

  const f32x4 z = {0.f, 0.f, 0.f, 0.f};
  f32x4 acc[4][4];
  #pragma unroll
  for (int i = 0; i < 4; ++i)
    #pragma unroll
    for (int j = 0; j < 4; ++j) acc[i][j] = z;

  // prologue: stage steps 0 and 1 (8 loads outstanding)
  gl_lds16(ga0, &Al[0][wv * 32][0]);
  gl_lds16(ga1, &Al[0][wv * 32 + 16][0]);
  gl_lds16(gb0, &Bl[0][wv * 32][0]);
  gl_lds16(gb1, &Bl[0][wv * 32 + 16][0]);
  gl_lds16(ga0 + 32, &Al[1][wv * 32][0]);
  gl_lds16(ga1 + 32, &Al[1][wv * 32 + 16][0]);
  gl_lds16(gb0 + 32, &Bl[1][wv * 32][0]);
  gl_lds16(gb1 + 32, &Bl[1][wv * 32 + 16][0]);

  const int nst = K / 32;            // 128 steps
  #pragma unroll 1
  for (int s = 0; s < nst; ++s) {
    int cur = s % 3;
    int wb = cur + 2; if (wb >= 3) wb -= 3;      // (s+2)%3
    int k0n = (s + 2 < nst ? s + 2 : nst - 1) * 32;
    gl_lds16(ga0 + k0n, &Al[wb][wv * 32][0]);
    gl_lds16(ga1 + k0n, &Al[wb][wv * 32 + 16][0]);
    gl_lds16(gb0 + k0n, &Bl[wb][wv * 32][0]);
    gl_lds16(gb1 + k0n, &Bl[wb][wv * 32 + 16][0]);
    // wait for step s's 4 loads (keep newest 8 = steps s+1, s+2 in flight)
    asm volatile("s_waitcnt vmcnt(8)" ::: "memory");
    __builtin_amdgcn_sched_barrier(0);
    __builtin_amdgcn_s_barrier();

    short8 af[4], bfr[4];
    #pragma unroll
    for (int m = 0; m < 4; ++m)
      af[m] = *(const short8*)(&Al[cur][wr * 64 + m * 16 + (l & 15)][(l >> 4) << 3]);
    #pragma unroll
    for (int n = 0; n < 4; ++n)
      bfr[n] = *(const short8*)(&Bl[cur][wc * 64 + n * 16 + (l & 15)][(l >> 4) << 3]);
    #pragma unroll
    for (int m = 0; m < 4; ++m)
      #pragma unroll
      for (int n = 0; n < 4; ++n)
        acc[m][n] = __builtin_amdgcn_mfma_f32_16x16x32_bf16(af[m], bfr[n], acc[m][n], 0, 0, 0);

    // all waves done reading buf cur before it is overwritten (iter s+1 writes (s+3)%3 == cur)
    __builtin_amdgcn_s_barrier();
  }

  int rbase = wr * 64 + ((l >> 4) << 2);
  int cbase = n0 + wc * 64 + (l & 15);
  #pragma unroll
  for (int n = 0; n < 4; ++n) {
    int col = cbase + n * 16;
    float bv = bias[col];
    #pragma unroll
    for (int m = 0; m < 4; ++m) {
      #pragma unroll
      for (int r = 0; r < 4; ++r) {
        int srow = slot0 + rbase + m * 16 + r;
        int tok = slot_token[srow];
        if (tok >= 0) {
          float v = acc[m][n][r] + bv;
          atomicAdd(&ffn[(size_t)tok * DMODEL + col], slot_gate[srow] * v);
        }
      }
    }
  }
}

// ---------------------------------------------------------------------------
__global__ __launch_bounds__(256) void final_add(
    const float* __restrict__ x1,
    const float* __restrict__ ffn,
    float* __restrict__ out)
{
  int i = blockIdx.x * 256 + threadIdx.x;
  f32x4 xr = ((const f32x4*)x1)[i];
  f32x4 fr = ((const f32x4*)ffn)[i];
  f32x4 o;
  o[0] = xr[0] + fr[0];
  o[1] = xr[1] + fr[1];
  o[2] = xr[2] + fr[2];
  o[3] = xr[3] + fr[3];
  ((f32x4*)out)[i] = o;
}

// ---------------------------------------------------------------------------
extern "C" void kernel_launch(void* const* d_in, const int* in_sizes, int n_in,
                              void* d_out, int out_size, void* d_ws, size_t ws_size,
                              hipStream_t stream) {
  (void)in_sizes; (void)n_in; (void)out_size;
  const float* x     = (const float*)d_in[0];
  const float* ln1_g = (const float*)d_in[1];
  const float* ln1_b = (const float*)d_in[2];
  const float* ln2_g = (const float*)d_in[3];
  const float* ln2_b = (const float*)d_in[4];
  const float* wqkv  = (const float*)d_in[5];
  const float* bqkv  = (const float*)d_in[6];
  const float* wo    = (const float*)d_in[7];
  const float* bo    = (const float*)d_in[8];
  const float* wrt   = (const float*)d_in[9];
  const float* w1    = (const float*)d_in[10];
  const float* b1    = (const float*)d_in[11];
  const float* w2    = (const float*)d_in[12];
  const float* b2    = (const float*)d_in[13];
  float* out = (float*)d_out;

  char* ws = (char*)d_ws;
  size_t off = 0;
  auto alloc = [&](size_t bytes) -> void* {
    void* p = ws + off;
    off += (bytes + 255) & ~(size_t)255;
    return p;
  };
  float*          x1    = (float*)alloc((size_t)TTOK * DMODEL * 4);
  unsigned short* h2    = (unsigned short*)alloc((size_t)TTOK * DMODEL * 2);
  int*            ctrl  = (int*)alloc(1024);
  int2*           t_e   = (int2*)alloc((size_t)TTOK * 8);
  float2*         t_g   = (float2*)alloc((size_t)TTOK * 8);
  int*            slot_token = (int*)alloc((size_t)SLOT_MAX * 4);
  float*          slot_gate  = (float*)alloc((size_t)SLOT_MAX * 4);
  float*          P1    = (float*)alloc((size_t)TTOK * DMODEL * 4);
  char*           P2    = (char*)alloc((size_t)SLOT_MAX * DFF * 2);
  unsigned short* w1t   = (unsigned short*)alloc((size_t)NE * DMODEL * DFF * 2);
  unsigned short* w2t   = (unsigned short*)alloc((size_t)NE * DFF * DMODEL * 2);
  unsigned short* wqkvTh = (unsigned short*)alloc((size_t)DMODEL * 3 * DMODEL * 2);
  unsigned short* wqkvTl = (unsigned short*)alloc((size_t)DMODEL * 3 * DMODEL * 2);
  unsigned short* woTh  = (unsigned short*)alloc((size_t)DMODEL * DMODEL * 2);
  unsigned short* woTl  = (unsigned short*)alloc((size_t)DMODEL * DMODEL * 2);
  unsigned short* hh    = (unsigned short*)alloc((size_t)TTOK * DMODEL * 2);
  unsigned short* hl    = (unsigned short*)alloc((size_t)TTOK * DMODEL * 2);
  unsigned short* ctxh  = (unsigned short*)alloc((size_t)TTOK * DMODEL * 2);
  unsigned short* ctxl  = (unsigned short*)alloc((size_t)TTOK * DMODEL * 2);
  // MFMA attention split-qkv arrays + flash partials
  size_t headsz = (size_t)NB * NH * SEQ * HDIM;   // elems per array
  unsigned short* Qh  = (unsigned short*)alloc(headsz * 2);
  unsigned short* Ql  = (unsigned short*)alloc(headsz * 2);
  unsigned short* Khp = (unsigned short*)alloc(headsz * 2);
  unsigned short* Klp = (unsigned short*)alloc(headsz * 2);
  unsigned short* Vth = (unsigned short*)alloc(headsz * 2);
  unsigned short* Vtl = (unsigned short*)alloc(headsz * 2);
  float*          paro2  = (float*)alloc((size_t)2 * TTOK * DMODEL * 4);
  float*          parml2 = (float*)alloc((size_t)2 * TTOK * NH * 2 * 4);

  float*          qkv  = (float*)P2;        // dead before Hs is written
  float*          ffn  = P1;
  unsigned short* Hs   = (unsigned short*)P2;

  // 0) zero control counters, mark all slots invalid
  hipMemsetAsync(ctrl, 0, 16 * 4, stream);
  hipMemsetAsync(slot_token, 0xFF, (size_t)SLOT_MAX * 4, stream);

  // 0b) weight prep
  transpose_conv<<<dim3(DFF / 64, DMODEL / 64, NE), 256, 0, stream>>>(
      w1, w1t, nullptr, DMODEL, DFF);
  transpose_conv<<<dim3(DMODEL / 64, DFF / 64, NE), 256, 0, stream>>>(
      w2, w2t, nullptr, DFF, DMODEL);
  transpose_conv<<<dim3(3 * DMODEL / 64, DMODEL / 64, 1), 256, 0, stream>>>(
      wqkv, wqkvTh, wqkvTl, DMODEL, 3 * DMODEL);
  transpose_conv<<<dim3(DMODEL / 64, DMODEL / 64, 1), 256, 0, stream>>>(
      wo, woTh, woTl, DMODEL, DMODEL);

  // 1) h = LN1(x) -> split hi/lo
  ln_kernel<2><<<TTOK, 256, 0, stream>>>(x, ln1_g, ln1_b, nullptr, hh, hl);
  // 2) qkv = h @ wqkv + bqkv   (split-bf16 MFMA, fp32-grade)
  mgemm_split<0><<<dim3(3 * DMODEL / 128, TTOK / 128), 256, 0, stream>>>(
      hh, hl, wqkvTh, wqkvTl, bqkv, nullptr, qkv, TTOK, 3 * DMODEL, DMODEL);
  // 3) ctx = causal attention (split-bf16 MFMA flash, parity+fold) -> merge
  qkv_split<<<dim3(SEQ / 64, NB * NH), 256, 0, stream>>>(
      qkv, Qh, Ql, Khp, Klp, Vth, Vtl);
  attn_mf3<<<dim3(32, NB * NH), 256, 0, stream>>>(
      Qh, Ql, Khp, Klp, Vth, Vtl, paro2, parml2);
  attn_merge<2><<<(TTOK * NH * 4) / 256, 256, 0, stream>>>(
      paro2, parml2, ctxh, ctxl);
  // 4) x1 = x + ctx @ wo + bo  (split-bf16 MFMA)
  mgemm_split<1><<<dim3(DMODEL / 128, TTOK / 128), 256, 0, stream>>>(
      ctxh, ctxl, woTh, woTl, bo, x, x1, TTOK, DMODEL, DMODEL);

  // 5) h2 = LN2(x1)
  ln_kernel<1><<<TTOK, 256, 0, stream>>>(x1, ln2_g, ln2_b, nullptr, h2, nullptr);
  // 6) router -> scan -> gather
  router_kernel<<<TTOK / 4, 256, 0, stream>>>(x1, ln2_g, ln2_b, wrt, ctrl, t_e, t_g);
  scan_kernel<<<1, 64, 0, stream>>>(ctrl);
  gather_kernel<<<TTOK / 256, 256, 0, stream>>>(ctrl, t_e, t_g, slot_token, slot_gate);
  // 7) sparse MoE (w1 = 2-phase pipelined; w2 = 3-buffer 2-ahead pipelined)
  hipMemsetAsync(ffn, 0, (size_t)TTOK * DMODEL * 4, stream);
  moe_w1f<<<dim3(DFF / 128, MT_MAX), 256, 0, stream>>>(
      h2, w1t, b1, ctrl, slot_token, Hs);
  moe_w2f<<<dim3(DMODEL / 128, MT_MAX), 256, 0, stream>>>(
      Hs, w2t, b2, ctrl, slot_token, slot_gate, ffn);
  // 8) out = x1 + ffn
  final_add<<<(TTOK * DMODEL / 4) / 256, 256, 0, stream>>>(x1, ffn, out);
}